// Round 8
// baseline (247.722 us; speedup 1.0000x reference)
//
#include <hip/hip_runtime.h>
#include <math.h>

// QANetAttBlock: B=16, S=1024, HID=512, H=8, DK=64
constexpr int CB = 16;
constexpr int CS = 1024;
constexpr int CHID = 512;
constexpr int CH = 8;
constexpr int CDK = 64;

typedef _Float16 f16;
typedef __attribute__((ext_vector_type(8))) _Float16 f16x8;
typedef __attribute__((ext_vector_type(4))) _Float16 f16x4;
typedef __attribute__((ext_vector_type(4))) float f32x4;
typedef __attribute__((ext_vector_type(4))) unsigned int u32x4;
typedef __attribute__((ext_vector_type(2))) unsigned int u32x2;

__device__ inline f32x4 mfma16(f16x8 a, f16x8 b, f32x4 c) {
  return __builtin_amdgcn_mfma_f32_16x16x32_f16(a, b, c, 0, 0, 0);
}

// async global->LDS, 16B per lane; dest must be wave-uniform base + lane*16
__device__ inline void gld16(const void* g, void* l) {
  __builtin_amdgcn_global_load_lds(
      (const __attribute__((address_space(1))) void*)g,
      (__attribute__((address_space(3))) void*)l, 16, 0, 0);
}

// raw v_exp_f32 (2^x). libm exp2f costs ~10 extra VALU/call.
__device__ inline float fast_exp2(float x) {
#if __has_builtin(__builtin_amdgcn_exp2f)
  return __builtin_amdgcn_exp2f(x);
#else
  return __expf(x * 0.6931471805599453f);
#endif
}

// packed f32x2 -> f16x2 with round-to-nearest-even as a raw dword.
__device__ inline unsigned pack_rne(float a, float b) {
  union { f16 h[2]; unsigned u; } c;
  c.h[0] = (f16)a;
  c.h[1] = (f16)b;
  return c.u;
}

// 4x4 quad-transpose of two dwords via gfx950 permlane swaps.
// Rows (16-lane groups) in:  x=[X0,X1,X2,X3], y=[Y0,Y1,Y2,Y3]
// After p32 (dst-hi<->src-lo) + p16 (dst-odd<->src-even):
//   x=[X0,X2,Y0,Y2], y=[X1,X3,Y1,Y3].
// HAZARD NOTE (r1/r2 failure root cause): raw back-to-back permlane asm
// violates the "VALU write -> v_permlane* read needs a wait state" rule.
// The builtins let the compiler insert the required hazard nops.
__device__ inline void quad_transpose(unsigned& x, unsigned& y) {
#if __has_builtin(__builtin_amdgcn_permlane32_swap) && \
    __has_builtin(__builtin_amdgcn_permlane16_swap)
  u32x2 a = __builtin_amdgcn_permlane32_swap(x, y, false, false);
  u32x2 b = __builtin_amdgcn_permlane16_swap(a[0], a[1], false, false);
  x = b[0];
  y = b[1];
#else
  asm volatile(
      "s_nop 1\n\t"
      "v_permlane32_swap_b32 %0, %1\n\t"
      "s_nop 1\n\t"
      "v_permlane16_swap_b32 %0, %1\n\t"
      "s_nop 1"
      : "+v"(x), "+v"(y));
#endif
}

#define LOG2E 1.4426950408889634f

// ---------------------------------------------------------------------------
// prep: blocks 0..8191 cast x fp32->fp16; blocks 8192..8207 compute lens[b]
// and zero Vsum (ws is poisoned 0xAA).
// ---------------------------------------------------------------------------
__global__ __launch_bounds__(256) void prep_kernel(const float4* __restrict__ x,
                                                   f16x4* __restrict__ xh,
                                                   const int* __restrict__ mask,
                                                   int* __restrict__ lens,
                                                   float* __restrict__ Vsum) {
  const int bid = blockIdx.x, t = threadIdx.x;
  __shared__ int red[256];
  if (bid < 8192) {
    const int idx = bid * 256 + t;
    const float4 v = x[idx];
    f16x4 o;
    o[0] = (f16)v.x; o[1] = (f16)v.y; o[2] = (f16)v.z; o[3] = (f16)v.w;
    xh[idx] = o;
  } else {
    const int b = bid - 8192;
    const int g = b * 256 + t;
    Vsum[g * 2] = 0.f;
    Vsum[g * 2 + 1] = 0.f;
    int s = 0;
    for (int i = t; i < CS; i += 256) s += mask[b * CS + i];
    red[t] = s;
    __syncthreads();
    for (int off = 128; off > 0; off >>= 1) {
      if (t < off) red[t] += red[t + off];
      __syncthreads();
    }
    if (t == 0) lens[b] = red[0];
  }
}

// ---------------------------------------------------------------------------
// cast + transpose weights via LDS (coalesced fp32 reads).
// ---------------------------------------------------------------------------
__global__ __launch_bounds__(256) void cast_w_kernel(const float* __restrict__ Wq,
                                                     const float* __restrict__ Wk,
                                                     const float* __restrict__ Wv,
                                                     const float* __restrict__ Wout,
                                                     f16* __restrict__ wtAll) {
  const int y = blockIdx.y, kb = blockIdx.x, t = threadIdx.x;
  const int k0 = kb * 64;
  const float* src;
  int ldsrc;
  f16* dst;
  if (y < 24) {
    const int which = y >> 3, h = y & 7;
    const float* W = (which == 0) ? Wq : (which == 1) ? Wk : Wv;
    src = W + (size_t)h * 32768 + (size_t)k0 * 64;
    ldsrc = 64;
    dst = wtAll + (size_t)which * 262144 + (size_t)h * 32768;
  } else {
    const int c = y - 24;
    src = Wout + (size_t)k0 * 512 + c * 64;
    ldsrc = 512;
    dst = wtAll + (size_t)3 * 262144 + (size_t)c * 64 * 512;
  }

  __shared__ float Ts[64][68];
  {
    const int kr = t >> 4, cg = (t & 15) * 4;
#pragma unroll
    for (int rr = 0; rr < 4; ++rr) {
      const float4 v = *(const float4*)&src[(size_t)(rr * 16 + kr) * ldsrc + cg];
      Ts[rr * 16 + kr][cg] = v.x;
      Ts[rr * 16 + kr][cg + 1] = v.y;
      Ts[rr * 16 + kr][cg + 2] = v.z;
      Ts[rr * 16 + kr][cg + 3] = v.w;
    }
  }
  __syncthreads();
  {
    const int n = t >> 2, seg = t & 3;
    f16x8 a, b;
#pragma unroll
    for (int j = 0; j < 8; ++j) {
      a[j] = (f16)Ts[seg * 16 + j][n];
      b[j] = (f16)Ts[seg * 16 + 8 + j][n];
    }
    f16* d = &dst[(size_t)n * 512 + k0 + seg * 16];
    *(f16x8*)d = a;
    *(f16x8*)(d + 8) = b;
  }
}

// ---------------------------------------------------------------------------
// Fused QKV projection: 128x128 tile, BK=64, gld16 staging with XOR column
// swizzle. grid (12 col-tiles, 128 row-tiles). Q pre-scaled by
// log2e/sqrt(n[b]); epilogues via padded Ts union, coalesced. V: fp32 col
// sums -> Vsum.
// ---------------------------------------------------------------------------
__global__ __launch_bounds__(256) void qkvf_kernel(
    const f16* __restrict__ xh, const f16* __restrict__ wtAll,
    const int* __restrict__ lens, f16* __restrict__ Qh, f16* __restrict__ Kh,
    f16* __restrict__ Vth, float* __restrict__ Vsum) {
  const int ct = blockIdx.x, rt = blockIdx.y;
  const int which = ct >> 2, hp = ct & 3;
  const f16* Wt = wtAll + (size_t)which * 262144 + (size_t)hp * 65536;
  const int row0 = rt * 128;
  const int b = row0 >> 10, s0 = row0 & 1023;
  const int h0 = hp * 2;
  const int t = threadIdx.x;
  const int w = t >> 6, lane = t & 63, quad = lane >> 4, lcol = lane & 15;
  const int wr = w >> 1, wc = w & 1;

  __shared__ union SM {
    struct { f16 Xs[128][64]; f16 Ws[128][64]; } a;  // unpadded (lds-dma)
    f16 Ts[128][136];                                // epilogue staging
  } sm;

  f32x4 acc[4][4];
#pragma unroll
  for (int i = 0; i < 4; ++i)
#pragma unroll
    for (int j = 0; j < 4; ++j) acc[i][j] = (f32x4){0.f, 0.f, 0.f, 0.f};

  for (int k0 = 0; k0 < CHID; k0 += 64) {
    __syncthreads();  // prior compute's LDS reads done
#pragma unroll
    for (int i = 0; i < 4; ++i) {
      const int c = t + 256 * i, r = c >> 3, sg = c & 7;
      const int gsw = (sg ^ (r & 7)) * 8;  // XOR swizzle on global source
      gld16(&xh[(size_t)(row0 + r) * CHID + k0 + gsw],
            (char*)&sm.a.Xs[0][0] + c * 16);
      gld16(&Wt[(size_t)r * CHID + k0 + gsw], (char*)&sm.a.Ws[0][0] + c * 16);
    }
    __syncthreads();  // drains vmcnt: LDS tiles ready

    f16x8 bf0[4], bf1[4];
#pragma unroll
    for (int j = 0; j < 4; ++j) {
      const int br = wc * 64 + j * 16 + lcol;
      bf0[j] = *(const f16x8*)&sm.a.Ws[br][(quad ^ (br & 7)) * 8];
      bf1[j] = *(const f16x8*)&sm.a.Ws[br][((quad ^ 4) ^ (br & 7)) * 8];
    }
#pragma unroll
    for (int i = 0; i < 4; ++i) {
      const int ar = wr * 64 + i * 16 + lcol;
      const f16x8 af0 = *(const f16x8*)&sm.a.Xs[ar][(quad ^ (ar & 7)) * 8];
      const f16x8 af1 =
          *(const f16x8*)&sm.a.Xs[ar][((quad ^ 4) ^ (ar & 7)) * 8];
#pragma unroll
      for (int j = 0; j < 4; ++j) {
        acc[i][j] = mfma16(af0, bf0[j], acc[i][j]);
        acc[i][j] = mfma16(af1, bf1[j], acc[i][j]);
      }
    }
  }

  if (which == 2) {
    // fp32 column sums -> Vsum (quad-reduced, register-only)
#pragma unroll
    for (int j = 0; j < 4; ++j) {
      float ps = 0.f;
#pragma unroll
      for (int i = 0; i < 4; ++i)
#pragma unroll
        for (int rr = 0; rr < 4; ++rr) ps += acc[i][j][rr];
      ps += __shfl_xor(ps, 16);
      ps += __shfl_xor(ps, 32);
      if (quad == 0) {
        const int d128 = wc * 64 + j * 16 + lcol;
        const int h = h0 + (d128 >> 6), d = d128 & 63;
        atomicAdd(&Vsum[((size_t)b * CH + h) * CDK + d], ps);
      }
    }
    // Ts[n][s]: packed f16x4 transpose writes, then coalesced V^T stores
    __syncthreads();
#pragma unroll
    for (int i = 0; i < 4; ++i)
#pragma unroll
      for (int j = 0; j < 4; ++j) {
        f16x4 v4;
#pragma unroll
        for (int rr = 0; rr < 4; ++rr) v4[rr] = (f16)acc[i][j][rr];
        *(f16x4*)&sm.Ts[wc * 64 + j * 16 + lcol][wr * 64 + i * 16 + quad * 4] =
            v4;
      }
    __syncthreads();
    const int c16 = t & 15;
#pragma unroll
    for (int p = 0; p < 8; ++p) {
      const int vr = p * 16 + (t >> 4);
      const int h = h0 + (vr >> 6), d = vr & 63;
      *(f16x8*)&Vth[(((size_t)b * CH + h) * CDK + d) * CS + s0 + c16 * 8] =
          *(const f16x8*)&sm.Ts[vr][c16 * 8];
    }
  } else {
    // Ts[s][n], then coalesced [B,H,S,64] stores (128-B runs)
    const float qsc = (which == 0) ? rsqrtf((float)lens[b]) * LOG2E : 1.0f;
    __syncthreads();
#pragma unroll
    for (int i = 0; i < 4; ++i)
#pragma unroll
      for (int j = 0; j < 4; ++j)
#pragma unroll
        for (int rr = 0; rr < 4; ++rr)
          sm.Ts[wr * 64 + i * 16 + quad * 4 + rr][wc * 64 + j * 16 + lcol] =
              (f16)(acc[i][j][rr] * qsc);
    __syncthreads();
    f16* O = (which == 0) ? Qh : Kh;
    const int c8 = t & 7;
#pragma unroll
    for (int p = 0; p < 4; ++p) {
      const int row = p * 32 + (t >> 3);
#pragma unroll
      for (int half = 0; half < 2; ++half) {
        const int h = h0 + half;
        *(f16x8*)&O[(((size_t)b * CH + h) * CS + s0 + row) * CDK + c8 * 8] =
            *(const f16x8*)&sm.Ts[row][half * 64 + c8 * 8];
      }
    }
  }
}

// ---------------------------------------------------------------------------
// Attention (MFMA flash, v8 = direct-from-cache, no LDS in the k-loop):
//  * r6 evidence: v6 (16 w/CU) and v7 (8 w/CU, half LDS traffic) both 45.3us
//    with all pipes <40% -> serialized phase latency under barrier lockstep,
//    not any throughput limit. K/V per (b,h) = 256KB, L2-resident (r5:
//    FETCH 21MB); one 64x64 K+V tile = 16KB, fits 32KB L1. Staging
//    cache-resident data in LDS was pure overhead (guide mistake #7).
//  * K/V fragments read DIRECTLY from global in MFMA layout (16B/lane).
//    Loop has zero barriers, zero LDS ops, zero stores -> waves free-run,
//    compiler hoists loads arbitrarily early (all-const __restrict).
//  * Wave = 2 sets (32 q-rows), inner code identical to v5/v6 (verified):
//    swapped QK^T, RNE pack + permlane quad-transpose, MFMA row-sums,
//    tail-split masking.
//  * grid 1024 (16b x 8h x 8qt), 4-wave blocks; h = id&7 keeps XCD
//    affinity; a CU's 4 blocks mix b, b+4, b+8, b+12 (imbalance smoothing).
//    launch_bounds(256,3): >=12 waves/CU, VGPR cap ~170 (no spill).
//  * LDS: epilogue St only (18.4KB), wave-private, no barrier.
// ---------------------------------------------------------------------------
__global__ __launch_bounds__(256, 3) void attn_kernel(
    const f16* __restrict__ Qh, const f16* __restrict__ Kh,
    const f16* __restrict__ Vth, const int* __restrict__ lens,
    const float* __restrict__ Vsum, f16* __restrict__ Hbh) {
  const int id = blockIdx.x;
  const int h = id & 7;          // XCD index under %8 round-robin
  const int rest = id >> 3;      // 0..127
  const int qt = rest & 7;
  const int b = rest >> 3;
  const int n = lens[b];
  const int t = threadIdx.x, w = t >> 6, lane = t & 63, quad = lane >> 4,
            lcol = lane & 15;

  const size_t bh = ((size_t)b * CH + h) * CS;
  const size_t bhd = ((size_t)b * CH + h) * CDK;

  const int nt = (n + 63) >> 6;
  const int rem = n & 63;
  const int ntm = rem ? nt - 1 : nt;  // unmasked main tiles

  __shared__ f16 St[4][32][72];  // epilogue staging only (wave-private)

  const int qbase = qt * 128 + w * 32;
  f16x8 qa[2][2];
#pragma unroll
  for (int set = 0; set < 2; ++set) {
    const size_t qr = bh + qbase + set * 16 + lcol;
    qa[set][0] = *(const f16x8*)&Qh[qr * CDK + quad * 8];
    qa[set][1] = *(const f16x8*)&Qh[qr * CDK + 32 + quad * 8];
  }

  f16x8 vones;
#pragma unroll
  for (int j = 0; j < 8; ++j) vones[j] = (f16)1.0f;

  f32x4 o[2][4];
#pragma unroll
  for (int set = 0; set < 2; ++set)
#pragma unroll
    for (int dt = 0; dt < 4; ++dt) o[set][dt] = (f32x4){0.f, 0.f, 0.f, 0.f};
  f32x4 o_l[2] = {(f32x4){0.f, 0.f, 0.f, 0.f}, (f32x4){0.f, 0.f, 0.f, 0.f}};

  // per-lane fragment base addresses (advance by 64 rows / 64 cols per tile)
  const f16* Kp = &Kh[(bh + lcol) * CDK + quad * 8];       // + ct*16*CDK
  const f16* Vp = &Vth[(bhd + lcol) * CS + quad * 8];      // + dt*16*CS + kt*64

  auto ktile = [&](const int kt, const bool masked) __attribute__((always_inline)) {
    // K fragments direct from global (L1/L2-resident), MFMA B-layout
    const f16* Kt = Kp + (size_t)kt * 64 * CDK;
    f16x8 kb[4][2];
#pragma unroll
    for (int ct = 0; ct < 4; ++ct) {
      kb[ct][0] = *(const f16x8*)(Kt + (size_t)ct * 16 * CDK);
      kb[ct][1] = *(const f16x8*)(Kt + (size_t)ct * 16 * CDK + 32);
    }

    // swapped QK^T + exp + in-register P->A-frag transpose
    f16x8 pa[2][2];
#pragma unroll
    for (int set = 0; set < 2; ++set) {
      f32x4 st[4];
#pragma unroll
      for (int ct = 0; ct < 4; ++ct) {
        st[ct] = mfma16(kb[ct][0], qa[set][0], (f32x4){0.f, 0.f, 0.f, 0.f});
        st[ct] = mfma16(kb[ct][1], qa[set][1], st[ct]);
      }
      unsigned pkd[4][2];
#pragma unroll
      for (int c = 0; c < 4; ++c) {
        float p[4];
#pragma unroll
        for (int r = 0; r < 4; ++r) {
          float e = fast_exp2(st[c][r]);
          if (masked) {
            const bool kvld = (kt * 64 + c * 16 + quad * 4 + r) < n;
            e = kvld ? e : 0.f;
          }
          p[r] = e;
        }
        pkd[c][0] = pack_rne(p[0], p[1]);
        pkd[c][1] = pack_rne(p[2], p[3]);
      }
      // quad-transpose: target quad t's dword j2 ends at k = 8t + 2*j2 + {0,1}
#pragma unroll
      for (int half = 0; half < 2; ++half) {
        unsigned x0 = pkd[2 * half][0], y0 = pkd[2 * half + 1][0];
        unsigned x1 = pkd[2 * half][1], y1 = pkd[2 * half + 1][1];
        quad_transpose(x0, y0);
        quad_transpose(x1, y1);
        union { u32x4 u; f16x8 h; } cc;
        cc.u = (u32x4){x0, x1, y0, y1};
        pa[set][half] = cc.h;
      }
    }

    // PV + row-sum MFMAs; V fragments direct from global (V^T layout)
    const f16* Vt = Vp + (size_t)kt * 64;
#pragma unroll
    for (int dt = 0; dt < 4; ++dt) {
      const f16x8 vb0 = *(const f16x8*)(Vt + (size_t)dt * 16 * CS);
      const f16x8 vb1 = *(const f16x8*)(Vt + (size_t)dt * 16 * CS + 32);
#pragma unroll
      for (int set = 0; set < 2; ++set) {
        o[set][dt] = mfma16(pa[set][0], vb0, o[set][dt]);
        o[set][dt] = mfma16(pa[set][1], vb1, o[set][dt]);
      }
    }
#pragma unroll
    for (int set = 0; set < 2; ++set) {
      o_l[set] = mfma16(pa[set][0], vones, o_l[set]);
      o_l[set] = mfma16(pa[set][1], vones, o_l[set]);
    }
  };

  int kt = 0;
  for (; kt < ntm; ++kt) ktile(kt, false);
  if (rem) ktile(kt, true);

  // per-lane inverse row-sums (already in O-layout: row quad*4+r, any col)
  float invl[2][4];
#pragma unroll
  for (int set = 0; set < 2; ++set)
#pragma unroll
    for (int r = 0; r < 4; ++r) invl[set][r] = 1.0f / o_l[set][r];

  // O -> wave-private St (f16), then coalesced 128-B-run stores (no barrier:
  // same-wave ds_write -> ds_read is program-ordered via lgkmcnt)
#pragma unroll
  for (int set = 0; set < 2; ++set)
#pragma unroll
    for (int dt = 0; dt < 4; ++dt)
#pragma unroll
      for (int r = 0; r < 4; ++r) {
        const int srow_l = set * 16 + quad * 4 + r;
        const int d = dt * 16 + lcol;
        const float val = (qbase + srow_l < n)
                              ? o[set][dt][r] * invl[set][r]
                              : Vsum[bhd + d] * (1.0f / 1024.0f);
        St[w][srow_l][d] = (f16)val;
      }
  {
    const int lr = lane >> 3, lc = lane & 7;
#pragma unroll
    for (int p = 0; p < 4; ++p) {
      const int row = p * 8 + lr;
      *(f16x8*)&Hbh[((size_t)b * CS + qbase + row) * (CH * CDK) + h * CDK +
                    lc * 8] = *(const f16x8*)&St[w][row][lc * 8];
    }
  }
}

// ---------------------------------------------------------------------------
// Output projection: 128x128 tile, BK=64, gld16 + XOR swizzle (as qkvf).
// grid (128 row-tiles, 4 col-tiles), block 256.
// ---------------------------------------------------------------------------
__global__ __launch_bounds__(256) void outp_kernel(const f16* __restrict__ Hbh,
                                                   const f16* __restrict__ woutt,
                                                   float* __restrict__ out) {
  const int rt = blockIdx.x, ctile = blockIdx.y;
  const int row0 = rt * 128, col0 = ctile * 128;
  const f16* Wt = woutt + (size_t)col0 * CHID;
  const int t = threadIdx.x;
  const int w = t >> 6, lane = t & 63, quad = lane >> 4, lcol = lane & 15;
  const int wr = w >> 1, wc = w & 1;

  __shared__ f16 Hs[128][64];  // unpadded (lds-dma), XOR-swizzled columns
  __shared__ f16 Ws[128][64];

  f32x4 acc[4][4];
#pragma unroll
  for (int i = 0; i < 4; ++i)
#pragma unroll
    for (int j = 0; j < 4; ++j) acc[i][j] = (f32x4){0.f, 0.f, 0.f, 0.f};

  for (int k0 = 0; k0 < CHID; k0 += 64) {
    __syncthreads();
#pragma unroll
    for (int i = 0; i < 4; ++i) {
      const int c = t + 256 * i, r = c >> 3, sg = c & 7;
      const int gsw = (sg ^ (r & 7)) * 8;
      gld16(&Hbh[(size_t)(row0 + r) * CHID + k0 + gsw],
            (char*)&Hs[0][0] + c * 16);
      gld16(&Wt[(size_t)r * CHID + k0 + gsw], (char*)&Ws[0][0] + c * 16);
    }
    __syncthreads();

    f16x8 bf0[4], bf1[4];
#pragma unroll
    for (int j = 0; j < 4; ++j) {
      const int br = wc * 64 + j * 16 + lcol;
      bf0[j] = *(const f16x8*)&Ws[br][(quad ^ (br & 7)) * 8];
      bf1[j] = *(const f16x8*)&Ws[br][((quad ^ 4) ^ (br & 7)) * 8];
    }
#pragma unroll
    for (int i = 0; i < 4; ++i) {
      const int ar = wr * 64 + i * 16 + lcol;
      const f16x8 af0 = *(const f16x8*)&Hs[ar][(quad ^ (ar & 7)) * 8];
      const f16x8 af1 = *(const f16x8*)&Hs[ar][((quad ^ 4) ^ (ar & 7)) * 8];
#pragma unroll
      for (int j = 0; j < 4; ++j) {
        acc[i][j] = mfma16(af0, bf0[j], acc[i][j]);
        acc[i][j] = mfma16(af1, bf1[j], acc[i][j]);
      }
    }
  }

#pragma unroll
  for (int i = 0; i < 4; ++i) {
#pragma unroll
    for (int rr = 0; rr < 4; ++rr) {
      const size_t rg = row0 + wr * 64 + i * 16 + quad * 4 + rr;
#pragma unroll
      for (int j = 0; j < 4; ++j)
        out[rg * CHID + col0 + wc * 64 + j * 16 + lcol] = acc[i][j][rr];
    }
  }
}

// ---------------------------------------------------------------------------
extern "C" void kernel_launch(void* const* d_in, const int* in_sizes, int n_in,
                              void* d_out, int out_size, void* d_ws,
                              size_t ws_size, hipStream_t stream) {
  const float* x = (const float*)d_in[0];
  const int* mask = (const int*)d_in[1];
  const float* Wq = (const float*)d_in[2];
  const float* Wk = (const float*)d_in[3];
  const float* Wv = (const float*)d_in[4];
  const float* Wout = (const float*)d_in[5];
  float* out = (float*)d_out;

  char* ws = (char*)d_ws;
  int* lens = (int*)ws;
  size_t off = 1024;
  const size_t NX = (size_t)CB * CS * CHID;   // 8,388,608
  const size_t NW = (size_t)CH * CHID * CDK;  // 262,144 per weight
  f16* xh = (f16*)(ws + off);    off += NX * 2;
  f16* wtAll = (f16*)(ws + off); off += NW * 4 * 2;
  f16* Qh = (f16*)(ws + off);    off += NX * 2;
  f16* Kh = (f16*)(ws + off);    off += NX * 2;
  f16* Vth = (f16*)(ws + off);   off += NX * 2;
  f16* Hbh = (f16*)(ws + off);   off += NX * 2;
  float* Vsum = (float*)(ws + off); off += (size_t)CB * CH * CDK * 4;
  f16* woutt = wtAll + NW * 3;

  prep_kernel<<<8208, 256, 0, stream>>>((const float4*)x, (f16x4*)xh, mask,
                                        lens, Vsum);
  cast_w_kernel<<<dim3(8, 32), 256, 0, stream>>>(Wq, Wk, Wv, Wout, wtAll);
  qkvf_kernel<<<dim3(12, 128), 256, 0, stream>>>(xh, wtAll, lens, Qh, Kh, Vth,
                                                 Vsum);
  attn_kernel<<<1024, 256, 0, stream>>>(Qh, Kh, Vth, lens, Vsum, Hbh);
  outp_kernel<<<dim3(128, 4), 256, 0, stream>>>(Hbh, woutt, out);
}

// Round 9
// 225.671 us; speedup vs baseline: 1.0977x; 1.0977x over previous
//
#include <hip/hip_runtime.h>
#include <math.h>

// QANetAttBlock: B=16, S=1024, HID=512, H=8, DK=64
constexpr int CB = 16;
constexpr int CS = 1024;
constexpr int CHID = 512;
constexpr int CH = 8;
constexpr int CDK = 64;

typedef _Float16 f16;
typedef __attribute__((ext_vector_type(8))) _Float16 f16x8;
typedef __attribute__((ext_vector_type(4))) _Float16 f16x4;
typedef __attribute__((ext_vector_type(4))) float f32x4;
typedef __attribute__((ext_vector_type(4))) unsigned int u32x4;
typedef __attribute__((ext_vector_type(2))) unsigned int u32x2;

__device__ inline f32x4 mfma16(f16x8 a, f16x8 b, f32x4 c) {
  return __builtin_amdgcn_mfma_f32_16x16x32_f16(a, b, c, 0, 0, 0);
}

// async global->LDS, 16B per lane; dest must be wave-uniform base + lane*16
__device__ inline void gld16(const void* g, void* l) {
  __builtin_amdgcn_global_load_lds(
      (const __attribute__((address_space(1))) void*)g,
      (__attribute__((address_space(3))) void*)l, 16, 0, 0);
}

// raw v_exp_f32 (2^x). libm exp2f costs ~10 extra VALU/call.
__device__ inline float fast_exp2(float x) {
#if __has_builtin(__builtin_amdgcn_exp2f)
  return __builtin_amdgcn_exp2f(x);
#else
  return __expf(x * 0.6931471805599453f);
#endif
}

// packed f32x2 -> f16x2 with round-to-nearest-even as a raw dword.
__device__ inline unsigned pack_rne(float a, float b) {
  union { f16 h[2]; unsigned u; } c;
  c.h[0] = (f16)a;
  c.h[1] = (f16)b;
  return c.u;
}

// 4x4 quad-transpose of two dwords via gfx950 permlane swaps.
// Rows (16-lane groups) in:  x=[X0,X1,X2,X3], y=[Y0,Y1,Y2,Y3]
// After p32 (dst-hi<->src-lo) + p16 (dst-odd<->src-even):
//   x=[X0,X2,Y0,Y2], y=[X1,X3,Y1,Y3].
// HAZARD NOTE (r1/r2 failure root cause): raw back-to-back permlane asm
// violates the "VALU write -> v_permlane* read needs a wait state" rule.
// The builtins let the compiler insert the required hazard nops.
__device__ inline void quad_transpose(unsigned& x, unsigned& y) {
#if __has_builtin(__builtin_amdgcn_permlane32_swap) && \
    __has_builtin(__builtin_amdgcn_permlane16_swap)
  u32x2 a = __builtin_amdgcn_permlane32_swap(x, y, false, false);
  u32x2 b = __builtin_amdgcn_permlane16_swap(a[0], a[1], false, false);
  x = b[0];
  y = b[1];
#else
  asm volatile(
      "s_nop 1\n\t"
      "v_permlane32_swap_b32 %0, %1\n\t"
      "s_nop 1\n\t"
      "v_permlane16_swap_b32 %0, %1\n\t"
      "s_nop 1"
      : "+v"(x), "+v"(y));
#endif
}

#define LOG2E 1.4426950408889634f

// ---------------------------------------------------------------------------
// prep: blocks 0..8191 cast x fp32->fp16; blocks 8192..8207 compute lens[b]
// and zero Vsum (ws is poisoned 0xAA).
// ---------------------------------------------------------------------------
__global__ __launch_bounds__(256) void prep_kernel(const float4* __restrict__ x,
                                                   f16x4* __restrict__ xh,
                                                   const int* __restrict__ mask,
                                                   int* __restrict__ lens,
                                                   float* __restrict__ Vsum) {
  const int bid = blockIdx.x, t = threadIdx.x;
  __shared__ int red[256];
  if (bid < 8192) {
    const int idx = bid * 256 + t;
    const float4 v = x[idx];
    f16x4 o;
    o[0] = (f16)v.x; o[1] = (f16)v.y; o[2] = (f16)v.z; o[3] = (f16)v.w;
    xh[idx] = o;
  } else {
    const int b = bid - 8192;
    const int g = b * 256 + t;
    Vsum[g * 2] = 0.f;
    Vsum[g * 2 + 1] = 0.f;
    int s = 0;
    for (int i = t; i < CS; i += 256) s += mask[b * CS + i];
    red[t] = s;
    __syncthreads();
    for (int off = 128; off > 0; off >>= 1) {
      if (t < off) red[t] += red[t + off];
      __syncthreads();
    }
    if (t == 0) lens[b] = red[0];
  }
}

// ---------------------------------------------------------------------------
// cast + transpose weights via LDS (coalesced fp32 reads).
// ---------------------------------------------------------------------------
__global__ __launch_bounds__(256) void cast_w_kernel(const float* __restrict__ Wq,
                                                     const float* __restrict__ Wk,
                                                     const float* __restrict__ Wv,
                                                     const float* __restrict__ Wout,
                                                     f16* __restrict__ wtAll) {
  const int y = blockIdx.y, kb = blockIdx.x, t = threadIdx.x;
  const int k0 = kb * 64;
  const float* src;
  int ldsrc;
  f16* dst;
  if (y < 24) {
    const int which = y >> 3, h = y & 7;
    const float* W = (which == 0) ? Wq : (which == 1) ? Wk : Wv;
    src = W + (size_t)h * 32768 + (size_t)k0 * 64;
    ldsrc = 64;
    dst = wtAll + (size_t)which * 262144 + (size_t)h * 32768;
  } else {
    const int c = y - 24;
    src = Wout + (size_t)k0 * 512 + c * 64;
    ldsrc = 512;
    dst = wtAll + (size_t)3 * 262144 + (size_t)c * 64 * 512;
  }

  __shared__ float Ts[64][68];
  {
    const int kr = t >> 4, cg = (t & 15) * 4;
#pragma unroll
    for (int rr = 0; rr < 4; ++rr) {
      const float4 v = *(const float4*)&src[(size_t)(rr * 16 + kr) * ldsrc + cg];
      Ts[rr * 16 + kr][cg] = v.x;
      Ts[rr * 16 + kr][cg + 1] = v.y;
      Ts[rr * 16 + kr][cg + 2] = v.z;
      Ts[rr * 16 + kr][cg + 3] = v.w;
    }
  }
  __syncthreads();
  {
    const int n = t >> 2, seg = t & 3;
    f16x8 a, b;
#pragma unroll
    for (int j = 0; j < 8; ++j) {
      a[j] = (f16)Ts[seg * 16 + j][n];
      b[j] = (f16)Ts[seg * 16 + 8 + j][n];
    }
    f16* d = &dst[(size_t)n * 512 + k0 + seg * 16];
    *(f16x8*)d = a;
    *(f16x8*)(d + 8) = b;
  }
}

// ---------------------------------------------------------------------------
// Fused QKV projection: 128x128 tile, BK=64, gld16 staging with XOR column
// swizzle. grid (12 col-tiles, 128 row-tiles). Q pre-scaled by
// log2e/sqrt(n[b]); epilogues via padded Ts union, coalesced. V: fp32 col
// sums -> Vsum.
// ---------------------------------------------------------------------------
__global__ __launch_bounds__(256) void qkvf_kernel(
    const f16* __restrict__ xh, const f16* __restrict__ wtAll,
    const int* __restrict__ lens, f16* __restrict__ Qh, f16* __restrict__ Kh,
    f16* __restrict__ Vth, float* __restrict__ Vsum) {
  const int ct = blockIdx.x, rt = blockIdx.y;
  const int which = ct >> 2, hp = ct & 3;
  const f16* Wt = wtAll + (size_t)which * 262144 + (size_t)hp * 65536;
  const int row0 = rt * 128;
  const int b = row0 >> 10, s0 = row0 & 1023;
  const int h0 = hp * 2;
  const int t = threadIdx.x;
  const int w = t >> 6, lane = t & 63, quad = lane >> 4, lcol = lane & 15;
  const int wr = w >> 1, wc = w & 1;

  __shared__ union SM {
    struct { f16 Xs[128][64]; f16 Ws[128][64]; } a;  // unpadded (lds-dma)
    f16 Ts[128][136];                                // epilogue staging
  } sm;

  f32x4 acc[4][4];
#pragma unroll
  for (int i = 0; i < 4; ++i)
#pragma unroll
    for (int j = 0; j < 4; ++j) acc[i][j] = (f32x4){0.f, 0.f, 0.f, 0.f};

  for (int k0 = 0; k0 < CHID; k0 += 64) {
    __syncthreads();  // prior compute's LDS reads done
#pragma unroll
    for (int i = 0; i < 4; ++i) {
      const int c = t + 256 * i, r = c >> 3, sg = c & 7;
      const int gsw = (sg ^ (r & 7)) * 8;  // XOR swizzle on global source
      gld16(&xh[(size_t)(row0 + r) * CHID + k0 + gsw],
            (char*)&sm.a.Xs[0][0] + c * 16);
      gld16(&Wt[(size_t)r * CHID + k0 + gsw], (char*)&sm.a.Ws[0][0] + c * 16);
    }
    __syncthreads();  // drains vmcnt: LDS tiles ready

    f16x8 bf0[4], bf1[4];
#pragma unroll
    for (int j = 0; j < 4; ++j) {
      const int br = wc * 64 + j * 16 + lcol;
      bf0[j] = *(const f16x8*)&sm.a.Ws[br][(quad ^ (br & 7)) * 8];
      bf1[j] = *(const f16x8*)&sm.a.Ws[br][((quad ^ 4) ^ (br & 7)) * 8];
    }
#pragma unroll
    for (int i = 0; i < 4; ++i) {
      const int ar = wr * 64 + i * 16 + lcol;
      const f16x8 af0 = *(const f16x8*)&sm.a.Xs[ar][(quad ^ (ar & 7)) * 8];
      const f16x8 af1 =
          *(const f16x8*)&sm.a.Xs[ar][((quad ^ 4) ^ (ar & 7)) * 8];
#pragma unroll
      for (int j = 0; j < 4; ++j) {
        acc[i][j] = mfma16(af0, bf0[j], acc[i][j]);
        acc[i][j] = mfma16(af1, bf1[j], acc[i][j]);
      }
    }
  }

  if (which == 2) {
    // fp32 column sums -> Vsum (quad-reduced, register-only)
#pragma unroll
    for (int j = 0; j < 4; ++j) {
      float ps = 0.f;
#pragma unroll
      for (int i = 0; i < 4; ++i)
#pragma unroll
        for (int rr = 0; rr < 4; ++rr) ps += acc[i][j][rr];
      ps += __shfl_xor(ps, 16);
      ps += __shfl_xor(ps, 32);
      if (quad == 0) {
        const int d128 = wc * 64 + j * 16 + lcol;
        const int h = h0 + (d128 >> 6), d = d128 & 63;
        atomicAdd(&Vsum[((size_t)b * CH + h) * CDK + d], ps);
      }
    }
    // Ts[n][s]: packed f16x4 transpose writes, then coalesced V^T stores
    __syncthreads();
#pragma unroll
    for (int i = 0; i < 4; ++i)
#pragma unroll
      for (int j = 0; j < 4; ++j) {
        f16x4 v4;
#pragma unroll
        for (int rr = 0; rr < 4; ++rr) v4[rr] = (f16)acc[i][j][rr];
        *(f16x4*)&sm.Ts[wc * 64 + j * 16 + lcol][wr * 64 + i * 16 + quad * 4] =
            v4;
      }
    __syncthreads();
    const int c16 = t & 15;
#pragma unroll
    for (int p = 0; p < 8; ++p) {
      const int vr = p * 16 + (t >> 4);
      const int h = h0 + (vr >> 6), d = vr & 63;
      *(f16x8*)&Vth[(((size_t)b * CH + h) * CDK + d) * CS + s0 + c16 * 8] =
          *(const f16x8*)&sm.Ts[vr][c16 * 8];
    }
  } else {
    // Ts[s][n], then coalesced [B,H,S,64] stores (128-B runs)
    const float qsc = (which == 0) ? rsqrtf((float)lens[b]) * LOG2E : 1.0f;
    __syncthreads();
#pragma unroll
    for (int i = 0; i < 4; ++i)
#pragma unroll
      for (int j = 0; j < 4; ++j)
#pragma unroll
        for (int rr = 0; rr < 4; ++rr)
          sm.Ts[wr * 64 + i * 16 + quad * 4 + rr][wc * 64 + j * 16 + lcol] =
              (f16)(acc[i][j][rr] * qsc);
    __syncthreads();
    f16* O = (which == 0) ? Qh : Kh;
    const int c8 = t & 7;
#pragma unroll
    for (int p = 0; p < 4; ++p) {
      const int row = p * 32 + (t >> 3);
#pragma unroll
      for (int half = 0; half < 2; ++half) {
        const int h = h0 + half;
        *(f16x8*)&O[(((size_t)b * CH + h) * CS + s0 + row) * CDK + c8 * 8] =
            *(const f16x8*)&sm.Ts[row][half * 64 + c8 * 8];
      }
    }
  }
}

// ---------------------------------------------------------------------------
// Attention (MFMA flash, v9 = v6 structure @ 128-row blocks + balance + T5):
//  * r8 lesson: direct-from-cache V gathers = 64 cache lines/instr -> TA
//    transaction storm (45->106us). LDS staging restored (v6/v7 structure,
//    byte-identical verified inner code: swapped QK^T, RNE pack + permlane
//    quad-transpose, MFMA row-sums, tail-split masking, kb-hoist, dbuf,
//    1 barrier/tile).
//  * 128-row blocks, 4 waves, 2 sets/wave; grid 1024 -> 4 blocks/CU
//    (LDS 4x36.9=147KB<160, VGPR ~70<128 w/ launch_bounds(256,4)) = 16
//    waves/CU ceiling (v6/v7 had 2 blocks/CU, occ 13.4%). Four INDEPENDENT
//    blocks per CU overlap each other's lockstep phases.
//  * balance decode: h=id&7 (XCD), b=(id>>3)&15 fastest -> each CU's 4
//    resident blocks mix 4 different n (lens spread 512..1024) -> tail cut.
//  * T5 s_setprio(1) around MFMA clusters: pays only with phase-diverse
//    waves (guide m191) -- which 4 blocks/CU now provides.
// ---------------------------------------------------------------------------
__global__ __launch_bounds__(256, 4) void attn_kernel(
    const f16* __restrict__ Qh, const f16* __restrict__ Kh,
    const f16* __restrict__ Vth, const int* __restrict__ lens,
    const float* __restrict__ Vsum, f16* __restrict__ Hbh) {
  const int id = blockIdx.x;
  const int h = id & 7;            // XCD index under %8 round-robin
  const int b = (id >> 3) & 15;    // fastest-varying on an XCD: n-mix per CU
  const int qt = id >> 7;          // 0..7
  const int n = lens[b];
  const int t = threadIdx.x, w = t >> 6, lane = t & 63, quad = lane >> 4,
            lcol = lane & 15;

  const size_t bh = ((size_t)b * CH + h) * CS;
  const size_t bhd = ((size_t)b * CH + h) * CDK;

  const int nt = (n + 63) >> 6;
  const int rem = n & 63;
  const int ntm = rem ? nt - 1 : nt;  // unmasked main tiles

  __shared__ union SM {
    struct { f16 Ks[2][64][72]; f16 Vs[2][64][72]; } kv;  // [buf][k|d][d|k]
    f16 St[4][32][72];  // epilogue staging (post-loop reuse)
  } sm;

  const int qbase = qt * 128 + w * 32;
  f16x8 qa[2][2];
#pragma unroll
  for (int set = 0; set < 2; ++set) {
    const size_t qr = bh + qbase + set * 16 + lcol;
    qa[set][0] = *(const f16x8*)&Qh[qr * CDK + quad * 8];
    qa[set][1] = *(const f16x8*)&Qh[qr * CDK + 32 + quad * 8];
  }

  f16x8 vones;
#pragma unroll
  for (int j = 0; j < 8; ++j) vones[j] = (f16)1.0f;

  f32x4 o[2][4];
#pragma unroll
  for (int set = 0; set < 2; ++set)
#pragma unroll
    for (int dt = 0; dt < 4; ++dt) o[set][dt] = (f32x4){0.f, 0.f, 0.f, 0.f};
  f32x4 o_l[2] = {(f32x4){0.f, 0.f, 0.f, 0.f}, (f32x4){0.f, 0.f, 0.f, 0.f}};

  // tile 0: load + stage into buffer 0
  f16x8 pk[2], pv[2];
#pragma unroll
  for (int i = 0; i < 2; ++i) {
    const int c = t + 256 * i, r = c >> 3, sg = c & 7;
    pk[i] = *(const f16x8*)&Kh[(bh + r) * CDK + sg * 8];
    pv[i] = *(const f16x8*)&Vth[(bhd + r) * CS + sg * 8];
  }
#pragma unroll
  for (int i = 0; i < 2; ++i) {
    const int c = t + 256 * i, r = c >> 3, sg = c & 7;
    *(f16x8*)&sm.kv.Ks[0][r][sg * 8] = pk[i];
    *(f16x8*)&sm.kv.Vs[0][r][sg * 8] = pv[i];
  }
  __syncthreads();

  auto ktile = [&](const int kt, const bool masked) __attribute__((always_inline)) {
    const int cur = kt & 1, nxt = cur ^ 1;
    // prefetch next tile into regs (clamped; uniform straight-line code)
    const int ktn = (kt + 1 < nt) ? kt + 1 : kt;
#pragma unroll
    for (int i = 0; i < 2; ++i) {
      const int c = t + 256 * i, r = c >> 3, sg = c & 7;
      pk[i] = *(const f16x8*)&Kh[(bh + ktn * 64 + r) * CDK + sg * 8];
      pv[i] = *(const f16x8*)&Vth[(bhd + r) * CS + ktn * 64 + sg * 8];
    }

    // K fragments: loaded ONCE, shared by both sets (set-independent)
    f16x8 kb[4][2];
#pragma unroll
    for (int ct = 0; ct < 4; ++ct) {
      kb[ct][0] = *(const f16x8*)&sm.kv.Ks[cur][ct * 16 + lcol][quad * 8];
      kb[ct][1] = *(const f16x8*)&sm.kv.Ks[cur][ct * 16 + lcol][32 + quad * 8];
    }

    // swapped QK^T + exp + in-register P->A-frag transpose
    f16x8 pa[2][2];
#pragma unroll
    for (int set = 0; set < 2; ++set) {
      f32x4 st[4];
      __builtin_amdgcn_s_setprio(1);
#pragma unroll
      for (int ct = 0; ct < 4; ++ct) {
        st[ct] = mfma16(kb[ct][0], qa[set][0], (f32x4){0.f, 0.f, 0.f, 0.f});
        st[ct] = mfma16(kb[ct][1], qa[set][1], st[ct]);
      }
      __builtin_amdgcn_s_setprio(0);
      unsigned pkd[4][2];
#pragma unroll
      for (int c = 0; c < 4; ++c) {
        float p[4];
#pragma unroll
        for (int r = 0; r < 4; ++r) {
          float e = fast_exp2(st[c][r]);
          if (masked) {
            const bool kvld = (kt * 64 + c * 16 + quad * 4 + r) < n;
            e = kvld ? e : 0.f;
          }
          p[r] = e;
        }
        pkd[c][0] = pack_rne(p[0], p[1]);
        pkd[c][1] = pack_rne(p[2], p[3]);
      }
      // quad-transpose: target quad t's dword j2 ends at k = 8t + 2*j2 + {0,1}
#pragma unroll
      for (int half = 0; half < 2; ++half) {
        unsigned x0 = pkd[2 * half][0], y0 = pkd[2 * half + 1][0];
        unsigned x1 = pkd[2 * half][1], y1 = pkd[2 * half + 1][1];
        quad_transpose(x0, y0);
        quad_transpose(x1, y1);
        union { u32x4 u; f16x8 h; } cc;
        cc.u = (u32x4){x0, x1, y0, y1};
        pa[set][half] = cc.h;
      }
    }

    // PV + row-sum MFMAs (P x ones = rowsum, lands directly in O-layout)
    __builtin_amdgcn_s_setprio(1);
#pragma unroll
    for (int dt = 0; dt < 4; ++dt) {
      const f16x8 vb0 = *(const f16x8*)&sm.kv.Vs[cur][dt * 16 + lcol][quad * 8];
      const f16x8 vb1 =
          *(const f16x8*)&sm.kv.Vs[cur][dt * 16 + lcol][32 + quad * 8];
#pragma unroll
      for (int set = 0; set < 2; ++set) {
        o[set][dt] = mfma16(pa[set][0], vb0, o[set][dt]);
        o[set][dt] = mfma16(pa[set][1], vb1, o[set][dt]);
      }
    }
#pragma unroll
    for (int set = 0; set < 2; ++set) {
      o_l[set] = mfma16(pa[set][0], vones, o_l[set]);
      o_l[set] = mfma16(pa[set][1], vones, o_l[set]);
    }
    __builtin_amdgcn_s_setprio(0);

    // stage next tile into the other buffer; one barrier covers both
    // write-visibility (buf nxt) and read-completion (buf cur)
#pragma unroll
    for (int i = 0; i < 2; ++i) {
      const int c = t + 256 * i, r = c >> 3, sg = c & 7;
      *(f16x8*)&sm.kv.Ks[nxt][r][sg * 8] = pk[i];
      *(f16x8*)&sm.kv.Vs[nxt][r][sg * 8] = pv[i];
    }
    __syncthreads();
  };

  int kt = 0;
  for (; kt < ntm; ++kt) ktile(kt, false);
  if (rem) ktile(kt, true);

  // per-lane inverse row-sums (already in O-layout: row quad*4+r, any col)
  float invl[2][4];
#pragma unroll
  for (int set = 0; set < 2; ++set)
#pragma unroll
    for (int r = 0; r < 4; ++r) invl[set][r] = 1.0f / o_l[set][r];

  // O -> wave-private St (f16), then coalesced 128-B-run stores.
  // (final loop barrier already fenced all K/V reads; St aliases kv)
#pragma unroll
  for (int set = 0; set < 2; ++set)
#pragma unroll
    for (int dt = 0; dt < 4; ++dt)
#pragma unroll
      for (int r = 0; r < 4; ++r) {
        const int srow_l = set * 16 + quad * 4 + r;
        const int d = dt * 16 + lcol;
        const float val = (qbase + srow_l < n)
                              ? o[set][dt][r] * invl[set][r]
                              : Vsum[bhd + d] * (1.0f / 1024.0f);
        sm.St[w][srow_l][d] = (f16)val;
      }
  {
    const int lr = lane >> 3, lc = lane & 7;
#pragma unroll
    for (int p = 0; p < 4; ++p) {
      const int row = p * 8 + lr;
      *(f16x8*)&Hbh[((size_t)b * CS + qbase + row) * (CH * CDK) + h * CDK +
                    lc * 8] = *(const f16x8*)&sm.St[w][row][lc * 8];
    }
  }
}

// ---------------------------------------------------------------------------
// Output projection: 128x128 tile, BK=64, gld16 + XOR swizzle (as qkvf).
// grid (128 row-tiles, 4 col-tiles), block 256.
// ---------------------------------------------------------------------------
__global__ __launch_bounds__(256) void outp_kernel(const f16* __restrict__ Hbh,
                                                   const f16* __restrict__ woutt,
                                                   float* __restrict__ out) {
  const int rt = blockIdx.x, ctile = blockIdx.y;
  const int row0 = rt * 128, col0 = ctile * 128;
  const f16* Wt = woutt + (size_t)col0 * CHID;
  const int t = threadIdx.x;
  const int w = t >> 6, lane = t & 63, quad = lane >> 4, lcol = lane & 15;
  const int wr = w >> 1, wc = w & 1;

  __shared__ f16 Hs[128][64];  // unpadded (lds-dma), XOR-swizzled columns
  __shared__ f16 Ws[128][64];

  f32x4 acc[4][4];
#pragma unroll
  for (int i = 0; i < 4; ++i)
#pragma unroll
    for (int j = 0; j < 4; ++j) acc[i][j] = (f32x4){0.f, 0.f, 0.f, 0.f};

  for (int k0 = 0; k0 < CHID; k0 += 64) {
    __syncthreads();
#pragma unroll
    for (int i = 0; i < 4; ++i) {
      const int c = t + 256 * i, r = c >> 3, sg = c & 7;
      const int gsw = (sg ^ (r & 7)) * 8;
      gld16(&Hbh[(size_t)(row0 + r) * CHID + k0 + gsw],
            (char*)&Hs[0][0] + c * 16);
      gld16(&Wt[(size_t)r * CHID + k0 + gsw], (char*)&Ws[0][0] + c * 16);
    }
    __syncthreads();

    f16x8 bf0[4], bf1[4];
#pragma unroll
    for (int j = 0; j < 4; ++j) {
      const int br = wc * 64 + j * 16 + lcol;
      bf0[j] = *(const f16x8*)&Ws[br][(quad ^ (br & 7)) * 8];
      bf1[j] = *(const f16x8*)&Ws[br][((quad ^ 4) ^ (br & 7)) * 8];
    }
#pragma unroll
    for (int i = 0; i < 4; ++i) {
      const int ar = wr * 64 + i * 16 + lcol;
      const f16x8 af0 = *(const f16x8*)&Hs[ar][(quad ^ (ar & 7)) * 8];
      const f16x8 af1 = *(const f16x8*)&Hs[ar][((quad ^ 4) ^ (ar & 7)) * 8];
#pragma unroll
      for (int j = 0; j < 4; ++j) {
        acc[i][j] = mfma16(af0, bf0[j], acc[i][j]);
        acc[i][j] = mfma16(af1, bf1[j], acc[i][j]);
      }
    }
  }

#pragma unroll
  for (int i = 0; i < 4; ++i) {
#pragma unroll
    for (int rr = 0; rr < 4; ++rr) {
      const size_t rg = row0 + wr * 64 + i * 16 + quad * 4 + rr;
#pragma unroll
      for (int j = 0; j < 4; ++j)
        out[rg * CHID + col0 + wc * 64 + j * 16 + lcol] = acc[i][j][rr];
    }
  }
}

// ---------------------------------------------------------------------------
extern "C" void kernel_launch(void* const* d_in, const int* in_sizes, int n_in,
                              void* d_out, int out_size, void* d_ws,
                              size_t ws_size, hipStream_t stream) {
  const float* x = (const float*)d_in[0];
  const int* mask = (const int*)d_in[1];
  const float* Wq = (const float*)d_in[2];
  const float* Wk = (const float*)d_in[3];
  const float* Wv = (const float*)d_in[4];
  const float* Wout = (const float*)d_in[5];
  float* out = (float*)d_out;

  char* ws = (char*)d_ws;
  int* lens = (int*)ws;
  size_t off = 1024;
  const size_t NX = (size_t)CB * CS * CHID;   // 8,388,608
  const size_t NW = (size_t)CH * CHID * CDK;  // 262,144 per weight
  f16* xh = (f16*)(ws + off);    off += NX * 2;
  f16* wtAll = (f16*)(ws + off); off += NW * 4 * 2;
  f16* Qh = (f16*)(ws + off);    off += NX * 2;
  f16* Kh = (f16*)(ws + off);    off += NX * 2;
  f16* Vth = (f16*)(ws + off);   off += NX * 2;
  f16* Hbh = (f16*)(ws + off);   off += NX * 2;
  float* Vsum = (float*)(ws + off); off += (size_t)CB * CH * CDK * 4;
  f16* woutt = wtAll + NW * 3;

  prep_kernel<<<8208, 256, 0, stream>>>((const float4*)x, (f16x4*)xh, mask,
                                        lens, Vsum);
  cast_w_kernel<<<dim3(8, 32), 256, 0, stream>>>(Wq, Wk, Wv, Wout, wtAll);
  qkvf_kernel<<<dim3(12, 128), 256, 0, stream>>>(xh, wtAll, lens, Qh, Kh, Vth,
                                                 Vsum);
  attn_kernel<<<1024, 256, 0, stream>>>(Qh, Kh, Vth, lens, Vsum, Hbh);
  outp_kernel<<<dim3(128, 4), 256, 0, stream>>>(Hbh, woutt, out);
}

// Round 10
// 215.193 us; speedup vs baseline: 1.1512x; 1.0487x over previous
//
#include <hip/hip_runtime.h>
#include <math.h>

// QANetAttBlock: B=16, S=1024, HID=512, H=8, DK=64
constexpr int CB = 16;
constexpr int CS = 1024;
constexpr int CHID = 512;
constexpr int CH = 8;
constexpr int CDK = 64;

typedef _Float16 f16;
typedef __attribute__((ext_vector_type(8))) _Float16 f16x8;
typedef __attribute__((ext_vector_type(4))) _Float16 f16x4;
typedef __attribute__((ext_vector_type(4))) float f32x4;
typedef __attribute__((ext_vector_type(4))) unsigned int u32x4;
typedef __attribute__((ext_vector_type(2))) unsigned int u32x2;

__device__ inline f32x4 mfma16(f16x8 a, f16x8 b, f32x4 c) {
  return __builtin_amdgcn_mfma_f32_16x16x32_f16(a, b, c, 0, 0, 0);
}

// async global->LDS, 16B per lane; dest must be wave-uniform base + lane*16
__device__ inline void gld16(const void* g, void* l) {
  __builtin_amdgcn_global_load_lds(
      (const __attribute__((address_space(1))) void*)g,
      (__attribute__((address_space(3))) void*)l, 16, 0, 0);
}

// raw v_exp_f32 (2^x). libm exp2f costs ~10 extra VALU/call.
__device__ inline float fast_exp2(float x) {
#if __has_builtin(__builtin_amdgcn_exp2f)
  return __builtin_amdgcn_exp2f(x);
#else
  return __expf(x * 0.6931471805599453f);
#endif
}

// packed f32x2 -> f16x2 with round-to-nearest-even as a raw dword.
__device__ inline unsigned pack_rne(float a, float b) {
  union { f16 h[2]; unsigned u; } c;
  c.h[0] = (f16)a;
  c.h[1] = (f16)b;
  return c.u;
}

// 4x4 quad-transpose of two dwords via gfx950 permlane swaps.
// Rows (16-lane groups) in:  x=[X0,X1,X2,X3], y=[Y0,Y1,Y2,Y3]
// After p32 (dst-hi<->src-lo) + p16 (dst-odd<->src-even):
//   x=[X0,X2,Y0,Y2], y=[X1,X3,Y1,Y3].
// HAZARD NOTE (r1/r2 failure root cause): raw back-to-back permlane asm
// violates the "VALU write -> v_permlane* read needs a wait state" rule.
// The builtins let the compiler insert the required hazard nops.
__device__ inline void quad_transpose(unsigned& x, unsigned& y) {
#if __has_builtin(__builtin_amdgcn_permlane32_swap) && \
    __has_builtin(__builtin_amdgcn_permlane16_swap)
  u32x2 a = __builtin_amdgcn_permlane32_swap(x, y, false, false);
  u32x2 b = __builtin_amdgcn_permlane16_swap(a[0], a[1], false, false);
  x = b[0];
  y = b[1];
#else
  asm volatile(
      "s_nop 1\n\t"
      "v_permlane32_swap_b32 %0, %1\n\t"
      "s_nop 1\n\t"
      "v_permlane16_swap_b32 %0, %1\n\t"
      "s_nop 1"
      : "+v"(x), "+v"(y));
#endif
}

#define LOG2E 1.4426950408889634f

// ---------------------------------------------------------------------------
// prep: blocks 0..8191 cast x fp32->fp16; blocks 8192..8207 compute lens[b]
// and zero Vsum (ws is poisoned 0xAA).
// ---------------------------------------------------------------------------
__global__ __launch_bounds__(256) void prep_kernel(const float4* __restrict__ x,
                                                   f16x4* __restrict__ xh,
                                                   const int* __restrict__ mask,
                                                   int* __restrict__ lens,
                                                   float* __restrict__ Vsum) {
  const int bid = blockIdx.x, t = threadIdx.x;
  __shared__ int red[256];
  if (bid < 8192) {
    const int idx = bid * 256 + t;
    const float4 v = x[idx];
    f16x4 o;
    o[0] = (f16)v.x; o[1] = (f16)v.y; o[2] = (f16)v.z; o[3] = (f16)v.w;
    xh[idx] = o;
  } else {
    const int b = bid - 8192;
    const int g = b * 256 + t;
    Vsum[g * 2] = 0.f;
    Vsum[g * 2 + 1] = 0.f;
    int s = 0;
    for (int i = t; i < CS; i += 256) s += mask[b * CS + i];
    red[t] = s;
    __syncthreads();
    for (int off = 128; off > 0; off >>= 1) {
      if (t < off) red[t] += red[t + off];
      __syncthreads();
    }
    if (t == 0) lens[b] = red[0];
  }
}

// ---------------------------------------------------------------------------
// cast + transpose weights via LDS (coalesced fp32 reads).
// ---------------------------------------------------------------------------
__global__ __launch_bounds__(256) void cast_w_kernel(const float* __restrict__ Wq,
                                                     const float* __restrict__ Wk,
                                                     const float* __restrict__ Wv,
                                                     const float* __restrict__ Wout,
                                                     f16* __restrict__ wtAll) {
  const int y = blockIdx.y, kb = blockIdx.x, t = threadIdx.x;
  const int k0 = kb * 64;
  const float* src;
  int ldsrc;
  f16* dst;
  if (y < 24) {
    const int which = y >> 3, h = y & 7;
    const float* W = (which == 0) ? Wq : (which == 1) ? Wk : Wv;
    src = W + (size_t)h * 32768 + (size_t)k0 * 64;
    ldsrc = 64;
    dst = wtAll + (size_t)which * 262144 + (size_t)h * 32768;
  } else {
    const int c = y - 24;
    src = Wout + (size_t)k0 * 512 + c * 64;
    ldsrc = 512;
    dst = wtAll + (size_t)3 * 262144 + (size_t)c * 64 * 512;
  }

  __shared__ float Ts[64][68];
  {
    const int kr = t >> 4, cg = (t & 15) * 4;
#pragma unroll
    for (int rr = 0; rr < 4; ++rr) {
      const float4 v = *(const float4*)&src[(size_t)(rr * 16 + kr) * ldsrc + cg];
      Ts[rr * 16 + kr][cg] = v.x;
      Ts[rr * 16 + kr][cg + 1] = v.y;
      Ts[rr * 16 + kr][cg + 2] = v.z;
      Ts[rr * 16 + kr][cg + 3] = v.w;
    }
  }
  __syncthreads();
  {
    const int n = t >> 2, seg = t & 3;
    f16x8 a, b;
#pragma unroll
    for (int j = 0; j < 8; ++j) {
      a[j] = (f16)Ts[seg * 16 + j][n];
      b[j] = (f16)Ts[seg * 16 + 8 + j][n];
    }
    f16* d = &dst[(size_t)n * 512 + k0 + seg * 16];
    *(f16x8*)d = a;
    *(f16x8*)(d + 8) = b;
  }
}

// ---------------------------------------------------------------------------
// Fused QKV projection: 128x128 tile, BK=64, gld16 staging with XOR column
// swizzle. grid (12 col-tiles, 128 row-tiles). Q pre-scaled by
// log2e/sqrt(n[b]); epilogues via padded Ts union, coalesced. V: fp32 col
// sums -> Vsum.
// ---------------------------------------------------------------------------
__global__ __launch_bounds__(256) void qkvf_kernel(
    const f16* __restrict__ xh, const f16* __restrict__ wtAll,
    const int* __restrict__ lens, f16* __restrict__ Qh, f16* __restrict__ Kh,
    f16* __restrict__ Vth, float* __restrict__ Vsum) {
  const int ct = blockIdx.x, rt = blockIdx.y;
  const int which = ct >> 2, hp = ct & 3;
  const f16* Wt = wtAll + (size_t)which * 262144 + (size_t)hp * 65536;
  const int row0 = rt * 128;
  const int b = row0 >> 10, s0 = row0 & 1023;
  const int h0 = hp * 2;
  const int t = threadIdx.x;
  const int w = t >> 6, lane = t & 63, quad = lane >> 4, lcol = lane & 15;
  const int wr = w >> 1, wc = w & 1;

  __shared__ union SM {
    struct { f16 Xs[128][64]; f16 Ws[128][64]; } a;  // unpadded (lds-dma)
    f16 Ts[128][136];                                // epilogue staging
  } sm;

  f32x4 acc[4][4];
#pragma unroll
  for (int i = 0; i < 4; ++i)
#pragma unroll
    for (int j = 0; j < 4; ++j) acc[i][j] = (f32x4){0.f, 0.f, 0.f, 0.f};

  for (int k0 = 0; k0 < CHID; k0 += 64) {
    __syncthreads();  // prior compute's LDS reads done
#pragma unroll
    for (int i = 0; i < 4; ++i) {
      const int c = t + 256 * i, r = c >> 3, sg = c & 7;
      const int gsw = (sg ^ (r & 7)) * 8;  // XOR swizzle on global source
      gld16(&xh[(size_t)(row0 + r) * CHID + k0 + gsw],
            (char*)&sm.a.Xs[0][0] + c * 16);
      gld16(&Wt[(size_t)r * CHID + k0 + gsw], (char*)&sm.a.Ws[0][0] + c * 16);
    }
    __syncthreads();  // drains vmcnt: LDS tiles ready

    f16x8 bf0[4], bf1[4];
#pragma unroll
    for (int j = 0; j < 4; ++j) {
      const int br = wc * 64 + j * 16 + lcol;
      bf0[j] = *(const f16x8*)&sm.a.Ws[br][(quad ^ (br & 7)) * 8];
      bf1[j] = *(const f16x8*)&sm.a.Ws[br][((quad ^ 4) ^ (br & 7)) * 8];
    }
#pragma unroll
    for (int i = 0; i < 4; ++i) {
      const int ar = wr * 64 + i * 16 + lcol;
      const f16x8 af0 = *(const f16x8*)&sm.a.Xs[ar][(quad ^ (ar & 7)) * 8];
      const f16x8 af1 =
          *(const f16x8*)&sm.a.Xs[ar][((quad ^ 4) ^ (ar & 7)) * 8];
#pragma unroll
      for (int j = 0; j < 4; ++j) {
        acc[i][j] = mfma16(af0, bf0[j], acc[i][j]);
        acc[i][j] = mfma16(af1, bf1[j], acc[i][j]);
      }
    }
  }

  if (which == 2) {
    // fp32 column sums -> Vsum (quad-reduced, register-only)
#pragma unroll
    for (int j = 0; j < 4; ++j) {
      float ps = 0.f;
#pragma unroll
      for (int i = 0; i < 4; ++i)
#pragma unroll
        for (int rr = 0; rr < 4; ++rr) ps += acc[i][j][rr];
      ps += __shfl_xor(ps, 16);
      ps += __shfl_xor(ps, 32);
      if (quad == 0) {
        const int d128 = wc * 64 + j * 16 + lcol;
        const int h = h0 + (d128 >> 6), d = d128 & 63;
        atomicAdd(&Vsum[((size_t)b * CH + h) * CDK + d], ps);
      }
    }
    // Ts[n][s]: packed f16x4 transpose writes, then coalesced V^T stores
    __syncthreads();
#pragma unroll
    for (int i = 0; i < 4; ++i)
#pragma unroll
      for (int j = 0; j < 4; ++j) {
        f16x4 v4;
#pragma unroll
        for (int rr = 0; rr < 4; ++rr) v4[rr] = (f16)acc[i][j][rr];
        *(f16x4*)&sm.Ts[wc * 64 + j * 16 + lcol][wr * 64 + i * 16 + quad * 4] =
            v4;
      }
    __syncthreads();
    const int c16 = t & 15;
#pragma unroll
    for (int p = 0; p < 8; ++p) {
      const int vr = p * 16 + (t >> 4);
      const int h = h0 + (vr >> 6), d = vr & 63;
      *(f16x8*)&Vth[(((size_t)b * CH + h) * CDK + d) * CS + s0 + c16 * 8] =
          *(const f16x8*)&sm.Ts[vr][c16 * 8];
    }
  } else {
    // Ts[s][n], then coalesced [B,H,S,64] stores (128-B runs)
    const float qsc = (which == 0) ? rsqrtf((float)lens[b]) * LOG2E : 1.0f;
    __syncthreads();
#pragma unroll
    for (int i = 0; i < 4; ++i)
#pragma unroll
      for (int j = 0; j < 4; ++j)
#pragma unroll
        for (int rr = 0; rr < 4; ++rr)
          sm.Ts[wr * 64 + i * 16 + quad * 4 + rr][wc * 64 + j * 16 + lcol] =
              (f16)(acc[i][j][rr] * qsc);
    __syncthreads();
    f16* O = (which == 0) ? Qh : Kh;
    const int c8 = t & 7;
#pragma unroll
    for (int p = 0; p < 4; ++p) {
      const int row = p * 32 + (t >> 3);
#pragma unroll
      for (int half = 0; half < 2; ++half) {
        const int h = h0 + half;
        *(f16x8*)&O[(((size_t)b * CH + h) * CS + s0 + row) * CDK + c8 * 8] =
            *(const f16x8*)&sm.Ts[row][half * 64 + c8 * 8];
      }
    }
  }
}

// ---------------------------------------------------------------------------
// Attention (MFMA flash, v10 = v5 inner (64 VGPR, no kb-hoist) + XCD decode
// + setprio):
//  * r9 lesson: kb-hoist under launch_bounds(256,4) spilled to scratch
//    (WRITE_SIZE 16->117MB, dur 2x). Reverted to v5's verified 64-VGPR
//    inner code: kb0/kb1 loaded per set, pk/pv reg prefetch, dbuf K/V,
//    1 barrier/tile, swapped QK^T, RNE pack + permlane quad-transpose,
//    MFMA row-sums, tail-split masking.
//  * r9 lesson 2: b-fastest decode put 16 x 256KB panels in each XCD L2
//    (= capacity, thrash; FETCH 21->33MB). Decode now qt-fastest:
//    h=id&7 (XCD), qt=(id>>3)&7, b=id>>6 -- the 8 q-blocks of one (b,h)
//    run consecutively on ONE XCD (v6's verified FETCH 113->21MB).
//  * 128-row blocks, grid 1024 -> 4 blocks/CU (LDS 147KB<160) = phase-
//    independent overlap v6 lacked; T5 setprio around MFMA clusters pays
//    in exactly this phase-diverse regime.
// ---------------------------------------------------------------------------
__global__ __launch_bounds__(256, 4) void attn_kernel(
    const f16* __restrict__ Qh, const f16* __restrict__ Kh,
    const f16* __restrict__ Vth, const int* __restrict__ lens,
    const float* __restrict__ Vsum, f16* __restrict__ Hbh) {
  const int id = blockIdx.x;
  const int h = id & 7;            // XCD index under %8 round-robin
  const int qt = (id >> 3) & 7;    // fastest on an XCD: same (b,h) panel
  const int b = id >> 6;           // 0..15
  const int n = lens[b];
  const int t = threadIdx.x, w = t >> 6, lane = t & 63, quad = lane >> 4,
            lcol = lane & 15;

  const size_t bh = ((size_t)b * CH + h) * CS;
  const size_t bhd = ((size_t)b * CH + h) * CDK;

  const int nt = (n + 63) >> 6;
  const int rem = n & 63;
  const int ntm = rem ? nt - 1 : nt;  // unmasked main tiles

  __shared__ union SM {
    struct { f16 Ks[2][64][72]; f16 Vs[2][64][72]; } kv;  // [buf][k|d][d|k]
    f16 St[4][32][72];  // epilogue staging (post-loop reuse)
  } sm;

  const int qbase = qt * 128 + w * 32;
  f16x8 qa[2][2];
#pragma unroll
  for (int set = 0; set < 2; ++set) {
    const size_t qr = bh + qbase + set * 16 + lcol;
    qa[set][0] = *(const f16x8*)&Qh[qr * CDK + quad * 8];
    qa[set][1] = *(const f16x8*)&Qh[qr * CDK + 32 + quad * 8];
  }

  f16x8 vones;
#pragma unroll
  for (int j = 0; j < 8; ++j) vones[j] = (f16)1.0f;

  f32x4 o[2][4];
#pragma unroll
  for (int set = 0; set < 2; ++set)
#pragma unroll
    for (int dt = 0; dt < 4; ++dt) o[set][dt] = (f32x4){0.f, 0.f, 0.f, 0.f};
  f32x4 o_l[2] = {(f32x4){0.f, 0.f, 0.f, 0.f}, (f32x4){0.f, 0.f, 0.f, 0.f}};

  // tile 0: load + stage into buffer 0
  f16x8 pk[2], pv[2];
#pragma unroll
  for (int i = 0; i < 2; ++i) {
    const int c = t + 256 * i, r = c >> 3, sg = c & 7;
    pk[i] = *(const f16x8*)&Kh[(bh + r) * CDK + sg * 8];
    pv[i] = *(const f16x8*)&Vth[(bhd + r) * CS + sg * 8];
  }
#pragma unroll
  for (int i = 0; i < 2; ++i) {
    const int c = t + 256 * i, r = c >> 3, sg = c & 7;
    *(f16x8*)&sm.kv.Ks[0][r][sg * 8] = pk[i];
    *(f16x8*)&sm.kv.Vs[0][r][sg * 8] = pv[i];
  }
  __syncthreads();

  auto ktile = [&](const int kt, const bool masked) __attribute__((always_inline)) {
    const int cur = kt & 1, nxt = cur ^ 1;
    // prefetch next tile into regs (clamped; uniform straight-line code)
    const int ktn = (kt + 1 < nt) ? kt + 1 : kt;
#pragma unroll
    for (int i = 0; i < 2; ++i) {
      const int c = t + 256 * i, r = c >> 3, sg = c & 7;
      pk[i] = *(const f16x8*)&Kh[(bh + ktn * 64 + r) * CDK + sg * 8];
      pv[i] = *(const f16x8*)&Vth[(bhd + r) * CS + ktn * 64 + sg * 8];
    }

    // swapped QK^T + exp + in-register P->A-frag transpose
    f16x8 pa[2][2];
#pragma unroll
    for (int set = 0; set < 2; ++set) {
      f32x4 st[4];
      __builtin_amdgcn_s_setprio(1);
#pragma unroll
      for (int ct = 0; ct < 4; ++ct) {
        const f16x8 kb0 = *(const f16x8*)&sm.kv.Ks[cur][ct * 16 + lcol][quad * 8];
        const f16x8 kb1 =
            *(const f16x8*)&sm.kv.Ks[cur][ct * 16 + lcol][32 + quad * 8];
        st[ct] = mfma16(kb0, qa[set][0], (f32x4){0.f, 0.f, 0.f, 0.f});
        st[ct] = mfma16(kb1, qa[set][1], st[ct]);
      }
      __builtin_amdgcn_s_setprio(0);
      unsigned pkd[4][2];
#pragma unroll
      for (int c = 0; c < 4; ++c) {
        float p[4];
#pragma unroll
        for (int r = 0; r < 4; ++r) {
          float e = fast_exp2(st[c][r]);
          if (masked) {
            const bool kvld = (kt * 64 + c * 16 + quad * 4 + r) < n;
            e = kvld ? e : 0.f;
          }
          p[r] = e;
        }
        pkd[c][0] = pack_rne(p[0], p[1]);
        pkd[c][1] = pack_rne(p[2], p[3]);
      }
      // quad-transpose: target quad t's dword j2 ends at k = 8t + 2*j2 + {0,1}
#pragma unroll
      for (int half = 0; half < 2; ++half) {
        unsigned x0 = pkd[2 * half][0], y0 = pkd[2 * half + 1][0];
        unsigned x1 = pkd[2 * half][1], y1 = pkd[2 * half + 1][1];
        quad_transpose(x0, y0);
        quad_transpose(x1, y1);
        union { u32x4 u; f16x8 h; } cc;
        cc.u = (u32x4){x0, x1, y0, y1};
        pa[set][half] = cc.h;
      }
    }

    // PV + row-sum MFMAs (P x ones = rowsum, lands directly in O-layout)
    __builtin_amdgcn_s_setprio(1);
#pragma unroll
    for (int dt = 0; dt < 4; ++dt) {
      const f16x8 vb0 = *(const f16x8*)&sm.kv.Vs[cur][dt * 16 + lcol][quad * 8];
      const f16x8 vb1 =
          *(const f16x8*)&sm.kv.Vs[cur][dt * 16 + lcol][32 + quad * 8];
#pragma unroll
      for (int set = 0; set < 2; ++set) {
        o[set][dt] = mfma16(pa[set][0], vb0, o[set][dt]);
        o[set][dt] = mfma16(pa[set][1], vb1, o[set][dt]);
      }
    }
#pragma unroll
    for (int set = 0; set < 2; ++set) {
      o_l[set] = mfma16(pa[set][0], vones, o_l[set]);
      o_l[set] = mfma16(pa[set][1], vones, o_l[set]);
    }
    __builtin_amdgcn_s_setprio(0);

    // stage next tile into the other buffer; one barrier covers both
    // write-visibility (buf nxt) and read-completion (buf cur)
#pragma unroll
    for (int i = 0; i < 2; ++i) {
      const int c = t + 256 * i, r = c >> 3, sg = c & 7;
      *(f16x8*)&sm.kv.Ks[nxt][r][sg * 8] = pk[i];
      *(f16x8*)&sm.kv.Vs[nxt][r][sg * 8] = pv[i];
    }
    __syncthreads();
  };

  int kt = 0;
  for (; kt < ntm; ++kt) ktile(kt, false);
  if (rem) ktile(kt, true);

  // per-lane inverse row-sums (already in O-layout: row quad*4+r, any col)
  float invl[2][4];
#pragma unroll
  for (int set = 0; set < 2; ++set)
#pragma unroll
    for (int r = 0; r < 4; ++r) invl[set][r] = 1.0f / o_l[set][r];

  // O -> wave-private St (f16), then coalesced 128-B-run stores.
  // (final loop barrier already fenced all K/V reads; St aliases kv)
#pragma unroll
  for (int set = 0; set < 2; ++set)
#pragma unroll
    for (int dt = 0; dt < 4; ++dt)
#pragma unroll
      for (int r = 0; r < 4; ++r) {
        const int srow_l = set * 16 + quad * 4 + r;
        const int d = dt * 16 + lcol;
        const float val = (qbase + srow_l < n)
                              ? o[set][dt][r] * invl[set][r]
                              : Vsum[bhd + d] * (1.0f / 1024.0f);
        sm.St[w][srow_l][d] = (f16)val;
      }
  {
    const int lr = lane >> 3, lc = lane & 7;
#pragma unroll
    for (int p = 0; p < 4; ++p) {
      const int row = p * 8 + lr;
      *(f16x8*)&Hbh[((size_t)b * CS + qbase + row) * (CH * CDK) + h * CDK +
                    lc * 8] = *(const f16x8*)&sm.St[w][row][lc * 8];
    }
  }
}

// ---------------------------------------------------------------------------
// Output projection: 128x128 tile, BK=64, gld16 + XOR swizzle (as qkvf).
// grid (128 row-tiles, 4 col-tiles), block 256.
// ---------------------------------------------------------------------------
__global__ __launch_bounds__(256) void outp_kernel(const f16* __restrict__ Hbh,
                                                   const f16* __restrict__ woutt,
                                                   float* __restrict__ out) {
  const int rt = blockIdx.x, ctile = blockIdx.y;
  const int row0 = rt * 128, col0 = ctile * 128;
  const f16* Wt = woutt + (size_t)col0 * CHID;
  const int t = threadIdx.x;
  const int w = t >> 6, lane = t & 63, quad = lane >> 4, lcol = lane & 15;
  const int wr = w >> 1, wc = w & 1;

  __shared__ f16 Hs[128][64];  // unpadded (lds-dma), XOR-swizzled columns
  __shared__ f16 Ws[128][64];

  f32x4 acc[4][4];
#pragma unroll
  for (int i = 0; i < 4; ++i)
#pragma unroll
    for (int j = 0; j < 4; ++j) acc[i][j] = (f32x4){0.f, 0.f, 0.f, 0.f};

  for (int k0 = 0; k0 < CHID; k0 += 64) {
    __syncthreads();
#pragma unroll
    for (int i = 0; i < 4; ++i) {
      const int c = t + 256 * i, r = c >> 3, sg = c & 7;
      const int gsw = (sg ^ (r & 7)) * 8;
      gld16(&Hbh[(size_t)(row0 + r) * CHID + k0 + gsw],
            (char*)&Hs[0][0] + c * 16);
      gld16(&Wt[(size_t)r * CHID + k0 + gsw], (char*)&Ws[0][0] + c * 16);
    }
    __syncthreads();

    f16x8 bf0[4], bf1[4];
#pragma unroll
    for (int j = 0; j < 4; ++j) {
      const int br = wc * 64 + j * 16 + lcol;
      bf0[j] = *(const f16x8*)&Ws[br][(quad ^ (br & 7)) * 8];
      bf1[j] = *(const f16x8*)&Ws[br][((quad ^ 4) ^ (br & 7)) * 8];
    }
#pragma unroll
    for (int i = 0; i < 4; ++i) {
      const int ar = wr * 64 + i * 16 + lcol;
      const f16x8 af0 = *(const f16x8*)&Hs[ar][(quad ^ (ar & 7)) * 8];
      const f16x8 af1 = *(const f16x8*)&Hs[ar][((quad ^ 4) ^ (ar & 7)) * 8];
#pragma unroll
      for (int j = 0; j < 4; ++j) {
        acc[i][j] = mfma16(af0, bf0[j], acc[i][j]);
        acc[i][j] = mfma16(af1, bf1[j], acc[i][j]);
      }
    }
  }

#pragma unroll
  for (int i = 0; i < 4; ++i) {
#pragma unroll
    for (int rr = 0; rr < 4; ++rr) {
      const size_t rg = row0 + wr * 64 + i * 16 + quad * 4 + rr;
#pragma unroll
      for (int j = 0; j < 4; ++j)
        out[rg * CHID + col0 + wc * 64 + j * 16 + lcol] = acc[i][j][rr];
    }
  }
}

// ---------------------------------------------------------------------------
extern "C" void kernel_launch(void* const* d_in, const int* in_sizes, int n_in,
                              void* d_out, int out_size, void* d_ws,
                              size_t ws_size, hipStream_t stream) {
  const float* x = (const float*)d_in[0];
  const int* mask = (const int*)d_in[1];
  const float* Wq = (const float*)d_in[2];
  const float* Wk = (const float*)d_in[3];
  const float* Wv = (const float*)d_in[4];
  const float* Wout = (const float*)d_in[5];
  float* out = (float*)d_out;

  char* ws = (char*)d_ws;
  int* lens = (int*)ws;
  size_t off = 1024;
  const size_t NX = (size_t)CB * CS * CHID;   // 8,388,608
  const size_t NW = (size_t)CH * CHID * CDK;  // 262,144 per weight
  f16* xh = (f16*)(ws + off);    off += NX * 2;
  f16* wtAll = (f16*)(ws + off); off += NW * 4 * 2;
  f16* Qh = (f16*)(ws + off);    off += NX * 2;
  f16* Kh = (f16*)(ws + off);    off += NX * 2;
  f16* Vth = (f16*)(ws + off);   off += NX * 2;
  f16* Hbh = (f16*)(ws + off);   off += NX * 2;
  float* Vsum = (float*)(ws + off); off += (size_t)CB * CH * CDK * 4;
  f16* woutt = wtAll + NW * 3;

  prep_kernel<<<8208, 256, 0, stream>>>((const float4*)x, (f16x4*)xh, mask,
                                        lens, Vsum);
  cast_w_kernel<<<dim3(8, 32), 256, 0, stream>>>(Wq, Wk, Wv, Wout, wtAll);
  qkvf_kernel<<<dim3(12, 128), 256, 0, stream>>>(xh, wtAll, lens, Qh, Kh, Vth,
                                                 Vsum);
  attn_kernel<<<1024, 256, 0, stream>>>(Qh, Kh, Vth, lens, Vsum, Hbh);
  outp_kernel<<<dim3(128, 4), 256, 0, stream>>>(Hbh, woutt, out);
}

// Round 11
// 190.441 us; speedup vs baseline: 1.3008x; 1.1300x over previous
//
#include <hip/hip_runtime.h>
#include <math.h>

// QANetAttBlock: B=16, S=1024, HID=512, H=8, DK=64
constexpr int CB = 16;
constexpr int CS = 1024;
constexpr int CHID = 512;
constexpr int CH = 8;
constexpr int CDK = 64;

typedef _Float16 f16;
typedef __attribute__((ext_vector_type(8))) _Float16 f16x8;
typedef __attribute__((ext_vector_type(4))) _Float16 f16x4;
typedef __attribute__((ext_vector_type(4))) float f32x4;
typedef __attribute__((ext_vector_type(4))) unsigned int u32x4;
typedef __attribute__((ext_vector_type(2))) unsigned int u32x2;

__device__ inline f32x4 mfma16(f16x8 a, f16x8 b, f32x4 c) {
  return __builtin_amdgcn_mfma_f32_16x16x32_f16(a, b, c, 0, 0, 0);
}

// async global->LDS, 16B per lane; dest must be wave-uniform base + lane*16
__device__ inline void gld16(const void* g, void* l) {
  __builtin_amdgcn_global_load_lds(
      (const __attribute__((address_space(1))) void*)g,
      (__attribute__((address_space(3))) void*)l, 16, 0, 0);
}

// raw v_exp_f32 (2^x). libm exp2f costs ~10 extra VALU/call.
__device__ inline float fast_exp2(float x) {
#if __has_builtin(__builtin_amdgcn_exp2f)
  return __builtin_amdgcn_exp2f(x);
#else
  return __expf(x * 0.6931471805599453f);
#endif
}

// packed f32x2 -> f16x2 with round-to-nearest-even as a raw dword.
__device__ inline unsigned pack_rne(float a, float b) {
  union { f16 h[2]; unsigned u; } c;
  c.h[0] = (f16)a;
  c.h[1] = (f16)b;
  return c.u;
}

// 4x4 quad-transpose of two dwords via gfx950 permlane swaps.
// Rows (16-lane groups) in:  x=[X0,X1,X2,X3], y=[Y0,Y1,Y2,Y3]
// After p32 (dst-hi<->src-lo) + p16 (dst-odd<->src-even):
//   x=[X0,X2,Y0,Y2], y=[X1,X3,Y1,Y3].
// HAZARD NOTE (r1/r2 failure root cause): raw back-to-back permlane asm
// violates the "VALU write -> v_permlane* read needs a wait state" rule.
// The builtins let the compiler insert the required hazard nops.
__device__ inline void quad_transpose(unsigned& x, unsigned& y) {
#if __has_builtin(__builtin_amdgcn_permlane32_swap) && \
    __has_builtin(__builtin_amdgcn_permlane16_swap)
  u32x2 a = __builtin_amdgcn_permlane32_swap(x, y, false, false);
  u32x2 b = __builtin_amdgcn_permlane16_swap(a[0], a[1], false, false);
  x = b[0];
  y = b[1];
#else
  asm volatile(
      "s_nop 1\n\t"
      "v_permlane32_swap_b32 %0, %1\n\t"
      "s_nop 1\n\t"
      "v_permlane16_swap_b32 %0, %1\n\t"
      "s_nop 1"
      : "+v"(x), "+v"(y));
#endif
}

#define LOG2E 1.4426950408889634f

// ---------------------------------------------------------------------------
// prep: blocks 0..8191 cast x fp32->fp16; blocks 8192..8207 compute lens[b]
// and zero Vsum (ws is poisoned 0xAA).
// ---------------------------------------------------------------------------
__global__ __launch_bounds__(256) void prep_kernel(const float4* __restrict__ x,
                                                   f16x4* __restrict__ xh,
                                                   const int* __restrict__ mask,
                                                   int* __restrict__ lens,
                                                   float* __restrict__ Vsum) {
  const int bid = blockIdx.x, t = threadIdx.x;
  __shared__ int red[256];
  if (bid < 8192) {
    const int idx = bid * 256 + t;
    const float4 v = x[idx];
    f16x4 o;
    o[0] = (f16)v.x; o[1] = (f16)v.y; o[2] = (f16)v.z; o[3] = (f16)v.w;
    xh[idx] = o;
  } else {
    const int b = bid - 8192;
    const int g = b * 256 + t;
    Vsum[g * 2] = 0.f;
    Vsum[g * 2 + 1] = 0.f;
    int s = 0;
    for (int i = t; i < CS; i += 256) s += mask[b * CS + i];
    red[t] = s;
    __syncthreads();
    for (int off = 128; off > 0; off >>= 1) {
      if (t < off) red[t] += red[t + off];
      __syncthreads();
    }
    if (t == 0) lens[b] = red[0];
  }
}

// ---------------------------------------------------------------------------
// cast + transpose weights via LDS (coalesced fp32 reads).
// ---------------------------------------------------------------------------
__global__ __launch_bounds__(256) void cast_w_kernel(const float* __restrict__ Wq,
                                                     const float* __restrict__ Wk,
                                                     const float* __restrict__ Wv,
                                                     const float* __restrict__ Wout,
                                                     f16* __restrict__ wtAll) {
  const int y = blockIdx.y, kb = blockIdx.x, t = threadIdx.x;
  const int k0 = kb * 64;
  const float* src;
  int ldsrc;
  f16* dst;
  if (y < 24) {
    const int which = y >> 3, h = y & 7;
    const float* W = (which == 0) ? Wq : (which == 1) ? Wk : Wv;
    src = W + (size_t)h * 32768 + (size_t)k0 * 64;
    ldsrc = 64;
    dst = wtAll + (size_t)which * 262144 + (size_t)h * 32768;
  } else {
    const int c = y - 24;
    src = Wout + (size_t)k0 * 512 + c * 64;
    ldsrc = 512;
    dst = wtAll + (size_t)3 * 262144 + (size_t)c * 64 * 512;
  }

  __shared__ float Ts[64][68];
  {
    const int kr = t >> 4, cg = (t & 15) * 4;
#pragma unroll
    for (int rr = 0; rr < 4; ++rr) {
      const float4 v = *(const float4*)&src[(size_t)(rr * 16 + kr) * ldsrc + cg];
      Ts[rr * 16 + kr][cg] = v.x;
      Ts[rr * 16 + kr][cg + 1] = v.y;
      Ts[rr * 16 + kr][cg + 2] = v.z;
      Ts[rr * 16 + kr][cg + 3] = v.w;
    }
  }
  __syncthreads();
  {
    const int n = t >> 2, seg = t & 3;
    f16x8 a, b;
#pragma unroll
    for (int j = 0; j < 8; ++j) {
      a[j] = (f16)Ts[seg * 16 + j][n];
      b[j] = (f16)Ts[seg * 16 + 8 + j][n];
    }
    f16* d = &dst[(size_t)n * 512 + k0 + seg * 16];
    *(f16x8*)d = a;
    *(f16x8*)(d + 8) = b;
  }
}

// ---------------------------------------------------------------------------
// Fused QKV projection: 128x128 tile, BK=64, gld16 staging with XOR column
// swizzle. grid (12 col-tiles, 128 row-tiles). Q pre-scaled by
// log2e/sqrt(n[b]); epilogues via padded Ts union, coalesced. V: fp32 col
// sums -> Vsum.
// ---------------------------------------------------------------------------
__global__ __launch_bounds__(256) void qkvf_kernel(
    const f16* __restrict__ xh, const f16* __restrict__ wtAll,
    const int* __restrict__ lens, f16* __restrict__ Qh, f16* __restrict__ Kh,
    f16* __restrict__ Vth, float* __restrict__ Vsum) {
  const int ct = blockIdx.x, rt = blockIdx.y;
  const int which = ct >> 2, hp = ct & 3;
  const f16* Wt = wtAll + (size_t)which * 262144 + (size_t)hp * 65536;
  const int row0 = rt * 128;
  const int b = row0 >> 10, s0 = row0 & 1023;
  const int h0 = hp * 2;
  const int t = threadIdx.x;
  const int w = t >> 6, lane = t & 63, quad = lane >> 4, lcol = lane & 15;
  const int wr = w >> 1, wc = w & 1;

  __shared__ union SM {
    struct { f16 Xs[128][64]; f16 Ws[128][64]; } a;  // unpadded (lds-dma)
    f16 Ts[128][136];                                // epilogue staging
  } sm;

  f32x4 acc[4][4];
#pragma unroll
  for (int i = 0; i < 4; ++i)
#pragma unroll
    for (int j = 0; j < 4; ++j) acc[i][j] = (f32x4){0.f, 0.f, 0.f, 0.f};

  for (int k0 = 0; k0 < CHID; k0 += 64) {
    __syncthreads();  // prior compute's LDS reads done
#pragma unroll
    for (int i = 0; i < 4; ++i) {
      const int c = t + 256 * i, r = c >> 3, sg = c & 7;
      const int gsw = (sg ^ (r & 7)) * 8;  // XOR swizzle on global source
      gld16(&xh[(size_t)(row0 + r) * CHID + k0 + gsw],
            (char*)&sm.a.Xs[0][0] + c * 16);
      gld16(&Wt[(size_t)r * CHID + k0 + gsw], (char*)&sm.a.Ws[0][0] + c * 16);
    }
    __syncthreads();  // drains vmcnt: LDS tiles ready

    f16x8 bf0[4], bf1[4];
#pragma unroll
    for (int j = 0; j < 4; ++j) {
      const int br = wc * 64 + j * 16 + lcol;
      bf0[j] = *(const f16x8*)&sm.a.Ws[br][(quad ^ (br & 7)) * 8];
      bf1[j] = *(const f16x8*)&sm.a.Ws[br][((quad ^ 4) ^ (br & 7)) * 8];
    }
#pragma unroll
    for (int i = 0; i < 4; ++i) {
      const int ar = wr * 64 + i * 16 + lcol;
      const f16x8 af0 = *(const f16x8*)&sm.a.Xs[ar][(quad ^ (ar & 7)) * 8];
      const f16x8 af1 =
          *(const f16x8*)&sm.a.Xs[ar][((quad ^ 4) ^ (ar & 7)) * 8];
#pragma unroll
      for (int j = 0; j < 4; ++j) {
        acc[i][j] = mfma16(af0, bf0[j], acc[i][j]);
        acc[i][j] = mfma16(af1, bf1[j], acc[i][j]);
      }
    }
  }

  if (which == 2) {
    // fp32 column sums -> Vsum (quad-reduced, register-only)
#pragma unroll
    for (int j = 0; j < 4; ++j) {
      float ps = 0.f;
#pragma unroll
      for (int i = 0; i < 4; ++i)
#pragma unroll
        for (int rr = 0; rr < 4; ++rr) ps += acc[i][j][rr];
      ps += __shfl_xor(ps, 16);
      ps += __shfl_xor(ps, 32);
      if (quad == 0) {
        const int d128 = wc * 64 + j * 16 + lcol;
        const int h = h0 + (d128 >> 6), d = d128 & 63;
        atomicAdd(&Vsum[((size_t)b * CH + h) * CDK + d], ps);
      }
    }
    // Ts[n][s]: packed f16x4 transpose writes, then coalesced V^T stores
    __syncthreads();
#pragma unroll
    for (int i = 0; i < 4; ++i)
#pragma unroll
      for (int j = 0; j < 4; ++j) {
        f16x4 v4;
#pragma unroll
        for (int rr = 0; rr < 4; ++rr) v4[rr] = (f16)acc[i][j][rr];
        *(f16x4*)&sm.Ts[wc * 64 + j * 16 + lcol][wr * 64 + i * 16 + quad * 4] =
            v4;
      }
    __syncthreads();
    const int c16 = t & 15;
#pragma unroll
    for (int p = 0; p < 8; ++p) {
      const int vr = p * 16 + (t >> 4);
      const int h = h0 + (vr >> 6), d = vr & 63;
      *(f16x8*)&Vth[(((size_t)b * CH + h) * CDK + d) * CS + s0 + c16 * 8] =
          *(const f16x8*)&sm.Ts[vr][c16 * 8];
    }
  } else {
    // Ts[s][n], then coalesced [B,H,S,64] stores (128-B runs)
    const float qsc = (which == 0) ? rsqrtf((float)lens[b]) * LOG2E : 1.0f;
    __syncthreads();
#pragma unroll
    for (int i = 0; i < 4; ++i)
#pragma unroll
      for (int j = 0; j < 4; ++j)
#pragma unroll
        for (int rr = 0; rr < 4; ++rr)
          sm.Ts[wr * 64 + i * 16 + quad * 4 + rr][wc * 64 + j * 16 + lcol] =
              (f16)(acc[i][j][rr] * qsc);
    __syncthreads();
    f16* O = (which == 0) ? Qh : Kh;
    const int c8 = t & 7;
#pragma unroll
    for (int p = 0; p < 4; ++p) {
      const int row = p * 32 + (t >> 3);
#pragma unroll
      for (int half = 0; half < 2; ++half) {
        const int h = h0 + half;
        *(f16x8*)&O[(((size_t)b * CH + h) * CS + s0 + row) * CDK + c8 * 8] =
            *(const f16x8*)&sm.Ts[row][half * 64 + c8 * 8];
      }
    }
  }
}

// ---------------------------------------------------------------------------
// Attention (MFMA flash, v11 = v10 minus setprio — single-variable isolate):
//  * r10 finding: WRITE_SIZE >= 93MB in EVERY kernel containing s_setprio
//    (v9: 117, v10: 93) and <= 24.5MB in every kernel without (v5: 24.5,
//    v6/v7: 16). r9's "kb-hoist spill" theory was refuted (v10 has no
//    hoist, genuine VGPR 64, still 93MB). setprio removed; everything else
//    byte-identical to v10.
//  * Inner code = v5's verified 64-VGPR structure: kb0/kb1 per set, pk/pv
//    reg prefetch, dbuf K/V, 1 barrier/tile, swapped QK^T, RNE pack +
//    permlane quad-transpose, MFMA row-sums, tail-split masking.
//  * XCD decode kept (demonstrated FETCH 113->31MB): h=id&7,
//    qt=(id>>3)&7 fastest on an XCD, b=id>>6.
//  * 128-row blocks, grid 1024, 4 blocks/CU (LDS 147KB<160).
// ---------------------------------------------------------------------------
__global__ __launch_bounds__(256, 4) void attn_kernel(
    const f16* __restrict__ Qh, const f16* __restrict__ Kh,
    const f16* __restrict__ Vth, const int* __restrict__ lens,
    const float* __restrict__ Vsum, f16* __restrict__ Hbh) {
  const int id = blockIdx.x;
  const int h = id & 7;            // XCD index under %8 round-robin
  const int qt = (id >> 3) & 7;    // fastest on an XCD: same (b,h) panel
  const int b = id >> 6;           // 0..15
  const int n = lens[b];
  const int t = threadIdx.x, w = t >> 6, lane = t & 63, quad = lane >> 4,
            lcol = lane & 15;

  const size_t bh = ((size_t)b * CH + h) * CS;
  const size_t bhd = ((size_t)b * CH + h) * CDK;

  const int nt = (n + 63) >> 6;
  const int rem = n & 63;
  const int ntm = rem ? nt - 1 : nt;  // unmasked main tiles

  __shared__ union SM {
    struct { f16 Ks[2][64][72]; f16 Vs[2][64][72]; } kv;  // [buf][k|d][d|k]
    f16 St[4][32][72];  // epilogue staging (post-loop reuse)
  } sm;

  const int qbase = qt * 128 + w * 32;
  f16x8 qa[2][2];
#pragma unroll
  for (int set = 0; set < 2; ++set) {
    const size_t qr = bh + qbase + set * 16 + lcol;
    qa[set][0] = *(const f16x8*)&Qh[qr * CDK + quad * 8];
    qa[set][1] = *(const f16x8*)&Qh[qr * CDK + 32 + quad * 8];
  }

  f16x8 vones;
#pragma unroll
  for (int j = 0; j < 8; ++j) vones[j] = (f16)1.0f;

  f32x4 o[2][4];
#pragma unroll
  for (int set = 0; set < 2; ++set)
#pragma unroll
    for (int dt = 0; dt < 4; ++dt) o[set][dt] = (f32x4){0.f, 0.f, 0.f, 0.f};
  f32x4 o_l[2] = {(f32x4){0.f, 0.f, 0.f, 0.f}, (f32x4){0.f, 0.f, 0.f, 0.f}};

  // tile 0: load + stage into buffer 0
  f16x8 pk[2], pv[2];
#pragma unroll
  for (int i = 0; i < 2; ++i) {
    const int c = t + 256 * i, r = c >> 3, sg = c & 7;
    pk[i] = *(const f16x8*)&Kh[(bh + r) * CDK + sg * 8];
    pv[i] = *(const f16x8*)&Vth[(bhd + r) * CS + sg * 8];
  }
#pragma unroll
  for (int i = 0; i < 2; ++i) {
    const int c = t + 256 * i, r = c >> 3, sg = c & 7;
    *(f16x8*)&sm.kv.Ks[0][r][sg * 8] = pk[i];
    *(f16x8*)&sm.kv.Vs[0][r][sg * 8] = pv[i];
  }
  __syncthreads();

  auto ktile = [&](const int kt, const bool masked) __attribute__((always_inline)) {
    const int cur = kt & 1, nxt = cur ^ 1;
    // prefetch next tile into regs (clamped; uniform straight-line code)
    const int ktn = (kt + 1 < nt) ? kt + 1 : kt;
#pragma unroll
    for (int i = 0; i < 2; ++i) {
      const int c = t + 256 * i, r = c >> 3, sg = c & 7;
      pk[i] = *(const f16x8*)&Kh[(bh + ktn * 64 + r) * CDK + sg * 8];
      pv[i] = *(const f16x8*)&Vth[(bhd + r) * CS + ktn * 64 + sg * 8];
    }

    // swapped QK^T + exp + in-register P->A-frag transpose
    f16x8 pa[2][2];
#pragma unroll
    for (int set = 0; set < 2; ++set) {
      f32x4 st[4];
#pragma unroll
      for (int ct = 0; ct < 4; ++ct) {
        const f16x8 kb0 = *(const f16x8*)&sm.kv.Ks[cur][ct * 16 + lcol][quad * 8];
        const f16x8 kb1 =
            *(const f16x8*)&sm.kv.Ks[cur][ct * 16 + lcol][32 + quad * 8];
        st[ct] = mfma16(kb0, qa[set][0], (f32x4){0.f, 0.f, 0.f, 0.f});
        st[ct] = mfma16(kb1, qa[set][1], st[ct]);
      }
      unsigned pkd[4][2];
#pragma unroll
      for (int c = 0; c < 4; ++c) {
        float p[4];
#pragma unroll
        for (int r = 0; r < 4; ++r) {
          float e = fast_exp2(st[c][r]);
          if (masked) {
            const bool kvld = (kt * 64 + c * 16 + quad * 4 + r) < n;
            e = kvld ? e : 0.f;
          }
          p[r] = e;
        }
        pkd[c][0] = pack_rne(p[0], p[1]);
        pkd[c][1] = pack_rne(p[2], p[3]);
      }
      // quad-transpose: target quad t's dword j2 ends at k = 8t + 2*j2 + {0,1}
#pragma unroll
      for (int half = 0; half < 2; ++half) {
        unsigned x0 = pkd[2 * half][0], y0 = pkd[2 * half + 1][0];
        unsigned x1 = pkd[2 * half][1], y1 = pkd[2 * half + 1][1];
        quad_transpose(x0, y0);
        quad_transpose(x1, y1);
        union { u32x4 u; f16x8 h; } cc;
        cc.u = (u32x4){x0, x1, y0, y1};
        pa[set][half] = cc.h;
      }
    }

    // PV + row-sum MFMAs (P x ones = rowsum, lands directly in O-layout)
#pragma unroll
    for (int dt = 0; dt < 4; ++dt) {
      const f16x8 vb0 = *(const f16x8*)&sm.kv.Vs[cur][dt * 16 + lcol][quad * 8];
      const f16x8 vb1 =
          *(const f16x8*)&sm.kv.Vs[cur][dt * 16 + lcol][32 + quad * 8];
#pragma unroll
      for (int set = 0; set < 2; ++set) {
        o[set][dt] = mfma16(pa[set][0], vb0, o[set][dt]);
        o[set][dt] = mfma16(pa[set][1], vb1, o[set][dt]);
      }
    }
#pragma unroll
    for (int set = 0; set < 2; ++set) {
      o_l[set] = mfma16(pa[set][0], vones, o_l[set]);
      o_l[set] = mfma16(pa[set][1], vones, o_l[set]);
    }

    // stage next tile into the other buffer; one barrier covers both
    // write-visibility (buf nxt) and read-completion (buf cur)
#pragma unroll
    for (int i = 0; i < 2; ++i) {
      const int c = t + 256 * i, r = c >> 3, sg = c & 7;
      *(f16x8*)&sm.kv.Ks[nxt][r][sg * 8] = pk[i];
      *(f16x8*)&sm.kv.Vs[nxt][r][sg * 8] = pv[i];
    }
    __syncthreads();
  };

  int kt = 0;
  for (; kt < ntm; ++kt) ktile(kt, false);
  if (rem) ktile(kt, true);

  // per-lane inverse row-sums (already in O-layout: row quad*4+r, any col)
  float invl[2][4];
#pragma unroll
  for (int set = 0; set < 2; ++set)
#pragma unroll
    for (int r = 0; r < 4; ++r) invl[set][r] = 1.0f / o_l[set][r];

  // O -> wave-private St (f16), then coalesced 128-B-run stores.
  // (final loop barrier already fenced all K/V reads; St aliases kv)
#pragma unroll
  for (int set = 0; set < 2; ++set)
#pragma unroll
    for (int dt = 0; dt < 4; ++dt)
#pragma unroll
      for (int r = 0; r < 4; ++r) {
        const int srow_l = set * 16 + quad * 4 + r;
        const int d = dt * 16 + lcol;
        const float val = (qbase + srow_l < n)
                              ? o[set][dt][r] * invl[set][r]
                              : Vsum[bhd + d] * (1.0f / 1024.0f);
        sm.St[w][srow_l][d] = (f16)val;
      }
  {
    const int lr = lane >> 3, lc = lane & 7;
#pragma unroll
    for (int p = 0; p < 4; ++p) {
      const int row = p * 8 + lr;
      *(f16x8*)&Hbh[((size_t)b * CS + qbase + row) * (CH * CDK) + h * CDK +
                    lc * 8] = *(const f16x8*)&sm.St[w][row][lc * 8];
    }
  }
}

// ---------------------------------------------------------------------------
// Output projection: 128x128 tile, BK=64, gld16 + XOR swizzle (as qkvf).
// grid (128 row-tiles, 4 col-tiles), block 256.
// ---------------------------------------------------------------------------
__global__ __launch_bounds__(256) void outp_kernel(const f16* __restrict__ Hbh,
                                                   const f16* __restrict__ woutt,
                                                   float* __restrict__ out) {
  const int rt = blockIdx.x, ctile = blockIdx.y;
  const int row0 = rt * 128, col0 = ctile * 128;
  const f16* Wt = woutt + (size_t)col0 * CHID;
  const int t = threadIdx.x;
  const int w = t >> 6, lane = t & 63, quad = lane >> 4, lcol = lane & 15;
  const int wr = w >> 1, wc = w & 1;

  __shared__ f16 Hs[128][64];  // unpadded (lds-dma), XOR-swizzled columns
  __shared__ f16 Ws[128][64];

  f32x4 acc[4][4];
#pragma unroll
  for (int i = 0; i < 4; ++i)
#pragma unroll
    for (int j = 0; j < 4; ++j) acc[i][j] = (f32x4){0.f, 0.f, 0.f, 0.f};

  for (int k0 = 0; k0 < CHID; k0 += 64) {
    __syncthreads();
#pragma unroll
    for (int i = 0; i < 4; ++i) {
      const int c = t + 256 * i, r = c >> 3, sg = c & 7;
      const int gsw = (sg ^ (r & 7)) * 8;
      gld16(&Hbh[(size_t)(row0 + r) * CHID + k0 + gsw],
            (char*)&Hs[0][0] + c * 16);
      gld16(&Wt[(size_t)r * CHID + k0 + gsw], (char*)&Ws[0][0] + c * 16);
    }
    __syncthreads();

    f16x8 bf0[4], bf1[4];
#pragma unroll
    for (int j = 0; j < 4; ++j) {
      const int br = wc * 64 + j * 16 + lcol;
      bf0[j] = *(const f16x8*)&Ws[br][(quad ^ (br & 7)) * 8];
      bf1[j] = *(const f16x8*)&Ws[br][((quad ^ 4) ^ (br & 7)) * 8];
    }
#pragma unroll
    for (int i = 0; i < 4; ++i) {
      const int ar = wr * 64 + i * 16 + lcol;
      const f16x8 af0 = *(const f16x8*)&Hs[ar][(quad ^ (ar & 7)) * 8];
      const f16x8 af1 = *(const f16x8*)&Hs[ar][((quad ^ 4) ^ (ar & 7)) * 8];
#pragma unroll
      for (int j = 0; j < 4; ++j) {
        acc[i][j] = mfma16(af0, bf0[j], acc[i][j]);
        acc[i][j] = mfma16(af1, bf1[j], acc[i][j]);
      }
    }
  }

#pragma unroll
  for (int i = 0; i < 4; ++i) {
#pragma unroll
    for (int rr = 0; rr < 4; ++rr) {
      const size_t rg = row0 + wr * 64 + i * 16 + quad * 4 + rr;
#pragma unroll
      for (int j = 0; j < 4; ++j)
        out[rg * CHID + col0 + wc * 64 + j * 16 + lcol] = acc[i][j][rr];
    }
  }
}

// ---------------------------------------------------------------------------
extern "C" void kernel_launch(void* const* d_in, const int* in_sizes, int n_in,
                              void* d_out, int out_size, void* d_ws,
                              size_t ws_size, hipStream_t stream) {
  const float* x = (const float*)d_in[0];
  const int* mask = (const int*)d_in[1];
  const float* Wq = (const float*)d_in[2];
  const float* Wk = (const float*)d_in[3];
  const float* Wv = (const float*)d_in[4];
  const float* Wout = (const float*)d_in[5];
  float* out = (float*)d_out;

  char* ws = (char*)d_ws;
  int* lens = (int*)ws;
  size_t off = 1024;
  const size_t NX = (size_t)CB * CS * CHID;   // 8,388,608
  const size_t NW = (size_t)CH * CHID * CDK;  // 262,144 per weight
  f16* xh = (f16*)(ws + off);    off += NX * 2;
  f16* wtAll = (f16*)(ws + off); off += NW * 4 * 2;
  f16* Qh = (f16*)(ws + off);    off += NX * 2;
  f16* Kh = (f16*)(ws + off);    off += NX * 2;
  f16* Vth = (f16*)(ws + off);   off += NX * 2;
  f16* Hbh = (f16*)(ws + off);   off += NX * 2;
  float* Vsum = (float*)(ws + off); off += (size_t)CB * CH * CDK * 4;
  f16* woutt = wtAll + NW * 3;

  prep_kernel<<<8208, 256, 0, stream>>>((const float4*)x, (f16x4*)xh, mask,
                                        lens, Vsum);
  cast_w_kernel<<<dim3(8, 32), 256, 0, stream>>>(Wq, Wk, Wv, Wout, wtAll);
  qkvf_kernel<<<dim3(12, 128), 256, 0, stream>>>(xh, wtAll, lens, Qh, Kh, Vth,
                                                 Vsum);
  attn_kernel<<<1024, 256, 0, stream>>>(Qh, Kh, Vth, lens, Vsum, Hbh);
  outp_kernel<<<dim3(128, 4), 256, 0, stream>>>(Hbh, woutt, out);
}

// Round 12
// 187.308 us; speedup vs baseline: 1.3225x; 1.0167x over previous
//
#include <hip/hip_runtime.h>
#include <math.h>

// QANetAttBlock: B=16, S=1024, HID=512, H=8, DK=64
constexpr int CB = 16;
constexpr int CS = 1024;
constexpr int CHID = 512;
constexpr int CH = 8;
constexpr int CDK = 64;

typedef _Float16 f16;
typedef __attribute__((ext_vector_type(8))) _Float16 f16x8;
typedef __attribute__((ext_vector_type(4))) _Float16 f16x4;
typedef __attribute__((ext_vector_type(4))) float f32x4;
typedef __attribute__((ext_vector_type(4))) unsigned int u32x4;
typedef __attribute__((ext_vector_type(2))) unsigned int u32x2;

__device__ inline f32x4 mfma16(f16x8 a, f16x8 b, f32x4 c) {
  return __builtin_amdgcn_mfma_f32_16x16x32_f16(a, b, c, 0, 0, 0);
}

// async global->LDS, 16B per lane; dest must be wave-uniform base + lane*16
__device__ inline void gld16(const void* g, void* l) {
  __builtin_amdgcn_global_load_lds(
      (const __attribute__((address_space(1))) void*)g,
      (__attribute__((address_space(3))) void*)l, 16, 0, 0);
}

// raw v_exp_f32 (2^x). libm exp2f costs ~10 extra VALU/call.
__device__ inline float fast_exp2(float x) {
#if __has_builtin(__builtin_amdgcn_exp2f)
  return __builtin_amdgcn_exp2f(x);
#else
  return __expf(x * 0.6931471805599453f);
#endif
}

// packed f32x2 -> f16x2 with round-to-nearest-even as a raw dword.
__device__ inline unsigned pack_rne(float a, float b) {
  union { f16 h[2]; unsigned u; } c;
  c.h[0] = (f16)a;
  c.h[1] = (f16)b;
  return c.u;
}

// 4x4 quad-transpose of two dwords via gfx950 permlane swaps.
// Rows (16-lane groups) in:  x=[X0,X1,X2,X3], y=[Y0,Y1,Y2,Y3]
// After p32 (dst-hi<->src-lo) + p16 (dst-odd<->src-even):
//   x=[X0,X2,Y0,Y2], y=[X1,X3,Y1,Y3].
// HAZARD NOTE (r1/r2 failure root cause): raw back-to-back permlane asm
// violates the "VALU write -> v_permlane* read needs a wait state" rule.
// The builtins let the compiler insert the required hazard nops.
__device__ inline void quad_transpose(unsigned& x, unsigned& y) {
#if __has_builtin(__builtin_amdgcn_permlane32_swap) && \
    __has_builtin(__builtin_amdgcn_permlane16_swap)
  u32x2 a = __builtin_amdgcn_permlane32_swap(x, y, false, false);
  u32x2 b = __builtin_amdgcn_permlane16_swap(a[0], a[1], false, false);
  x = b[0];
  y = b[1];
#else
  asm volatile(
      "s_nop 1\n\t"
      "v_permlane32_swap_b32 %0, %1\n\t"
      "s_nop 1\n\t"
      "v_permlane16_swap_b32 %0, %1\n\t"
      "s_nop 1"
      : "+v"(x), "+v"(y));
#endif
}

#define LOG2E 1.4426950408889634f

// ---------------------------------------------------------------------------
// prep: blocks 0..8191 cast x fp32->fp16; blocks 8192..8207 compute lens[b]
// and zero Vsum (ws is poisoned 0xAA).
// ---------------------------------------------------------------------------
__global__ __launch_bounds__(256) void prep_kernel(const float4* __restrict__ x,
                                                   f16x4* __restrict__ xh,
                                                   const int* __restrict__ mask,
                                                   int* __restrict__ lens,
                                                   float* __restrict__ Vsum) {
  const int bid = blockIdx.x, t = threadIdx.x;
  __shared__ int red[256];
  if (bid < 8192) {
    const int idx = bid * 256 + t;
    const float4 v = x[idx];
    f16x4 o;
    o[0] = (f16)v.x; o[1] = (f16)v.y; o[2] = (f16)v.z; o[3] = (f16)v.w;
    xh[idx] = o;
  } else {
    const int b = bid - 8192;
    const int g = b * 256 + t;
    Vsum[g * 2] = 0.f;
    Vsum[g * 2 + 1] = 0.f;
    int s = 0;
    for (int i = t; i < CS; i += 256) s += mask[b * CS + i];
    red[t] = s;
    __syncthreads();
    for (int off = 128; off > 0; off >>= 1) {
      if (t < off) red[t] += red[t + off];
      __syncthreads();
    }
    if (t == 0) lens[b] = red[0];
  }
}

// ---------------------------------------------------------------------------
// cast + transpose weights via LDS (coalesced fp32 reads).
// ---------------------------------------------------------------------------
__global__ __launch_bounds__(256) void cast_w_kernel(const float* __restrict__ Wq,
                                                     const float* __restrict__ Wk,
                                                     const float* __restrict__ Wv,
                                                     const float* __restrict__ Wout,
                                                     f16* __restrict__ wtAll) {
  const int y = blockIdx.y, kb = blockIdx.x, t = threadIdx.x;
  const int k0 = kb * 64;
  const float* src;
  int ldsrc;
  f16* dst;
  if (y < 24) {
    const int which = y >> 3, h = y & 7;
    const float* W = (which == 0) ? Wq : (which == 1) ? Wk : Wv;
    src = W + (size_t)h * 32768 + (size_t)k0 * 64;
    ldsrc = 64;
    dst = wtAll + (size_t)which * 262144 + (size_t)h * 32768;
  } else {
    const int c = y - 24;
    src = Wout + (size_t)k0 * 512 + c * 64;
    ldsrc = 512;
    dst = wtAll + (size_t)3 * 262144 + (size_t)c * 64 * 512;
  }

  __shared__ float Ts[64][68];
  {
    const int kr = t >> 4, cg = (t & 15) * 4;
#pragma unroll
    for (int rr = 0; rr < 4; ++rr) {
      const float4 v = *(const float4*)&src[(size_t)(rr * 16 + kr) * ldsrc + cg];
      Ts[rr * 16 + kr][cg] = v.x;
      Ts[rr * 16 + kr][cg + 1] = v.y;
      Ts[rr * 16 + kr][cg + 2] = v.z;
      Ts[rr * 16 + kr][cg + 3] = v.w;
    }
  }
  __syncthreads();
  {
    const int n = t >> 2, seg = t & 3;
    f16x8 a, b;
#pragma unroll
    for (int j = 0; j < 8; ++j) {
      a[j] = (f16)Ts[seg * 16 + j][n];
      b[j] = (f16)Ts[seg * 16 + 8 + j][n];
    }
    f16* d = &dst[(size_t)n * 512 + k0 + seg * 16];
    *(f16x8*)d = a;
    *(f16x8*)(d + 8) = b;
  }
}

// ---------------------------------------------------------------------------
// Fused QKV projection: 128x128 tile, BK=64, gld16 staging with XOR column
// swizzle. 1-D grid 1536, XCD-affine decode (v12): all 12 col-tile blocks
// of one row-panel land consecutively on ONE XCD -> the 128KB xh panel is
// fetched once per L2 instead of ~4x round-robin (r11: FETCH 70.8MB vs
// ~18MB ideal). Q pre-scaled by log2e/sqrt(n[b]); epilogues via padded Ts
// union, coalesced. V: fp32 col sums -> Vsum.
// ---------------------------------------------------------------------------
__global__ __launch_bounds__(256) void qkvf_kernel(
    const f16* __restrict__ xh, const f16* __restrict__ wtAll,
    const int* __restrict__ lens, f16* __restrict__ Qh, f16* __restrict__ Kh,
    f16* __restrict__ Vth, float* __restrict__ Vsum) {
  const int id = blockIdx.x;
  const int xcd = id & 7;          // XCD under %8 round-robin
  const int local = id >> 3;       // 0..191 within XCD
  const int ct = local % 12;       // col-tile: which*4 + hp
  const int rt = xcd * 16 + local / 12;  // row-tile 0..127, contiguous per XCD
  const int which = ct >> 2, hp = ct & 3;
  const f16* Wt = wtAll + (size_t)which * 262144 + (size_t)hp * 65536;
  const int row0 = rt * 128;
  const int b = row0 >> 10, s0 = row0 & 1023;
  const int h0 = hp * 2;
  const int t = threadIdx.x;
  const int w = t >> 6, lane = t & 63, quad = lane >> 4, lcol = lane & 15;
  const int wr = w >> 1, wc = w & 1;

  __shared__ union SM {
    struct { f16 Xs[128][64]; f16 Ws[128][64]; } a;  // unpadded (lds-dma)
    f16 Ts[128][136];                                // epilogue staging
  } sm;

  f32x4 acc[4][4];
#pragma unroll
  for (int i = 0; i < 4; ++i)
#pragma unroll
    for (int j = 0; j < 4; ++j) acc[i][j] = (f32x4){0.f, 0.f, 0.f, 0.f};

  for (int k0 = 0; k0 < CHID; k0 += 64) {
    __syncthreads();  // prior compute's LDS reads done
#pragma unroll
    for (int i = 0; i < 4; ++i) {
      const int c = t + 256 * i, r = c >> 3, sg = c & 7;
      const int gsw = (sg ^ (r & 7)) * 8;  // XOR swizzle on global source
      gld16(&xh[(size_t)(row0 + r) * CHID + k0 + gsw],
            (char*)&sm.a.Xs[0][0] + c * 16);
      gld16(&Wt[(size_t)r * CHID + k0 + gsw], (char*)&sm.a.Ws[0][0] + c * 16);
    }
    __syncthreads();  // drains vmcnt: LDS tiles ready

    f16x8 bf0[4], bf1[4];
#pragma unroll
    for (int j = 0; j < 4; ++j) {
      const int br = wc * 64 + j * 16 + lcol;
      bf0[j] = *(const f16x8*)&sm.a.Ws[br][(quad ^ (br & 7)) * 8];
      bf1[j] = *(const f16x8*)&sm.a.Ws[br][((quad ^ 4) ^ (br & 7)) * 8];
    }
#pragma unroll
    for (int i = 0; i < 4; ++i) {
      const int ar = wr * 64 + i * 16 + lcol;
      const f16x8 af0 = *(const f16x8*)&sm.a.Xs[ar][(quad ^ (ar & 7)) * 8];
      const f16x8 af1 =
          *(const f16x8*)&sm.a.Xs[ar][((quad ^ 4) ^ (ar & 7)) * 8];
#pragma unroll
      for (int j = 0; j < 4; ++j) {
        acc[i][j] = mfma16(af0, bf0[j], acc[i][j]);
        acc[i][j] = mfma16(af1, bf1[j], acc[i][j]);
      }
    }
  }

  if (which == 2) {
    // fp32 column sums -> Vsum (quad-reduced, register-only)
#pragma unroll
    for (int j = 0; j < 4; ++j) {
      float ps = 0.f;
#pragma unroll
      for (int i = 0; i < 4; ++i)
#pragma unroll
        for (int rr = 0; rr < 4; ++rr) ps += acc[i][j][rr];
      ps += __shfl_xor(ps, 16);
      ps += __shfl_xor(ps, 32);
      if (quad == 0) {
        const int d128 = wc * 64 + j * 16 + lcol;
        const int h = h0 + (d128 >> 6), d = d128 & 63;
        atomicAdd(&Vsum[((size_t)b * CH + h) * CDK + d], ps);
      }
    }
    // Ts[n][s]: packed f16x4 transpose writes, then coalesced V^T stores
    __syncthreads();
#pragma unroll
    for (int i = 0; i < 4; ++i)
#pragma unroll
      for (int j = 0; j < 4; ++j) {
        f16x4 v4;
#pragma unroll
        for (int rr = 0; rr < 4; ++rr) v4[rr] = (f16)acc[i][j][rr];
        *(f16x4*)&sm.Ts[wc * 64 + j * 16 + lcol][wr * 64 + i * 16 + quad * 4] =
            v4;
      }
    __syncthreads();
    const int c16 = t & 15;
#pragma unroll
    for (int p = 0; p < 8; ++p) {
      const int vr = p * 16 + (t >> 4);
      const int h = h0 + (vr >> 6), d = vr & 63;
      *(f16x8*)&Vth[(((size_t)b * CH + h) * CDK + d) * CS + s0 + c16 * 8] =
          *(const f16x8*)&sm.Ts[vr][c16 * 8];
    }
  } else {
    // Ts[s][n], then coalesced [B,H,S,64] stores (128-B runs)
    const float qsc = (which == 0) ? rsqrtf((float)lens[b]) * LOG2E : 1.0f;
    __syncthreads();
#pragma unroll
    for (int i = 0; i < 4; ++i)
#pragma unroll
      for (int j = 0; j < 4; ++j)
#pragma unroll
        for (int rr = 0; rr < 4; ++rr)
          sm.Ts[wr * 64 + i * 16 + quad * 4 + rr][wc * 64 + j * 16 + lcol] =
              (f16)(acc[i][j][rr] * qsc);
    __syncthreads();
    f16* O = (which == 0) ? Qh : Kh;
    const int c8 = t & 7;
#pragma unroll
    for (int p = 0; p < 4; ++p) {
      const int row = p * 32 + (t >> 3);
#pragma unroll
      for (int half = 0; half < 2; ++half) {
        const int h = h0 + half;
        *(f16x8*)&O[(((size_t)b * CH + h) * CS + s0 + row) * CDK + c8 * 8] =
            *(const f16x8*)&sm.Ts[row][half * 64 + c8 * 8];
      }
    }
  }
}

// ---------------------------------------------------------------------------
// Attention (MFMA flash, v11 — unchanged from r11, verified 44-45us):
//  * v5's 64-VGPR inner code: kb0/kb1 per set, pk/pv reg prefetch, dbuf
//    K/V, 1 barrier/tile, swapped QK^T, RNE pack + permlane quad-transpose,
//    MFMA row-sums, tail-split masking. NO setprio (r10/r11: s_setprio in
//    this barrier-locked block produced 70-90MB phantom WRITE + 26us).
//  * XCD decode: h=id&7, qt=(id>>3)&7 fastest, b=id>>6 (FETCH 113->31MB).
//  * 128-row blocks, grid 1024, 4 blocks/CU (LDS 147KB<160).
// ---------------------------------------------------------------------------
__global__ __launch_bounds__(256, 4) void attn_kernel(
    const f16* __restrict__ Qh, const f16* __restrict__ Kh,
    const f16* __restrict__ Vth, const int* __restrict__ lens,
    const float* __restrict__ Vsum, f16* __restrict__ Hbh) {
  const int id = blockIdx.x;
  const int h = id & 7;            // XCD index under %8 round-robin
  const int qt = (id >> 3) & 7;    // fastest on an XCD: same (b,h) panel
  const int b = id >> 6;           // 0..15
  const int n = lens[b];
  const int t = threadIdx.x, w = t >> 6, lane = t & 63, quad = lane >> 4,
            lcol = lane & 15;

  const size_t bh = ((size_t)b * CH + h) * CS;
  const size_t bhd = ((size_t)b * CH + h) * CDK;

  const int nt = (n + 63) >> 6;
  const int rem = n & 63;
  const int ntm = rem ? nt - 1 : nt;  // unmasked main tiles

  __shared__ union SM {
    struct { f16 Ks[2][64][72]; f16 Vs[2][64][72]; } kv;  // [buf][k|d][d|k]
    f16 St[4][32][72];  // epilogue staging (post-loop reuse)
  } sm;

  const int qbase = qt * 128 + w * 32;
  f16x8 qa[2][2];
#pragma unroll
  for (int set = 0; set < 2; ++set) {
    const size_t qr = bh + qbase + set * 16 + lcol;
    qa[set][0] = *(const f16x8*)&Qh[qr * CDK + quad * 8];
    qa[set][1] = *(const f16x8*)&Qh[qr * CDK + 32 + quad * 8];
  }

  f16x8 vones;
#pragma unroll
  for (int j = 0; j < 8; ++j) vones[j] = (f16)1.0f;

  f32x4 o[2][4];
#pragma unroll
  for (int set = 0; set < 2; ++set)
#pragma unroll
    for (int dt = 0; dt < 4; ++dt) o[set][dt] = (f32x4){0.f, 0.f, 0.f, 0.f};
  f32x4 o_l[2] = {(f32x4){0.f, 0.f, 0.f, 0.f}, (f32x4){0.f, 0.f, 0.f, 0.f}};

  // tile 0: load + stage into buffer 0
  f16x8 pk[2], pv[2];
#pragma unroll
  for (int i = 0; i < 2; ++i) {
    const int c = t + 256 * i, r = c >> 3, sg = c & 7;
    pk[i] = *(const f16x8*)&Kh[(bh + r) * CDK + sg * 8];
    pv[i] = *(const f16x8*)&Vth[(bhd + r) * CS + sg * 8];
  }
#pragma unroll
  for (int i = 0; i < 2; ++i) {
    const int c = t + 256 * i, r = c >> 3, sg = c & 7;
    *(f16x8*)&sm.kv.Ks[0][r][sg * 8] = pk[i];
    *(f16x8*)&sm.kv.Vs[0][r][sg * 8] = pv[i];
  }
  __syncthreads();

  auto ktile = [&](const int kt, const bool masked) __attribute__((always_inline)) {
    const int cur = kt & 1, nxt = cur ^ 1;
    // prefetch next tile into regs (clamped; uniform straight-line code)
    const int ktn = (kt + 1 < nt) ? kt + 1 : kt;
#pragma unroll
    for (int i = 0; i < 2; ++i) {
      const int c = t + 256 * i, r = c >> 3, sg = c & 7;
      pk[i] = *(const f16x8*)&Kh[(bh + ktn * 64 + r) * CDK + sg * 8];
      pv[i] = *(const f16x8*)&Vth[(bhd + r) * CS + ktn * 64 + sg * 8];
    }

    // swapped QK^T + exp + in-register P->A-frag transpose
    f16x8 pa[2][2];
#pragma unroll
    for (int set = 0; set < 2; ++set) {
      f32x4 st[4];
#pragma unroll
      for (int ct = 0; ct < 4; ++ct) {
        const f16x8 kb0 = *(const f16x8*)&sm.kv.Ks[cur][ct * 16 + lcol][quad * 8];
        const f16x8 kb1 =
            *(const f16x8*)&sm.kv.Ks[cur][ct * 16 + lcol][32 + quad * 8];
        st[ct] = mfma16(kb0, qa[set][0], (f32x4){0.f, 0.f, 0.f, 0.f});
        st[ct] = mfma16(kb1, qa[set][1], st[ct]);
      }
      unsigned pkd[4][2];
#pragma unroll
      for (int c = 0; c < 4; ++c) {
        float p[4];
#pragma unroll
        for (int r = 0; r < 4; ++r) {
          float e = fast_exp2(st[c][r]);
          if (masked) {
            const bool kvld = (kt * 64 + c * 16 + quad * 4 + r) < n;
            e = kvld ? e : 0.f;
          }
          p[r] = e;
        }
        pkd[c][0] = pack_rne(p[0], p[1]);
        pkd[c][1] = pack_rne(p[2], p[3]);
      }
      // quad-transpose: target quad t's dword j2 ends at k = 8t + 2*j2 + {0,1}
#pragma unroll
      for (int half = 0; half < 2; ++half) {
        unsigned x0 = pkd[2 * half][0], y0 = pkd[2 * half + 1][0];
        unsigned x1 = pkd[2 * half][1], y1 = pkd[2 * half + 1][1];
        quad_transpose(x0, y0);
        quad_transpose(x1, y1);
        union { u32x4 u; f16x8 h; } cc;
        cc.u = (u32x4){x0, x1, y0, y1};
        pa[set][half] = cc.h;
      }
    }

    // PV + row-sum MFMAs (P x ones = rowsum, lands directly in O-layout)
#pragma unroll
    for (int dt = 0; dt < 4; ++dt) {
      const f16x8 vb0 = *(const f16x8*)&sm.kv.Vs[cur][dt * 16 + lcol][quad * 8];
      const f16x8 vb1 =
          *(const f16x8*)&sm.kv.Vs[cur][dt * 16 + lcol][32 + quad * 8];
#pragma unroll
      for (int set = 0; set < 2; ++set) {
        o[set][dt] = mfma16(pa[set][0], vb0, o[set][dt]);
        o[set][dt] = mfma16(pa[set][1], vb1, o[set][dt]);
      }
    }
#pragma unroll
    for (int set = 0; set < 2; ++set) {
      o_l[set] = mfma16(pa[set][0], vones, o_l[set]);
      o_l[set] = mfma16(pa[set][1], vones, o_l[set]);
    }

    // stage next tile into the other buffer; one barrier covers both
    // write-visibility (buf nxt) and read-completion (buf cur)
#pragma unroll
    for (int i = 0; i < 2; ++i) {
      const int c = t + 256 * i, r = c >> 3, sg = c & 7;
      *(f16x8*)&sm.kv.Ks[nxt][r][sg * 8] = pk[i];
      *(f16x8*)&sm.kv.Vs[nxt][r][sg * 8] = pv[i];
    }
    __syncthreads();
  };

  int kt = 0;
  for (; kt < ntm; ++kt) ktile(kt, false);
  if (rem) ktile(kt, true);

  // per-lane inverse row-sums (already in O-layout: row quad*4+r, any col)
  float invl[2][4];
#pragma unroll
  for (int set = 0; set < 2; ++set)
#pragma unroll
    for (int r = 0; r < 4; ++r) invl[set][r] = 1.0f / o_l[set][r];

  // O -> wave-private St (f16), then coalesced 128-B-run stores.
  // (final loop barrier already fenced all K/V reads; St aliases kv)
#pragma unroll
  for (int set = 0; set < 2; ++set)
#pragma unroll
    for (int dt = 0; dt < 4; ++dt)
#pragma unroll
      for (int r = 0; r < 4; ++r) {
        const int srow_l = set * 16 + quad * 4 + r;
        const int d = dt * 16 + lcol;
        const float val = (qbase + srow_l < n)
                              ? o[set][dt][r] * invl[set][r]
                              : Vsum[bhd + d] * (1.0f / 1024.0f);
        sm.St[w][srow_l][d] = (f16)val;
      }
  {
    const int lr = lane >> 3, lc = lane & 7;
#pragma unroll
    for (int p = 0; p < 4; ++p) {
      const int row = p * 8 + lr;
      *(f16x8*)&Hbh[((size_t)b * CS + qbase + row) * (CH * CDK) + h * CDK +
                    lc * 8] = *(const f16x8*)&sm.St[w][row][lc * 8];
    }
  }
}

// ---------------------------------------------------------------------------
// Output projection: 128x128 tile, BK=64, gld16 + XOR swizzle (as qkvf).
// 1-D grid 512, XCD-affine decode (v12): the 4 ctile blocks of one Hbh
// row-panel land consecutively on ONE XCD; woutt (0.5MB) L2-resident.
// ---------------------------------------------------------------------------
__global__ __launch_bounds__(256) void outp_kernel(const f16* __restrict__ Hbh,
                                                   const f16* __restrict__ woutt,
                                                   float* __restrict__ out) {
  const int id = blockIdx.x;
  const int xcd = id & 7;
  const int local = id >> 3;            // 0..63 per XCD
  const int ctile = local & 3;
  const int rt = xcd * 16 + (local >> 2);  // 0..127, contiguous per XCD
  const int row0 = rt * 128, col0 = ctile * 128;
  const f16* Wt = woutt + (size_t)col0 * CHID;
  const int t = threadIdx.x;
  const int w = t >> 6, lane = t & 63, quad = lane >> 4, lcol = lane & 15;
  const int wr = w >> 1, wc = w & 1;

  __shared__ f16 Hs[128][64];  // unpadded (lds-dma), XOR-swizzled columns
  __shared__ f16 Ws[128][64];

  f32x4 acc[4][4];
#pragma unroll
  for (int i = 0; i < 4; ++i)
#pragma unroll
    for (int j = 0; j < 4; ++j) acc[i][j] = (f32x4){0.f, 0.f, 0.f, 0.f};

  for (int k0 = 0; k0 < CHID; k0 += 64) {
    __syncthreads();
#pragma unroll
    for (int i = 0; i < 4; ++i) {
      const int c = t + 256 * i, r = c >> 3, sg = c & 7;
      const int gsw = (sg ^ (r & 7)) * 8;
      gld16(&Hbh[(size_t)(row0 + r) * CHID + k0 + gsw],
            (char*)&Hs[0][0] + c * 16);
      gld16(&Wt[(size_t)r * CHID + k0 + gsw], (char*)&Ws[0][0] + c * 16);
    }
    __syncthreads();

    f16x8 bf0[4], bf1[4];
#pragma unroll
    for (int j = 0; j < 4; ++j) {
      const int br = wc * 64 + j * 16 + lcol;
      bf0[j] = *(const f16x8*)&Ws[br][(quad ^ (br & 7)) * 8];
      bf1[j] = *(const f16x8*)&Ws[br][((quad ^ 4) ^ (br & 7)) * 8];
    }
#pragma unroll
    for (int i = 0; i < 4; ++i) {
      const int ar = wr * 64 + i * 16 + lcol;
      const f16x8 af0 = *(const f16x8*)&Hs[ar][(quad ^ (ar & 7)) * 8];
      const f16x8 af1 = *(const f16x8*)&Hs[ar][((quad ^ 4) ^ (ar & 7)) * 8];
#pragma unroll
      for (int j = 0; j < 4; ++j) {
        acc[i][j] = mfma16(af0, bf0[j], acc[i][j]);
        acc[i][j] = mfma16(af1, bf1[j], acc[i][j]);
      }
    }
  }

#pragma unroll
  for (int i = 0; i < 4; ++i) {
#pragma unroll
    for (int rr = 0; rr < 4; ++rr) {
      const size_t rg = row0 + wr * 64 + i * 16 + quad * 4 + rr;
#pragma unroll
      for (int j = 0; j < 4; ++j)
        out[rg * CHID + col0 + wc * 64 + j * 16 + lcol] = acc[i][j][rr];
    }
  }
}

// ---------------------------------------------------------------------------
extern "C" void kernel_launch(void* const* d_in, const int* in_sizes, int n_in,
                              void* d_out, int out_size, void* d_ws,
                              size_t ws_size, hipStream_t stream) {
  const float* x = (const float*)d_in[0];
  const int* mask = (const int*)d_in[1];
  const float* Wq = (const float*)d_in[2];
  const float* Wk = (const float*)d_in[3];
  const float* Wv = (const float*)d_in[4];
  const float* Wout = (const float*)d_in[5];
  float* out = (float*)d_out;

  char* ws = (char*)d_ws;
  int* lens = (int*)ws;
  size_t off = 1024;
  const size_t NX = (size_t)CB * CS * CHID;   // 8,388,608
  const size_t NW = (size_t)CH * CHID * CDK;  // 262,144 per weight
  f16* xh = (f16*)(ws + off);    off += NX * 2;
  f16* wtAll = (f16*)(ws + off); off += NW * 4 * 2;
  f16* Qh = (f16*)(ws + off);    off += NX * 2;
  f16* Kh = (f16*)(ws + off);    off += NX * 2;
  f16* Vth = (f16*)(ws + off);   off += NX * 2;
  f16* Hbh = (f16*)(ws + off);   off += NX * 2;
  float* Vsum = (float*)(ws + off); off += (size_t)CB * CH * CDK * 4;
  f16* woutt = wtAll + NW * 3;

  prep_kernel<<<8208, 256, 0, stream>>>((const float4*)x, (f16x4*)xh, mask,
                                        lens, Vsum);
  cast_w_kernel<<<dim3(8, 32), 256, 0, stream>>>(Wq, Wk, Wv, Wout, wtAll);
  qkvf_kernel<<<1536, 256, 0, stream>>>(xh, wtAll, lens, Qh, Kh, Vth, Vsum);
  attn_kernel<<<1024, 256, 0, stream>>>(Qh, Kh, Vth, lens, Vsum, Hbh);
  outp_kernel<<<512, 256, 0, stream>>>(Hbh, woutt, out);
}

// Round 15
// 186.321 us; speedup vs baseline: 1.3295x; 1.0053x over previous
//
#include <hip/hip_runtime.h>
#include <math.h>

// QANetAttBlock: B=16, S=1024, HID=512, H=8, DK=64
constexpr int CB = 16;
constexpr int CS = 1024;
constexpr int CHID = 512;
constexpr int CH = 8;
constexpr int CDK = 64;

typedef _Float16 f16;
typedef __attribute__((ext_vector_type(8))) _Float16 f16x8;
typedef __attribute__((ext_vector_type(4))) _Float16 f16x4;
typedef __attribute__((ext_vector_type(4))) float f32x4;
typedef __attribute__((ext_vector_type(4))) unsigned int u32x4;
typedef __attribute__((ext_vector_type(2))) unsigned int u32x2;

__device__ inline f32x4 mfma16(f16x8 a, f16x8 b, f32x4 c) {
  return __builtin_amdgcn_mfma_f32_16x16x32_f16(a, b, c, 0, 0, 0);
}

// async global->LDS, 16B per lane; dest must be wave-uniform base + lane*16
__device__ inline void gld16(const void* g, void* l) {
  __builtin_amdgcn_global_load_lds(
      (const __attribute__((address_space(1))) void*)g,
      (__attribute__((address_space(3))) void*)l, 16, 0, 0);
}

// raw v_exp_f32 (2^x). libm exp2f costs ~10 extra VALU/call.
__device__ inline float fast_exp2(float x) {
#if __has_builtin(__builtin_amdgcn_exp2f)
  return __builtin_amdgcn_exp2f(x);
#else
  return __expf(x * 0.6931471805599453f);
#endif
}

// packed f32x2 -> f16x2 with round-to-nearest-even as a raw dword.
__device__ inline unsigned pack_rne(float a, float b) {
  union { f16 h[2]; unsigned u; } c;
  c.h[0] = (f16)a;
  c.h[1] = (f16)b;
  return c.u;
}

// 4x4 quad-transpose of two dwords via gfx950 permlane swaps.
// Rows (16-lane groups) in:  x=[X0,X1,X2,X3], y=[Y0,Y1,Y2,Y3]
// After p32 (dst-hi<->src-lo) + p16 (dst-odd<->src-even):
//   x=[X0,X2,Y0,Y2], y=[X1,X3,Y1,Y3].
// HAZARD NOTE (r1/r2 failure root cause): raw back-to-back permlane asm
// violates the "VALU write -> v_permlane* read needs a wait state" rule.
// The builtins let the compiler insert the required hazard nops.
__device__ inline void quad_transpose(unsigned& x, unsigned& y) {
#if __has_builtin(__builtin_amdgcn_permlane32_swap) && \
    __has_builtin(__builtin_amdgcn_permlane16_swap)
  u32x2 a = __builtin_amdgcn_permlane32_swap(x, y, false, false);
  u32x2 b = __builtin_amdgcn_permlane16_swap(a[0], a[1], false, false);
  x = b[0];
  y = b[1];
#else
  asm volatile(
      "s_nop 1\n\t"
      "v_permlane32_swap_b32 %0, %1\n\t"
      "s_nop 1\n\t"
      "v_permlane16_swap_b32 %0, %1\n\t"
      "s_nop 1"
      : "+v"(x), "+v"(y));
#endif
}

#define LOG2E 1.4426950408889634f

// ---------------------------------------------------------------------------
// prep: blocks 0..8191 cast x fp32->fp16; blocks 8192..8207 compute lens[b]
// and zero Vsum (ws is poisoned 0xAA).
// ---------------------------------------------------------------------------
__global__ __launch_bounds__(256) void prep_kernel(const float4* __restrict__ x,
                                                   f16x4* __restrict__ xh,
                                                   const int* __restrict__ mask,
                                                   int* __restrict__ lens,
                                                   float* __restrict__ Vsum) {
  const int bid = blockIdx.x, t = threadIdx.x;
  __shared__ int red[256];
  if (bid < 8192) {
    const int idx = bid * 256 + t;
    const float4 v = x[idx];
    f16x4 o;
    o[0] = (f16)v.x; o[1] = (f16)v.y; o[2] = (f16)v.z; o[3] = (f16)v.w;
    xh[idx] = o;
  } else {
    const int b = bid - 8192;
    const int g = b * 256 + t;
    Vsum[g * 2] = 0.f;
    Vsum[g * 2 + 1] = 0.f;
    int s = 0;
    for (int i = t; i < CS; i += 256) s += mask[b * CS + i];
    red[t] = s;
    __syncthreads();
    for (int off = 128; off > 0; off >>= 1) {
      if (t < off) red[t] += red[t + off];
      __syncthreads();
    }
    if (t == 0) lens[b] = red[0];
  }
}

// ---------------------------------------------------------------------------
// cast + transpose weights via LDS (coalesced fp32 reads).
// ---------------------------------------------------------------------------
__global__ __launch_bounds__(256) void cast_w_kernel(const float* __restrict__ Wq,
                                                     const float* __restrict__ Wk,
                                                     const float* __restrict__ Wv,
                                                     const float* __restrict__ Wout,
                                                     f16* __restrict__ wtAll) {
  const int y = blockIdx.y, kb = blockIdx.x, t = threadIdx.x;
  const int k0 = kb * 64;
  const float* src;
  int ldsrc;
  f16* dst;
  if (y < 24) {
    const int which = y >> 3, h = y & 7;
    const float* W = (which == 0) ? Wq : (which == 1) ? Wk : Wv;
    src = W + (size_t)h * 32768 + (size_t)k0 * 64;
    ldsrc = 64;
    dst = wtAll + (size_t)which * 262144 + (size_t)h * 32768;
  } else {
    const int c = y - 24;
    src = Wout + (size_t)k0 * 512 + c * 64;
    ldsrc = 512;
    dst = wtAll + (size_t)3 * 262144 + (size_t)c * 64 * 512;
  }

  __shared__ float Ts[64][68];
  {
    const int kr = t >> 4, cg = (t & 15) * 4;
#pragma unroll
    for (int rr = 0; rr < 4; ++rr) {
      const float4 v = *(const float4*)&src[(size_t)(rr * 16 + kr) * ldsrc + cg];
      Ts[rr * 16 + kr][cg] = v.x;
      Ts[rr * 16 + kr][cg + 1] = v.y;
      Ts[rr * 16 + kr][cg + 2] = v.z;
      Ts[rr * 16 + kr][cg + 3] = v.w;
    }
  }
  __syncthreads();
  {
    const int n = t >> 2, seg = t & 3;
    f16x8 a, b;
#pragma unroll
    for (int j = 0; j < 8; ++j) {
      a[j] = (f16)Ts[seg * 16 + j][n];
      b[j] = (f16)Ts[seg * 16 + 8 + j][n];
    }
    f16* d = &dst[(size_t)n * 512 + k0 + seg * 16];
    *(f16x8*)d = a;
    *(f16x8*)(d + 8) = b;
  }
}

// ---------------------------------------------------------------------------
// Fused QKV projection v13: ct-PAIRED 128x256 tiles, BK=64.
// r12 analysis: qkvf = m97-structure GEMM at effective N~1850 -> 288 TF,
// exactly on the m102 shape curve; short K (8 k-steps) makes the per-step
// barrier drain dominate. Fix: each block computes TWO adjacent col-tiles
// (one `which`, hp pair) -> per k-step stage Xs ONCE + Ws0 + Ws1, then
// 128 MFMAs per barrier (was 64). Staging/MFMA drops 2.7x; X-traffic halves.
// grid 768 (xcd=id&7, pr=local%6, rt=xcd*16+local/6 -- XCD-affine kept).
// acc[2][4][4]=128 VGPR; launch_bounds(256,2) caps 256 (r9 spill lesson:
// watch WRITE_SIZE). LDS 48KB (Xs+Ws[2] / Ts union), 2 blocks/CU.
// Epilogues run per-j sequentially through the shared Ts union.
// ---------------------------------------------------------------------------
__global__ __launch_bounds__(256, 2) void qkvf_kernel(
    const f16* __restrict__ xh, const f16* __restrict__ wtAll,
    const int* __restrict__ lens, f16* __restrict__ Qh, f16* __restrict__ Kh,
    f16* __restrict__ Vth, float* __restrict__ Vsum) {
  const int id = blockIdx.x;
  const int xcd = id & 7;                 // XCD under %8 round-robin
  const int local = id >> 3;              // 0..95 within XCD
  const int pr = local % 6;               // ct-pair index
  const int rt = xcd * 16 + local / 6;    // row-tile 0..127, contiguous/XCD
  const int ct0 = pr * 2;                 // pair covers ct0, ct0+1
  const int which = ct0 >> 2;             // uniform across the pair
  const f16* Wt0 = wtAll + (size_t)which * 262144 + (size_t)(ct0 & 3) * 65536;
  const f16* Wt1 =
      wtAll + (size_t)which * 262144 + (size_t)((ct0 + 1) & 3) * 65536;
  const int row0 = rt * 128;
  const int b = row0 >> 10, s0 = row0 & 1023;
  const int t = threadIdx.x;
  const int w = t >> 6, lane = t & 63, quad = lane >> 4, lcol = lane & 15;
  const int wr = w >> 1, wc = w & 1;

  __shared__ union SM {
    struct { f16 Xs[128][64]; f16 Ws[2][128][64]; } a;  // unpadded (lds-dma)
    f16 Ts[128][136];                                   // epilogue staging
  } sm;

  f32x4 acc[2][4][4];
#pragma unroll
  for (int j = 0; j < 2; ++j)
#pragma unroll
    for (int i = 0; i < 4; ++i)
#pragma unroll
      for (int jj = 0; jj < 4; ++jj) acc[j][i][jj] = (f32x4){0.f, 0.f, 0.f, 0.f};

  for (int k0 = 0; k0 < CHID; k0 += 64) {
    __syncthreads();  // prior compute's LDS reads done
#pragma unroll
    for (int i = 0; i < 4; ++i) {
      const int c = t + 256 * i, r = c >> 3, sg = c & 7;
      const int gsw = (sg ^ (r & 7)) * 8;  // XOR swizzle on global source
      gld16(&xh[(size_t)(row0 + r) * CHID + k0 + gsw],
            (char*)&sm.a.Xs[0][0] + c * 16);
      gld16(&Wt0[(size_t)r * CHID + k0 + gsw],
            (char*)&sm.a.Ws[0][0][0] + c * 16);
      gld16(&Wt1[(size_t)r * CHID + k0 + gsw],
            (char*)&sm.a.Ws[1][0][0] + c * 16);
    }
    __syncthreads();  // drains vmcnt: LDS tiles ready

#pragma unroll
    for (int j = 0; j < 2; ++j) {
      f16x8 bf0[4], bf1[4];
#pragma unroll
      for (int jj = 0; jj < 4; ++jj) {
        const int br = wc * 64 + jj * 16 + lcol;
        bf0[jj] = *(const f16x8*)&sm.a.Ws[j][br][(quad ^ (br & 7)) * 8];
        bf1[jj] = *(const f16x8*)&sm.a.Ws[j][br][((quad ^ 4) ^ (br & 7)) * 8];
      }
#pragma unroll
      for (int i = 0; i < 4; ++i) {
        const int ar = wr * 64 + i * 16 + lcol;
        const f16x8 af0 = *(const f16x8*)&sm.a.Xs[ar][(quad ^ (ar & 7)) * 8];
        const f16x8 af1 =
            *(const f16x8*)&sm.a.Xs[ar][((quad ^ 4) ^ (ar & 7)) * 8];
#pragma unroll
        for (int jj = 0; jj < 4; ++jj) {
          acc[j][i][jj] = mfma16(af0, bf0[jj], acc[j][i][jj]);
          acc[j][i][jj] = mfma16(af1, bf1[jj], acc[j][i][jj]);
        }
      }
    }
  }

  // epilogues: one per paired col-tile, sequential through the Ts union
#pragma unroll
  for (int j = 0; j < 2; ++j) {
    const int hp = (ct0 + j) & 3;
    const int h0 = hp * 2;
    if (which == 2) {
      // fp32 column sums -> Vsum (quad-reduced, register-only)
#pragma unroll
      for (int jj = 0; jj < 4; ++jj) {
        float ps = 0.f;
#pragma unroll
        for (int i = 0; i < 4; ++i)
#pragma unroll
          for (int rr = 0; rr < 4; ++rr) ps += acc[j][i][jj][rr];
        ps += __shfl_xor(ps, 16);
        ps += __shfl_xor(ps, 32);
        if (quad == 0) {
          const int d128 = wc * 64 + jj * 16 + lcol;
          const int h = h0 + (d128 >> 6), d = d128 & 63;
          atomicAdd(&Vsum[((size_t)b * CH + h) * CDK + d], ps);
        }
      }
      // Ts[n][s]: packed f16x4 transpose writes, then coalesced V^T stores
      __syncthreads();
#pragma unroll
      for (int i = 0; i < 4; ++i)
#pragma unroll
        for (int jj = 0; jj < 4; ++jj) {
          f16x4 v4;
#pragma unroll
          for (int rr = 0; rr < 4; ++rr) v4[rr] = (f16)acc[j][i][jj][rr];
          *(f16x4*)&sm.Ts[wc * 64 + jj * 16 + lcol]
                         [wr * 64 + i * 16 + quad * 4] = v4;
        }
      __syncthreads();
      const int c16 = t & 15;
#pragma unroll
      for (int p = 0; p < 8; ++p) {
        const int vr = p * 16 + (t >> 4);
        const int h = h0 + (vr >> 6), d = vr & 63;
        *(f16x8*)&Vth[(((size_t)b * CH + h) * CDK + d) * CS + s0 + c16 * 8] =
            *(const f16x8*)&sm.Ts[vr][c16 * 8];
      }
    } else {
      // Ts[s][n], then coalesced [B,H,S,64] stores (128-B runs)
      const float qsc = (which == 0) ? rsqrtf((float)lens[b]) * LOG2E : 1.0f;
      __syncthreads();
#pragma unroll
      for (int i = 0; i < 4; ++i)
#pragma unroll
        for (int jj = 0; jj < 4; ++jj)
#pragma unroll
          for (int rr = 0; rr < 4; ++rr)
            sm.Ts[wr * 64 + i * 16 + quad * 4 + rr][wc * 64 + jj * 16 + lcol] =
                (f16)(acc[j][i][jj][rr] * qsc);
      __syncthreads();
      f16* O = (which == 0) ? Qh : Kh;
      const int c8 = t & 7;
#pragma unroll
      for (int p = 0; p < 4; ++p) {
        const int row = p * 32 + (t >> 3);
#pragma unroll
        for (int half = 0; half < 2; ++half) {
          const int h = h0 + half;
          *(f16x8*)&O[(((size_t)b * CH + h) * CS + s0 + row) * CDK + c8 * 8] =
              *(const f16x8*)&sm.Ts[row][half * 64 + c8 * 8];
        }
      }
    }
  }
}

// ---------------------------------------------------------------------------
// Attention (MFMA flash, v11 — unchanged, verified 44us):
//  * v5's 64-VGPR inner code: kb0/kb1 per set, pk/pv reg prefetch, dbuf
//    K/V, 1 barrier/tile, swapped QK^T, RNE pack + permlane quad-transpose,
//    MFMA row-sums, tail-split masking. NO setprio (r10/r11: s_setprio in
//    this barrier-locked block produced 70-90MB phantom WRITE + 26us).
//  * XCD decode: h=id&7, qt=(id>>3)&7 fastest, b=id>>6 (FETCH 113->23MB).
//  * 128-row blocks, grid 1024, 4 blocks/CU (LDS 147KB<160).
// ---------------------------------------------------------------------------
__global__ __launch_bounds__(256, 4) void attn_kernel(
    const f16* __restrict__ Qh, const f16* __restrict__ Kh,
    const f16* __restrict__ Vth, const int* __restrict__ lens,
    const float* __restrict__ Vsum, f16* __restrict__ Hbh) {
  const int id = blockIdx.x;
  const int h = id & 7;            // XCD index under %8 round-robin
  const int qt = (id >> 3) & 7;    // fastest on an XCD: same (b,h) panel
  const int b = id >> 6;           // 0..15
  const int n = lens[b];
  const int t = threadIdx.x, w = t >> 6, lane = t & 63, quad = lane >> 4,
            lcol = lane & 15;

  const size_t bh = ((size_t)b * CH + h) * CS;
  const size_t bhd = ((size_t)b * CH + h) * CDK;

  const int nt = (n + 63) >> 6;
  const int rem = n & 63;
  const int ntm = rem ? nt - 1 : nt;  // unmasked main tiles

  __shared__ union SM {
    struct { f16 Ks[2][64][72]; f16 Vs[2][64][72]; } kv;  // [buf][k|d][d|k]
    f16 St[4][32][72];  // epilogue staging (post-loop reuse)
  } sm;

  const int qbase = qt * 128 + w * 32;
  f16x8 qa[2][2];
#pragma unroll
  for (int set = 0; set < 2; ++set) {
    const size_t qr = bh + qbase + set * 16 + lcol;
    qa[set][0] = *(const f16x8*)&Qh[qr * CDK + quad * 8];
    qa[set][1] = *(const f16x8*)&Qh[qr * CDK + 32 + quad * 8];
  }

  f16x8 vones;
#pragma unroll
  for (int j = 0; j < 8; ++j) vones[j] = (f16)1.0f;

  f32x4 o[2][4];
#pragma unroll
  for (int set = 0; set < 2; ++set)
#pragma unroll
    for (int dt = 0; dt < 4; ++dt) o[set][dt] = (f32x4){0.f, 0.f, 0.f, 0.f};
  f32x4 o_l[2] = {(f32x4){0.f, 0.f, 0.f, 0.f}, (f32x4){0.f, 0.f, 0.f, 0.f}};

  // tile 0: load + stage into buffer 0
  f16x8 pk[2], pv[2];
#pragma unroll
  for (int i = 0; i < 2; ++i) {
    const int c = t + 256 * i, r = c >> 3, sg = c & 7;
    pk[i] = *(const f16x8*)&Kh[(bh + r) * CDK + sg * 8];
    pv[i] = *(const f16x8*)&Vth[(bhd + r) * CS + sg * 8];
  }
#pragma unroll
  for (int i = 0; i < 2; ++i) {
    const int c = t + 256 * i, r = c >> 3, sg = c & 7;
    *(f16x8*)&sm.kv.Ks[0][r][sg * 8] = pk[i];
    *(f16x8*)&sm.kv.Vs[0][r][sg * 8] = pv[i];
  }
  __syncthreads();

  auto ktile = [&](const int kt, const bool masked) __attribute__((always_inline)) {
    const int cur = kt & 1, nxt = cur ^ 1;
    // prefetch next tile into regs (clamped; uniform straight-line code)
    const int ktn = (kt + 1 < nt) ? kt + 1 : kt;
#pragma unroll
    for (int i = 0; i < 2; ++i) {
      const int c = t + 256 * i, r = c >> 3, sg = c & 7;
      pk[i] = *(const f16x8*)&Kh[(bh + ktn * 64 + r) * CDK + sg * 8];
      pv[i] = *(const f16x8*)&Vth[(bhd + r) * CS + ktn * 64 + sg * 8];
    }

    // swapped QK^T + exp + in-register P->A-frag transpose
    f16x8 pa[2][2];
#pragma unroll
    for (int set = 0; set < 2; ++set) {
      f32x4 st[4];
#pragma unroll
      for (int ct = 0; ct < 4; ++ct) {
        const f16x8 kb0 = *(const f16x8*)&sm.kv.Ks[cur][ct * 16 + lcol][quad * 8];
        const f16x8 kb1 =
            *(const f16x8*)&sm.kv.Ks[cur][ct * 16 + lcol][32 + quad * 8];
        st[ct] = mfma16(kb0, qa[set][0], (f32x4){0.f, 0.f, 0.f, 0.f});
        st[ct] = mfma16(kb1, qa[set][1], st[ct]);
      }
      unsigned pkd[4][2];
#pragma unroll
      for (int c = 0; c < 4; ++c) {
        float p[4];
#pragma unroll
        for (int r = 0; r < 4; ++r) {
          float e = fast_exp2(st[c][r]);
          if (masked) {
            const bool kvld = (kt * 64 + c * 16 + quad * 4 + r) < n;
            e = kvld ? e : 0.f;
          }
          p[r] = e;
        }
        pkd[c][0] = pack_rne(p[0], p[1]);
        pkd[c][1] = pack_rne(p[2], p[3]);
      }
      // quad-transpose: target quad t's dword j2 ends at k = 8t + 2*j2 + {0,1}
#pragma unroll
      for (int half = 0; half < 2; ++half) {
        unsigned x0 = pkd[2 * half][0], y0 = pkd[2 * half + 1][0];
        unsigned x1 = pkd[2 * half][1], y1 = pkd[2 * half + 1][1];
        quad_transpose(x0, y0);
        quad_transpose(x1, y1);
        union { u32x4 u; f16x8 h; } cc;
        cc.u = (u32x4){x0, x1, y0, y1};
        pa[set][half] = cc.h;
      }
    }

    // PV + row-sum MFMAs (P x ones = rowsum, lands directly in O-layout)
#pragma unroll
    for (int dt = 0; dt < 4; ++dt) {
      const f16x8 vb0 = *(const f16x8*)&sm.kv.Vs[cur][dt * 16 + lcol][quad * 8];
      const f16x8 vb1 =
          *(const f16x8*)&sm.kv.Vs[cur][dt * 16 + lcol][32 + quad * 8];
#pragma unroll
      for (int set = 0; set < 2; ++set) {
        o[set][dt] = mfma16(pa[set][0], vb0, o[set][dt]);
        o[set][dt] = mfma16(pa[set][1], vb1, o[set][dt]);
      }
    }
#pragma unroll
    for (int set = 0; set < 2; ++set) {
      o_l[set] = mfma16(pa[set][0], vones, o_l[set]);
      o_l[set] = mfma16(pa[set][1], vones, o_l[set]);
    }

    // stage next tile into the other buffer; one barrier covers both
    // write-visibility (buf nxt) and read-completion (buf cur)
#pragma unroll
    for (int i = 0; i < 2; ++i) {
      const int c = t + 256 * i, r = c >> 3, sg = c & 7;
      *(f16x8*)&sm.kv.Ks[nxt][r][sg * 8] = pk[i];
      *(f16x8*)&sm.kv.Vs[nxt][r][sg * 8] = pv[i];
    }
    __syncthreads();
  };

  int kt = 0;
  for (; kt < ntm; ++kt) ktile(kt, false);
  if (rem) ktile(kt, true);

  // per-lane inverse row-sums (already in O-layout: row quad*4+r, any col)
  float invl[2][4];
#pragma unroll
  for (int set = 0; set < 2; ++set)
#pragma unroll
    for (int r = 0; r < 4; ++r) invl[set][r] = 1.0f / o_l[set][r];

  // O -> wave-private St (f16), then coalesced 128-B-run stores.
  // (final loop barrier already fenced all K/V reads; St aliases kv)
#pragma unroll
  for (int set = 0; set < 2; ++set)
#pragma unroll
    for (int dt = 0; dt < 4; ++dt)
#pragma unroll
      for (int r = 0; r < 4; ++r) {
        const int srow_l = set * 16 + quad * 4 + r;
        const int d = dt * 16 + lcol;
        const float val = (qbase + srow_l < n)
                              ? o[set][dt][r] * invl[set][r]
                              : Vsum[bhd + d] * (1.0f / 1024.0f);
        sm.St[w][srow_l][d] = (f16)val;
      }
  {
    const int lr = lane >> 3, lc = lane & 7;
#pragma unroll
    for (int p = 0; p < 4; ++p) {
      const int row = p * 8 + lr;
      *(f16x8*)&Hbh[((size_t)b * CS + qbase + row) * (CH * CDK) + h * CDK +
                    lc * 8] = *(const f16x8*)&sm.St[w][row][lc * 8];
    }
  }
}

// ---------------------------------------------------------------------------
// Output projection: 128x128 tile, BK=64, gld16 + XOR swizzle (as qkvf).
// 1-D grid 512, XCD-affine decode: the 4 ctile blocks of one Hbh row-panel
// land consecutively on ONE XCD; woutt (0.5MB) L2-resident.
// ---------------------------------------------------------------------------
__global__ __launch_bounds__(256) void outp_kernel(const f16* __restrict__ Hbh,
                                                   const f16* __restrict__ woutt,
                                                   float* __restrict__ out) {
  const int id = blockIdx.x;
  const int xcd = id & 7;
  const int local = id >> 3;            // 0..63 per XCD
  const int ctile = local & 3;
  const int rt = xcd * 16 + (local >> 2);  // 0..127, contiguous per XCD
  const int row0 = rt * 128, col0 = ctile * 128;
  const f16* Wt = woutt + (size_t)col0 * CHID;
  const int t = threadIdx.x;
  const int w = t >> 6, lane = t & 63, quad = lane >> 4, lcol = lane & 15;
  const int wr = w >> 1, wc = w & 1;

  __shared__ f16 Hs[128][64];  // unpadded (lds-dma), XOR-swizzled columns
  __shared__ f16 Ws[128][64];

  f32x4 acc[4][4];
#pragma unroll
  for (int i = 0; i < 4; ++i)
#pragma unroll
    for (int j = 0; j < 4; ++j) acc[i][j] = (f32x4){0.f, 0.f, 0.f, 0.f};

  for (int k0 = 0; k0 < CHID; k0 += 64) {
    __syncthreads();
#pragma unroll
    for (int i = 0; i < 4; ++i) {
      const int c = t + 256 * i, r = c >> 3, sg = c & 7;
      const int gsw = (sg ^ (r & 7)) * 8;
      gld16(&Hbh[(size_t)(row0 + r) * CHID + k0 + gsw],
            (char*)&Hs[0][0] + c * 16);
      gld16(&Wt[(size_t)r * CHID + k0 + gsw], (char*)&Ws[0][0] + c * 16);
    }
    __syncthreads();

    f16x8 bf0[4], bf1[4];
#pragma unroll
    for (int j = 0; j < 4; ++j) {
      const int br = wc * 64 + j * 16 + lcol;
      bf0[j] = *(const f16x8*)&Ws[br][(quad ^ (br & 7)) * 8];
      bf1[j] = *(const f16x8*)&Ws[br][((quad ^ 4) ^ (br & 7)) * 8];
    }
#pragma unroll
    for (int i = 0; i < 4; ++i) {
      const int ar = wr * 64 + i * 16 + lcol;
      const f16x8 af0 = *(const f16x8*)&Hs[ar][(quad ^ (ar & 7)) * 8];
      const f16x8 af1 = *(const f16x8*)&Hs[ar][((quad ^ 4) ^ (ar & 7)) * 8];
#pragma unroll
      for (int j = 0; j < 4; ++j) {
        acc[i][j] = mfma16(af0, bf0[j], acc[i][j]);
        acc[i][j] = mfma16(af1, bf1[j], acc[i][j]);
      }
    }
  }

#pragma unroll
  for (int i = 0; i < 4; ++i) {
#pragma unroll
    for (int rr = 0; rr < 4; ++rr) {
      const size_t rg = row0 + wr * 64 + i * 16 + quad * 4 + rr;
#pragma unroll
      for (int j = 0; j < 4; ++j)
        out[rg * CHID + col0 + wc * 64 + j * 16 + lcol] = acc[i][j][rr];
    }
  }
}

// ---------------------------------------------------------------------------
extern "C" void kernel_launch(void* const* d_in, const int* in_sizes, int n_in,
                              void* d_out, int out_size, void* d_ws,
                              size_t ws_size, hipStream_t stream) {
  const float* x = (const float*)d_in[0];
  const int* mask = (const int*)d_in[1];
  const float* Wq = (const float*)d_in[2];
  const float* Wk = (const float*)d_in[3];
  const float* Wv = (const float*)d_in[4];
  const float* Wout = (const float*)d_in[5];
  float* out = (float*)d_out;

  char* ws = (char*)d_ws;
  int* lens = (int*)ws;
  size_t off = 1024;
  const size_t NX = (size_t)CB * CS * CHID;   // 8,388,608
  const size_t NW = (size_t)CH * CHID * CDK;  // 262,144 per weight
  f16* xh = (f16*)(ws + off);    off += NX * 2;
  f16* wtAll = (f16*)(ws + off); off += NW * 4 * 2;
  f16* Qh = (f16*)(ws + off);    off += NX * 2;
  f16* Kh = (f16*)(ws + off);    off += NX * 2;
  f16* Vth = (f16*)(ws + off);   off += NX * 2;
  f16* Hbh = (f16*)(ws + off);   off += NX * 2;
  float* Vsum = (float*)(ws + off); off += (size_t)CB * CH * CDK * 4;
  f16* woutt = wtAll + NW * 3;

  prep_kernel<<<8208, 256, 0, stream>>>((const float4*)x, (f16x4*)xh, mask,
                                        lens, Vsum);
  cast_w_kernel<<<dim3(8, 32), 256, 0, stream>>>(Wq, Wk, Wv, Wout, wtAll);
  qkvf_kernel<<<768, 256, 0, stream>>>(xh, wtAll, lens, Qh, Kh, Vth, Vsum);
  attn_kernel<<<1024, 256, 0, stream>>>(Qh, Kh, Vth, lens, Vsum, Hbh);
  outp_kernel<<<512, 256, 0, stream>>>(Hbh, woutt, out);
}

// Round 17
// 183.516 us; speedup vs baseline: 1.3499x; 1.0153x over previous
//
#include <hip/hip_runtime.h>
#include <math.h>

// QANetAttBlock: B=16, S=1024, HID=512, H=8, DK=64
constexpr int CB = 16;
constexpr int CS = 1024;
constexpr int CHID = 512;
constexpr int CH = 8;
constexpr int CDK = 64;

typedef _Float16 f16;
typedef __attribute__((ext_vector_type(8))) _Float16 f16x8;
typedef __attribute__((ext_vector_type(4))) _Float16 f16x4;
typedef __attribute__((ext_vector_type(4))) float f32x4;
typedef __attribute__((ext_vector_type(4))) unsigned int u32x4;
typedef __attribute__((ext_vector_type(2))) unsigned int u32x2;

__device__ inline f32x4 mfma16(f16x8 a, f16x8 b, f32x4 c) {
  return __builtin_amdgcn_mfma_f32_16x16x32_f16(a, b, c, 0, 0, 0);
}

// async global->LDS, 16B per lane; dest must be wave-uniform base + lane*16
__device__ inline void gld16(const void* g, void* l) {
  __builtin_amdgcn_global_load_lds(
      (const __attribute__((address_space(1))) void*)g,
      (__attribute__((address_space(3))) void*)l, 16, 0, 0);
}

// raw v_exp_f32 (2^x). libm exp2f costs ~10 extra VALU/call.
__device__ inline float fast_exp2(float x) {
#if __has_builtin(__builtin_amdgcn_exp2f)
  return __builtin_amdgcn_exp2f(x);
#else
  return __expf(x * 0.6931471805599453f);
#endif
}

// packed f32x2 -> f16x2 with round-to-nearest-even as a raw dword.
__device__ inline unsigned pack_rne(float a, float b) {
  union { f16 h[2]; unsigned u; } c;
  c.h[0] = (f16)a;
  c.h[1] = (f16)b;
  return c.u;
}

// 4x4 quad-transpose of two dwords via gfx950 permlane swaps.
// Rows (16-lane groups) in:  x=[X0,X1,X2,X3], y=[Y0,Y1,Y2,Y3]
// After p32 (dst-hi<->src-lo) + p16 (dst-odd<->src-even):
//   x=[X0,X2,Y0,Y2], y=[X1,X3,Y1,Y3].
// HAZARD NOTE (r1/r2 failure root cause): raw back-to-back permlane asm
// violates the "VALU write -> v_permlane* read needs a wait state" rule.
// The builtins let the compiler insert the required hazard nops.
__device__ inline void quad_transpose(unsigned& x, unsigned& y) {
#if __has_builtin(__builtin_amdgcn_permlane32_swap) && \
    __has_builtin(__builtin_amdgcn_permlane16_swap)
  u32x2 a = __builtin_amdgcn_permlane32_swap(x, y, false, false);
  u32x2 b = __builtin_amdgcn_permlane16_swap(a[0], a[1], false, false);
  x = b[0];
  y = b[1];
#else
  asm volatile(
      "s_nop 1\n\t"
      "v_permlane32_swap_b32 %0, %1\n\t"
      "s_nop 1\n\t"
      "v_permlane16_swap_b32 %0, %1\n\t"
      "s_nop 1"
      : "+v"(x), "+v"(y));
#endif
}

#define LOG2E 1.4426950408889634f

// ---------------------------------------------------------------------------
// fused prep + cast_w (v15: one launch instead of two; the 256 cast_w
// blocks hide under prep's 8192-block tail):
//   blocks 0..8191   : cast x fp32->fp16 (coalesced float4 -> f16x4)
//   blocks 8192..8447: weight cast+transpose via LDS (kb=local&7, y=local>>3)
//   blocks 8448..8463: lens[b] reduction + Vsum zero (ws poisoned 0xAA)
// ---------------------------------------------------------------------------
__global__ __launch_bounds__(256) void prep_kernel(
    const float4* __restrict__ x, f16x4* __restrict__ xh,
    const int* __restrict__ mask, int* __restrict__ lens,
    float* __restrict__ Vsum, const float* __restrict__ Wq,
    const float* __restrict__ Wk, const float* __restrict__ Wv,
    const float* __restrict__ Wout, f16* __restrict__ wtAll) {
  const int bid = blockIdx.x, t = threadIdx.x;
  __shared__ union {
    int red[256];
    float Ts[64][68];
  } u;
  if (bid < 8192) {
    const int idx = bid * 256 + t;
    const float4 v = x[idx];
    f16x4 o;
    o[0] = (f16)v.x; o[1] = (f16)v.y; o[2] = (f16)v.z; o[3] = (f16)v.w;
    xh[idx] = o;
  } else if (bid < 8448) {
    // cast_w body (verified): decode local block -> (kb, y)
    const int local = bid - 8192;
    const int kb = local & 7, y = local >> 3;
    const int k0 = kb * 64;
    const float* src;
    int ldsrc;
    f16* dst;
    if (y < 24) {
      const int which = y >> 3, h = y & 7;
      const float* W = (which == 0) ? Wq : (which == 1) ? Wk : Wv;
      src = W + (size_t)h * 32768 + (size_t)k0 * 64;
      ldsrc = 64;
      dst = wtAll + (size_t)which * 262144 + (size_t)h * 32768;
    } else {
      const int c = y - 24;
      src = Wout + (size_t)k0 * 512 + c * 64;
      ldsrc = 512;
      dst = wtAll + (size_t)3 * 262144 + (size_t)c * 64 * 512;
    }
    {
      const int kr = t >> 4, cg = (t & 15) * 4;
#pragma unroll
      for (int rr = 0; rr < 4; ++rr) {
        const float4 v =
            *(const float4*)&src[(size_t)(rr * 16 + kr) * ldsrc + cg];
        u.Ts[rr * 16 + kr][cg] = v.x;
        u.Ts[rr * 16 + kr][cg + 1] = v.y;
        u.Ts[rr * 16 + kr][cg + 2] = v.z;
        u.Ts[rr * 16 + kr][cg + 3] = v.w;
      }
    }
    __syncthreads();
    {
      const int n = t >> 2, seg = t & 3;
      f16x8 a, b;
#pragma unroll
      for (int j = 0; j < 8; ++j) {
        a[j] = (f16)u.Ts[seg * 16 + j][n];
        b[j] = (f16)u.Ts[seg * 16 + 8 + j][n];
      }
      f16* d = &dst[(size_t)n * 512 + k0 + seg * 16];
      *(f16x8*)d = a;
      *(f16x8*)(d + 8) = b;
    }
  } else {
    const int b = bid - 8448;
    const int g = b * 256 + t;
    Vsum[g * 2] = 0.f;
    Vsum[g * 2 + 1] = 0.f;
    int s = 0;
    for (int i = t; i < CS; i += 256) s += mask[b * CS + i];
    u.red[t] = s;
    __syncthreads();
    for (int off = 128; off > 0; off >>= 1) {
      if (t < off) u.red[t] += u.red[t + off];
      __syncthreads();
    }
    if (t == 0) lens[b] = u.red[0];
  }
}

// ---------------------------------------------------------------------------
// Fused QKV projection v13 (kept from r15, verified): ct-PAIRED 128x256
// tiles, BK=64; 128 MFMAs per barrier; grid 768 XCD-affine. r15 post-mortem:
// pairing ~neutral (occupancy traded for amortization) but passing; kept.
// ---------------------------------------------------------------------------
__global__ __launch_bounds__(256, 2) void qkvf_kernel(
    const f16* __restrict__ xh, const f16* __restrict__ wtAll,
    const int* __restrict__ lens, f16* __restrict__ Qh, f16* __restrict__ Kh,
    f16* __restrict__ Vth, float* __restrict__ Vsum) {
  const int id = blockIdx.x;
  const int xcd = id & 7;                 // XCD under %8 round-robin
  const int local = id >> 3;              // 0..95 within XCD
  const int pr = local % 6;               // ct-pair index
  const int rt = xcd * 16 + local / 6;    // row-tile 0..127, contiguous/XCD
  const int ct0 = pr * 2;                 // pair covers ct0, ct0+1
  const int which = ct0 >> 2;             // uniform across the pair
  const f16* Wt0 = wtAll + (size_t)which * 262144 + (size_t)(ct0 & 3) * 65536;
  const f16* Wt1 =
      wtAll + (size_t)which * 262144 + (size_t)((ct0 + 1) & 3) * 65536;
  const int row0 = rt * 128;
  const int b = row0 >> 10, s0 = row0 & 1023;
  const int t = threadIdx.x;
  const int w = t >> 6, lane = t & 63, quad = lane >> 4, lcol = lane & 15;
  const int wr = w >> 1, wc = w & 1;

  __shared__ union SM {
    struct { f16 Xs[128][64]; f16 Ws[2][128][64]; } a;  // unpadded (lds-dma)
    f16 Ts[128][136];                                   // epilogue staging
  } sm;

  f32x4 acc[2][4][4];
#pragma unroll
  for (int j = 0; j < 2; ++j)
#pragma unroll
    for (int i = 0; i < 4; ++i)
#pragma unroll
      for (int jj = 0; jj < 4; ++jj) acc[j][i][jj] = (f32x4){0.f, 0.f, 0.f, 0.f};

  for (int k0 = 0; k0 < CHID; k0 += 64) {
    __syncthreads();  // prior compute's LDS reads done
#pragma unroll
    for (int i = 0; i < 4; ++i) {
      const int c = t + 256 * i, r = c >> 3, sg = c & 7;
      const int gsw = (sg ^ (r & 7)) * 8;  // XOR swizzle on global source
      gld16(&xh[(size_t)(row0 + r) * CHID + k0 + gsw],
            (char*)&sm.a.Xs[0][0] + c * 16);
      gld16(&Wt0[(size_t)r * CHID + k0 + gsw],
            (char*)&sm.a.Ws[0][0][0] + c * 16);
      gld16(&Wt1[(size_t)r * CHID + k0 + gsw],
            (char*)&sm.a.Ws[1][0][0] + c * 16);
    }
    __syncthreads();  // drains vmcnt: LDS tiles ready

#pragma unroll
    for (int j = 0; j < 2; ++j) {
      f16x8 bf0[4], bf1[4];
#pragma unroll
      for (int jj = 0; jj < 4; ++jj) {
        const int br = wc * 64 + jj * 16 + lcol;
        bf0[jj] = *(const f16x8*)&sm.a.Ws[j][br][(quad ^ (br & 7)) * 8];
        bf1[jj] = *(const f16x8*)&sm.a.Ws[j][br][((quad ^ 4) ^ (br & 7)) * 8];
      }
#pragma unroll
      for (int i = 0; i < 4; ++i) {
        const int ar = wr * 64 + i * 16 + lcol;
        const f16x8 af0 = *(const f16x8*)&sm.a.Xs[ar][(quad ^ (ar & 7)) * 8];
        const f16x8 af1 =
            *(const f16x8*)&sm.a.Xs[ar][((quad ^ 4) ^ (ar & 7)) * 8];
#pragma unroll
        for (int jj = 0; jj < 4; ++jj) {
          acc[j][i][jj] = mfma16(af0, bf0[jj], acc[j][i][jj]);
          acc[j][i][jj] = mfma16(af1, bf1[jj], acc[j][i][jj]);
        }
      }
    }
  }

  // epilogues: one per paired col-tile, sequential through the Ts union
#pragma unroll
  for (int j = 0; j < 2; ++j) {
    const int hp = (ct0 + j) & 3;
    const int h0 = hp * 2;
    if (which == 2) {
      // fp32 column sums -> Vsum (quad-reduced, register-only)
#pragma unroll
      for (int jj = 0; jj < 4; ++jj) {
        float ps = 0.f;
#pragma unroll
        for (int i = 0; i < 4; ++i)
#pragma unroll
          for (int rr = 0; rr < 4; ++rr) ps += acc[j][i][jj][rr];
        ps += __shfl_xor(ps, 16);
        ps += __shfl_xor(ps, 32);
        if (quad == 0) {
          const int d128 = wc * 64 + jj * 16 + lcol;
          const int h = h0 + (d128 >> 6), d = d128 & 63;
          atomicAdd(&Vsum[((size_t)b * CH + h) * CDK + d], ps);
        }
      }
      // Ts[n][s]: packed f16x4 transpose writes, then coalesced V^T stores
      __syncthreads();
#pragma unroll
      for (int i = 0; i < 4; ++i)
#pragma unroll
        for (int jj = 0; jj < 4; ++jj) {
          f16x4 v4;
#pragma unroll
          for (int rr = 0; rr < 4; ++rr) v4[rr] = (f16)acc[j][i][jj][rr];
          *(f16x4*)&sm.Ts[wc * 64 + jj * 16 + lcol]
                         [wr * 64 + i * 16 + quad * 4] = v4;
        }
      __syncthreads();
      const int c16 = t & 15;
#pragma unroll
      for (int p = 0; p < 8; ++p) {
        const int vr = p * 16 + (t >> 4);
        const int h = h0 + (vr >> 6), d = vr & 63;
        *(f16x8*)&Vth[(((size_t)b * CH + h) * CDK + d) * CS + s0 + c16 * 8] =
            *(const f16x8*)&sm.Ts[vr][c16 * 8];
      }
    } else {
      // Ts[s][n], then coalesced [B,H,S,64] stores (128-B runs)
      const float qsc = (which == 0) ? rsqrtf((float)lens[b]) * LOG2E : 1.0f;
      __syncthreads();
#pragma unroll
      for (int i = 0; i < 4; ++i)
#pragma unroll
        for (int jj = 0; jj < 4; ++jj)
#pragma unroll
          for (int rr = 0; rr < 4; ++rr)
            sm.Ts[wr * 64 + i * 16 + quad * 4 + rr][wc * 64 + jj * 16 + lcol] =
                (f16)(acc[j][i][jj][rr] * qsc);
      __syncthreads();
      f16* O = (which == 0) ? Qh : Kh;
      const int c8 = t & 7;
#pragma unroll
      for (int p = 0; p < 4; ++p) {
        const int row = p * 32 + (t >> 3);
#pragma unroll
        for (int half = 0; half < 2; ++half) {
          const int h = h0 + half;
          *(f16x8*)&O[(((size_t)b * CH + h) * CS + s0 + row) * CDK + c8 * 8] =
              *(const f16x8*)&sm.Ts[row][half * 64 + c8 * 8];
        }
      }
    }
  }
}

// ---------------------------------------------------------------------------
// Attention (MFMA flash, v11 — unchanged, verified 44us):
//  * v5's 64-VGPR inner code: kb0/kb1 per set, pk/pv reg prefetch, dbuf
//    K/V, 1 barrier/tile, swapped QK^T, RNE pack + permlane quad-transpose,
//    MFMA row-sums, tail-split masking. NO setprio (r10/r11: s_setprio in
//    this barrier-locked block produced 70-90MB phantom WRITE + 26us).
//  * XCD decode: h=id&7, qt=(id>>3)&7 fastest, b=id>>6 (FETCH 113->23MB).
//  * 128-row blocks, grid 1024, 4 blocks/CU (LDS 147KB<160).
// ---------------------------------------------------------------------------
__global__ __launch_bounds__(256, 4) void attn_kernel(
    const f16* __restrict__ Qh, const f16* __restrict__ Kh,
    const f16* __restrict__ Vth, const int* __restrict__ lens,
    const float* __restrict__ Vsum, f16* __restrict__ Hbh) {
  const int id = blockIdx.x;
  const int h = id & 7;            // XCD index under %8 round-robin
  const int qt = (id >> 3) & 7;    // fastest on an XCD: same (b,h) panel
  const int b = id >> 6;           // 0..15
  const int n = lens[b];
  const int t = threadIdx.x, w = t >> 6, lane = t & 63, quad = lane >> 4,
            lcol = lane & 15;

  const size_t bh = ((size_t)b * CH + h) * CS;
  const size_t bhd = ((size_t)b * CH + h) * CDK;

  const int nt = (n + 63) >> 6;
  const int rem = n & 63;
  const int ntm = rem ? nt - 1 : nt;  // unmasked main tiles

  __shared__ union SM {
    struct { f16 Ks[2][64][72]; f16 Vs[2][64][72]; } kv;  // [buf][k|d][d|k]
    f16 St[4][32][72];  // epilogue staging (post-loop reuse)
  } sm;

  const int qbase = qt * 128 + w * 32;
  f16x8 qa[2][2];
#pragma unroll
  for (int set = 0; set < 2; ++set) {
    const size_t qr = bh + qbase + set * 16 + lcol;
    qa[set][0] = *(const f16x8*)&Qh[qr * CDK + quad * 8];
    qa[set][1] = *(const f16x8*)&Qh[qr * CDK + 32 + quad * 8];
  }

  f16x8 vones;
#pragma unroll
  for (int j = 0; j < 8; ++j) vones[j] = (f16)1.0f;

  f32x4 o[2][4];
#pragma unroll
  for (int set = 0; set < 2; ++set)
#pragma unroll
    for (int dt = 0; dt < 4; ++dt) o[set][dt] = (f32x4){0.f, 0.f, 0.f, 0.f};
  f32x4 o_l[2] = {(f32x4){0.f, 0.f, 0.f, 0.f}, (f32x4){0.f, 0.f, 0.f, 0.f}};

  // tile 0: load + stage into buffer 0
  f16x8 pk[2], pv[2];
#pragma unroll
  for (int i = 0; i < 2; ++i) {
    const int c = t + 256 * i, r = c >> 3, sg = c & 7;
    pk[i] = *(const f16x8*)&Kh[(bh + r) * CDK + sg * 8];
    pv[i] = *(const f16x8*)&Vth[(bhd + r) * CS + sg * 8];
  }
#pragma unroll
  for (int i = 0; i < 2; ++i) {
    const int c = t + 256 * i, r = c >> 3, sg = c & 7;
    *(f16x8*)&sm.kv.Ks[0][r][sg * 8] = pk[i];
    *(f16x8*)&sm.kv.Vs[0][r][sg * 8] = pv[i];
  }
  __syncthreads();

  auto ktile = [&](const int kt, const bool masked) __attribute__((always_inline)) {
    const int cur = kt & 1, nxt = cur ^ 1;
    // prefetch next tile into regs (clamped; uniform straight-line code)
    const int ktn = (kt + 1 < nt) ? kt + 1 : kt;
#pragma unroll
    for (int i = 0; i < 2; ++i) {
      const int c = t + 256 * i, r = c >> 3, sg = c & 7;
      pk[i] = *(const f16x8*)&Kh[(bh + ktn * 64 + r) * CDK + sg * 8];
      pv[i] = *(const f16x8*)&Vth[(bhd + r) * CS + ktn * 64 + sg * 8];
    }

    // swapped QK^T + exp + in-register P->A-frag transpose
    f16x8 pa[2][2];
#pragma unroll
    for (int set = 0; set < 2; ++set) {
      f32x4 st[4];
#pragma unroll
      for (int ct = 0; ct < 4; ++ct) {
        const f16x8 kb0 = *(const f16x8*)&sm.kv.Ks[cur][ct * 16 + lcol][quad * 8];
        const f16x8 kb1 =
            *(const f16x8*)&sm.kv.Ks[cur][ct * 16 + lcol][32 + quad * 8];
        st[ct] = mfma16(kb0, qa[set][0], (f32x4){0.f, 0.f, 0.f, 0.f});
        st[ct] = mfma16(kb1, qa[set][1], st[ct]);
      }
      unsigned pkd[4][2];
#pragma unroll
      for (int c = 0; c < 4; ++c) {
        float p[4];
#pragma unroll
        for (int r = 0; r < 4; ++r) {
          float e = fast_exp2(st[c][r]);
          if (masked) {
            const bool kvld = (kt * 64 + c * 16 + quad * 4 + r) < n;
            e = kvld ? e : 0.f;
          }
          p[r] = e;
        }
        pkd[c][0] = pack_rne(p[0], p[1]);
        pkd[c][1] = pack_rne(p[2], p[3]);
      }
      // quad-transpose: target quad t's dword j2 ends at k = 8t + 2*j2 + {0,1}
#pragma unroll
      for (int half = 0; half < 2; ++half) {
        unsigned x0 = pkd[2 * half][0], y0 = pkd[2 * half + 1][0];
        unsigned x1 = pkd[2 * half][1], y1 = pkd[2 * half + 1][1];
        quad_transpose(x0, y0);
        quad_transpose(x1, y1);
        union { u32x4 u; f16x8 h; } cc;
        cc.u = (u32x4){x0, x1, y0, y1};
        pa[set][half] = cc.h;
      }
    }

    // PV + row-sum MFMAs (P x ones = rowsum, lands directly in O-layout)
#pragma unroll
    for (int dt = 0; dt < 4; ++dt) {
      const f16x8 vb0 = *(const f16x8*)&sm.kv.Vs[cur][dt * 16 + lcol][quad * 8];
      const f16x8 vb1 =
          *(const f16x8*)&sm.kv.Vs[cur][dt * 16 + lcol][32 + quad * 8];
#pragma unroll
      for (int set = 0; set < 2; ++set) {
        o[set][dt] = mfma16(pa[set][0], vb0, o[set][dt]);
        o[set][dt] = mfma16(pa[set][1], vb1, o[set][dt]);
      }
    }
#pragma unroll
    for (int set = 0; set < 2; ++set) {
      o_l[set] = mfma16(pa[set][0], vones, o_l[set]);
      o_l[set] = mfma16(pa[set][1], vones, o_l[set]);
    }

    // stage next tile into the other buffer; one barrier covers both
    // write-visibility (buf nxt) and read-completion (buf cur)
#pragma unroll
    for (int i = 0; i < 2; ++i) {
      const int c = t + 256 * i, r = c >> 3, sg = c & 7;
      *(f16x8*)&sm.kv.Ks[nxt][r][sg * 8] = pk[i];
      *(f16x8*)&sm.kv.Vs[nxt][r][sg * 8] = pv[i];
    }
    __syncthreads();
  };

  int kt = 0;
  for (; kt < ntm; ++kt) ktile(kt, false);
  if (rem) ktile(kt, true);

  // per-lane inverse row-sums (already in O-layout: row quad*4+r, any col)
  float invl[2][4];
#pragma unroll
  for (int set = 0; set < 2; ++set)
#pragma unroll
    for (int r = 0; r < 4; ++r) invl[set][r] = 1.0f / o_l[set][r];

  // O -> wave-private St (f16), then coalesced 128-B-run stores.
  // (final loop barrier already fenced all K/V reads; St aliases kv)
#pragma unroll
  for (int set = 0; set < 2; ++set)
#pragma unroll
    for (int dt = 0; dt < 4; ++dt)
#pragma unroll
      for (int r = 0; r < 4; ++r) {
        const int srow_l = set * 16 + quad * 4 + r;
        const int d = dt * 16 + lcol;
        const float val = (qbase + srow_l < n)
                              ? o[set][dt][r] * invl[set][r]
                              : Vsum[bhd + d] * (1.0f / 1024.0f);
        sm.St[w][srow_l][d] = (f16)val;
      }
  {
    const int lr = lane >> 3, lc = lane & 7;
#pragma unroll
    for (int p = 0; p < 4; ++p) {
      const int row = p * 8 + lr;
      *(f16x8*)&Hbh[((size_t)b * CS + qbase + row) * (CH * CDK) + h * CDK +
                    lc * 8] = *(const f16x8*)&sm.St[w][row][lc * 8];
    }
  }
}

// ---------------------------------------------------------------------------
// Output projection: 128x128 tile, BK=64, gld16 + XOR swizzle (as qkvf).
// 1-D grid 512, XCD-affine decode: the 4 ctile blocks of one Hbh row-panel
// land consecutively on ONE XCD; woutt (0.5MB) L2-resident. NOT paired
// (r15 lesson: pairing halves blocks/CU, occupancy loss ~= barrier gain).
// ---------------------------------------------------------------------------
__global__ __launch_bounds__(256) void outp_kernel(const f16* __restrict__ Hbh,
                                                   const f16* __restrict__ woutt,
                                                   float* __restrict__ out) {
  const int id = blockIdx.x;
  const int xcd = id & 7;
  const int local = id >> 3;            // 0..63 per XCD
  const int ctile = local & 3;
  const int rt = xcd * 16 + (local >> 2);  // 0..127, contiguous per XCD
  const int row0 = rt * 128, col0 = ctile * 128;
  const f16* Wt = woutt + (size_t)col0 * CHID;
  const int t = threadIdx.x;
  const int w = t >> 6, lane = t & 63, quad = lane >> 4, lcol = lane & 15;
  const int wr = w >> 1, wc = w & 1;

  __shared__ f16 Hs[128][64];  // unpadded (lds-dma), XOR-swizzled columns
  __shared__ f16 Ws[128][64];

  f32x4 acc[4][4];
#pragma unroll
  for (int i = 0; i < 4; ++i)
#pragma unroll
    for (int j = 0; j < 4; ++j) acc[i][j] = (f32x4){0.f, 0.f, 0.f, 0.f};

  for (int k0 = 0; k0 < CHID; k0 += 64) {
    __syncthreads();
#pragma unroll
    for (int i = 0; i < 4; ++i) {
      const int c = t + 256 * i, r = c >> 3, sg = c & 7;
      const int gsw = (sg ^ (r & 7)) * 8;
      gld16(&Hbh[(size_t)(row0 + r) * CHID + k0 + gsw],
            (char*)&Hs[0][0] + c * 16);
      gld16(&Wt[(size_t)r * CHID + k0 + gsw], (char*)&Ws[0][0] + c * 16);
    }
    __syncthreads();

    f16x8 bf0[4], bf1[4];
#pragma unroll
    for (int j = 0; j < 4; ++j) {
      const int br = wc * 64 + j * 16 + lcol;
      bf0[j] = *(const f16x8*)&Ws[br][(quad ^ (br & 7)) * 8];
      bf1[j] = *(const f16x8*)&Ws[br][((quad ^ 4) ^ (br & 7)) * 8];
    }
#pragma unroll
    for (int i = 0; i < 4; ++i) {
      const int ar = wr * 64 + i * 16 + lcol;
      const f16x8 af0 = *(const f16x8*)&Hs[ar][(quad ^ (ar & 7)) * 8];
      const f16x8 af1 = *(const f16x8*)&Hs[ar][((quad ^ 4) ^ (ar & 7)) * 8];
#pragma unroll
      for (int j = 0; j < 4; ++j) {
        acc[i][j] = mfma16(af0, bf0[j], acc[i][j]);
        acc[i][j] = mfma16(af1, bf1[j], acc[i][j]);
      }
    }
  }

#pragma unroll
  for (int i = 0; i < 4; ++i) {
#pragma unroll
    for (int rr = 0; rr < 4; ++rr) {
      const size_t rg = row0 + wr * 64 + i * 16 + quad * 4 + rr;
#pragma unroll
      for (int j = 0; j < 4; ++j)
        out[rg * CHID + col0 + wc * 64 + j * 16 + lcol] = acc[i][j][rr];
    }
  }
}

// ---------------------------------------------------------------------------
extern "C" void kernel_launch(void* const* d_in, const int* in_sizes, int n_in,
                              void* d_out, int out_size, void* d_ws,
                              size_t ws_size, hipStream_t stream) {
  const float* x = (const float*)d_in[0];
  const int* mask = (const int*)d_in[1];
  const float* Wq = (const float*)d_in[2];
  const float* Wk = (const float*)d_in[3];
  const float* Wv = (const float*)d_in[4];
  const float* Wout = (const float*)d_in[5];
  float* out = (float*)d_out;

  char* ws = (char*)d_ws;
  int* lens = (int*)ws;
  size_t off = 1024;
  const size_t NX = (size_t)CB * CS * CHID;   // 8,388,608
  const size_t NW = (size_t)CH * CHID * CDK;  // 262,144 per weight
  f16* xh = (f16*)(ws + off);    off += NX * 2;
  f16* wtAll = (f16*)(ws + off); off += NW * 4 * 2;
  f16* Qh = (f16*)(ws + off);    off += NX * 2;
  f16* Kh = (f16*)(ws + off);    off += NX * 2;
  f16* Vth = (f16*)(ws + off);   off += NX * 2;
  f16* Hbh = (f16*)(ws + off);   off += NX * 2;
  float* Vsum = (float*)(ws + off); off += (size_t)CB * CH * CDK * 4;
  f16* woutt = wtAll + NW * 3;

  prep_kernel<<<8464, 256, 0, stream>>>((const float4*)x, (f16x4*)xh, mask,
                                        lens, Vsum, Wq, Wk, Wv, Wout, wtAll);
  qkvf_kernel<<<768, 256, 0, stream>>>(xh, wtAll, lens, Qh, Kh, Vth, Vsum);
  attn_kernel<<<1024, 256, 0, stream>>>(Qh, Kh, Vth, lens, Vsum, Hbh);
  outp_kernel<<<512, 256, 0, stream>>>(Hbh, woutt, out);
}

// Round 19
// 178.449 us; speedup vs baseline: 1.3882x; 1.0284x over previous
//
#include <hip/hip_runtime.h>
#include <math.h>

// QANetAttBlock: B=16, S=1024, HID=512, H=8, DK=64
constexpr int CB = 16;
constexpr int CS = 1024;
constexpr int CHID = 512;
constexpr int CH = 8;
constexpr int CDK = 64;

typedef _Float16 f16;
typedef __attribute__((ext_vector_type(8))) _Float16 f16x8;
typedef __attribute__((ext_vector_type(4))) _Float16 f16x4;
typedef __attribute__((ext_vector_type(4))) float f32x4;
typedef __attribute__((ext_vector_type(4))) unsigned int u32x4;
typedef __attribute__((ext_vector_type(2))) unsigned int u32x2;

__device__ inline f32x4 mfma16(f16x8 a, f16x8 b, f32x4 c) {
  return __builtin_amdgcn_mfma_f32_16x16x32_f16(a, b, c, 0, 0, 0);
}

// async global->LDS, 16B per lane; dest must be wave-uniform base + lane*16
__device__ inline void gld16(const void* g, void* l) {
  __builtin_amdgcn_global_load_lds(
      (const __attribute__((address_space(1))) void*)g,
      (__attribute__((address_space(3))) void*)l, 16, 0, 0);
}

// raw v_exp_f32 (2^x). libm exp2f costs ~10 extra VALU/call.
__device__ inline float fast_exp2(float x) {
#if __has_builtin(__builtin_amdgcn_exp2f)
  return __builtin_amdgcn_exp2f(x);
#else
  return __expf(x * 0.6931471805599453f);
#endif
}

// packed f32x2 -> f16x2 with round-to-nearest-even as a raw dword.
__device__ inline unsigned pack_rne(float a, float b) {
  union { f16 h[2]; unsigned u; } c;
  c.h[0] = (f16)a;
  c.h[1] = (f16)b;
  return c.u;
}

// 4x4 quad-transpose of two dwords via gfx950 permlane swaps.
// Rows (16-lane groups) in:  x=[X0,X1,X2,X3], y=[Y0,Y1,Y2,Y3]
// After p32 (dst-hi<->src-lo) + p16 (dst-odd<->src-even):
//   x=[X0,X2,Y0,Y2], y=[X1,X3,Y1,Y3].
// HAZARD NOTE (r1/r2 failure root cause): raw back-to-back permlane asm
// violates the "VALU write -> v_permlane* read needs a wait state" rule.
// The builtins let the compiler insert the required hazard nops.
__device__ inline void quad_transpose(unsigned& x, unsigned& y) {
#if __has_builtin(__builtin_amdgcn_permlane32_swap) && \
    __has_builtin(__builtin_amdgcn_permlane16_swap)
  u32x2 a = __builtin_amdgcn_permlane32_swap(x, y, false, false);
  u32x2 b = __builtin_amdgcn_permlane16_swap(a[0], a[1], false, false);
  x = b[0];
  y = b[1];
#else
  asm volatile(
      "s_nop 1\n\t"
      "v_permlane32_swap_b32 %0, %1\n\t"
      "s_nop 1\n\t"
      "v_permlane16_swap_b32 %0, %1\n\t"
      "s_nop 1"
      : "+v"(x), "+v"(y));
#endif
}

#define LOG2E 1.4426950408889634f

// ---------------------------------------------------------------------------
// fused prep + cast_w (one launch; the 256 cast_w blocks hide under prep's
// 8192-block tail):
//   blocks 0..8191   : cast x fp32->fp16 (coalesced float4 -> f16x4)
//   blocks 8192..8447: weight cast+transpose via LDS (kb=local&7, y=local>>3)
//   blocks 8448..8463: lens[b] reduction + Vsum zero (ws poisoned 0xAA)
// ---------------------------------------------------------------------------
__global__ __launch_bounds__(256) void prep_kernel(
    const float4* __restrict__ x, f16x4* __restrict__ xh,
    const int* __restrict__ mask, int* __restrict__ lens,
    float* __restrict__ Vsum, const float* __restrict__ Wq,
    const float* __restrict__ Wk, const float* __restrict__ Wv,
    const float* __restrict__ Wout, f16* __restrict__ wtAll) {
  const int bid = blockIdx.x, t = threadIdx.x;
  __shared__ union {
    int red[256];
    float Ts[64][68];
  } u;
  if (bid < 8192) {
    const int idx = bid * 256 + t;
    const float4 v = x[idx];
    f16x4 o;
    o[0] = (f16)v.x; o[1] = (f16)v.y; o[2] = (f16)v.z; o[3] = (f16)v.w;
    xh[idx] = o;
  } else if (bid < 8448) {
    // cast_w body (verified): decode local block -> (kb, y)
    const int local = bid - 8192;
    const int kb = local & 7, y = local >> 3;
    const int k0 = kb * 64;
    const float* src;
    int ldsrc;
    f16* dst;
    if (y < 24) {
      const int which = y >> 3, h = y & 7;
      const float* W = (which == 0) ? Wq : (which == 1) ? Wk : Wv;
      src = W + (size_t)h * 32768 + (size_t)k0 * 64;
      ldsrc = 64;
      dst = wtAll + (size_t)which * 262144 + (size_t)h * 32768;
    } else {
      const int c = y - 24;
      src = Wout + (size_t)k0 * 512 + c * 64;
      ldsrc = 512;
      dst = wtAll + (size_t)3 * 262144 + (size_t)c * 64 * 512;
    }
    {
      const int kr = t >> 4, cg = (t & 15) * 4;
#pragma unroll
      for (int rr = 0; rr < 4; ++rr) {
        const float4 v =
            *(const float4*)&src[(size_t)(rr * 16 + kr) * ldsrc + cg];
        u.Ts[rr * 16 + kr][cg] = v.x;
        u.Ts[rr * 16 + kr][cg + 1] = v.y;
        u.Ts[rr * 16 + kr][cg + 2] = v.z;
        u.Ts[rr * 16 + kr][cg + 3] = v.w;
      }
    }
    __syncthreads();
    {
      const int n = t >> 2, seg = t & 3;
      f16x8 a, b;
#pragma unroll
      for (int j = 0; j < 8; ++j) {
        a[j] = (f16)u.Ts[seg * 16 + j][n];
        b[j] = (f16)u.Ts[seg * 16 + 8 + j][n];
      }
      f16* d = &dst[(size_t)n * 512 + k0 + seg * 16];
      *(f16x8*)d = a;
      *(f16x8*)(d + 8) = b;
    }
  } else {
    const int b = bid - 8448;
    const int g = b * 256 + t;
    Vsum[g * 2] = 0.f;
    Vsum[g * 2 + 1] = 0.f;
    int s = 0;
    for (int i = t; i < CS; i += 256) s += mask[b * CS + i];
    u.red[t] = s;
    __syncthreads();
    for (int off = 128; off > 0; off >>= 1) {
      if (t < off) u.red[t] += u.red[t + off];
      __syncthreads();
    }
    if (t == 0) lens[b] = u.red[0];
  }
}

// ---------------------------------------------------------------------------
// Fused QKV projection (verified): ct-PAIRED 128x256 tiles, BK=64;
// 128 MFMAs per barrier; grid 768 XCD-affine.
// ---------------------------------------------------------------------------
__global__ __launch_bounds__(256, 2) void qkvf_kernel(
    const f16* __restrict__ xh, const f16* __restrict__ wtAll,
    const int* __restrict__ lens, f16* __restrict__ Qh, f16* __restrict__ Kh,
    f16* __restrict__ Vth, float* __restrict__ Vsum) {
  const int id = blockIdx.x;
  const int xcd = id & 7;                 // XCD under %8 round-robin
  const int local = id >> 3;              // 0..95 within XCD
  const int pr = local % 6;               // ct-pair index
  const int rt = xcd * 16 + local / 6;    // row-tile 0..127, contiguous/XCD
  const int ct0 = pr * 2;                 // pair covers ct0, ct0+1
  const int which = ct0 >> 2;             // uniform across the pair
  const f16* Wt0 = wtAll + (size_t)which * 262144 + (size_t)(ct0 & 3) * 65536;
  const f16* Wt1 =
      wtAll + (size_t)which * 262144 + (size_t)((ct0 + 1) & 3) * 65536;
  const int row0 = rt * 128;
  const int b = row0 >> 10, s0 = row0 & 1023;
  const int t = threadIdx.x;
  const int w = t >> 6, lane = t & 63, quad = lane >> 4, lcol = lane & 15;
  const int wr = w >> 1, wc = w & 1;

  __shared__ union SM {
    struct { f16 Xs[128][64]; f16 Ws[2][128][64]; } a;  // unpadded (lds-dma)
    f16 Ts[128][136];                                   // epilogue staging
  } sm;

  f32x4 acc[2][4][4];
#pragma unroll
  for (int j = 0; j < 2; ++j)
#pragma unroll
    for (int i = 0; i < 4; ++i)
#pragma unroll
      for (int jj = 0; jj < 4; ++jj) acc[j][i][jj] = (f32x4){0.f, 0.f, 0.f, 0.f};

  for (int k0 = 0; k0 < CHID; k0 += 64) {
    __syncthreads();  // prior compute's LDS reads done
#pragma unroll
    for (int i = 0; i < 4; ++i) {
      const int c = t + 256 * i, r = c >> 3, sg = c & 7;
      const int gsw = (sg ^ (r & 7)) * 8;  // XOR swizzle on global source
      gld16(&xh[(size_t)(row0 + r) * CHID + k0 + gsw],
            (char*)&sm.a.Xs[0][0] + c * 16);
      gld16(&Wt0[(size_t)r * CHID + k0 + gsw],
            (char*)&sm.a.Ws[0][0][0] + c * 16);
      gld16(&Wt1[(size_t)r * CHID + k0 + gsw],
            (char*)&sm.a.Ws[1][0][0] + c * 16);
    }
    __syncthreads();  // drains vmcnt: LDS tiles ready

#pragma unroll
    for (int j = 0; j < 2; ++j) {
      f16x8 bf0[4], bf1[4];
#pragma unroll
      for (int jj = 0; jj < 4; ++jj) {
        const int br = wc * 64 + jj * 16 + lcol;
        bf0[jj] = *(const f16x8*)&sm.a.Ws[j][br][(quad ^ (br & 7)) * 8];
        bf1[jj] = *(const f16x8*)&sm.a.Ws[j][br][((quad ^ 4) ^ (br & 7)) * 8];
      }
#pragma unroll
      for (int i = 0; i < 4; ++i) {
        const int ar = wr * 64 + i * 16 + lcol;
        const f16x8 af0 = *(const f16x8*)&sm.a.Xs[ar][(quad ^ (ar & 7)) * 8];
        const f16x8 af1 =
            *(const f16x8*)&sm.a.Xs[ar][((quad ^ 4) ^ (ar & 7)) * 8];
#pragma unroll
        for (int jj = 0; jj < 4; ++jj) {
          acc[j][i][jj] = mfma16(af0, bf0[jj], acc[j][i][jj]);
          acc[j][i][jj] = mfma16(af1, bf1[jj], acc[j][i][jj]);
        }
      }
    }
  }

  // epilogues: one per paired col-tile, sequential through the Ts union
#pragma unroll
  for (int j = 0; j < 2; ++j) {
    const int hp = (ct0 + j) & 3;
    const int h0 = hp * 2;
    if (which == 2) {
      // fp32 column sums -> Vsum (quad-reduced, register-only)
#pragma unroll
      for (int jj = 0; jj < 4; ++jj) {
        float ps = 0.f;
#pragma unroll
        for (int i = 0; i < 4; ++i)
#pragma unroll
          for (int rr = 0; rr < 4; ++rr) ps += acc[j][i][jj][rr];
        ps += __shfl_xor(ps, 16);
        ps += __shfl_xor(ps, 32);
        if (quad == 0) {
          const int d128 = wc * 64 + jj * 16 + lcol;
          const int h = h0 + (d128 >> 6), d = d128 & 63;
          atomicAdd(&Vsum[((size_t)b * CH + h) * CDK + d], ps);
        }
      }
      // Ts[n][s]: packed f16x4 transpose writes, then coalesced V^T stores
      __syncthreads();
#pragma unroll
      for (int i = 0; i < 4; ++i)
#pragma unroll
        for (int jj = 0; jj < 4; ++jj) {
          f16x4 v4;
#pragma unroll
          for (int rr = 0; rr < 4; ++rr) v4[rr] = (f16)acc[j][i][jj][rr];
          *(f16x4*)&sm.Ts[wc * 64 + jj * 16 + lcol]
                         [wr * 64 + i * 16 + quad * 4] = v4;
        }
      __syncthreads();
      const int c16 = t & 15;
#pragma unroll
      for (int p = 0; p < 8; ++p) {
        const int vr = p * 16 + (t >> 4);
        const int h = h0 + (vr >> 6), d = vr & 63;
        *(f16x8*)&Vth[(((size_t)b * CH + h) * CDK + d) * CS + s0 + c16 * 8] =
            *(const f16x8*)&sm.Ts[vr][c16 * 8];
      }
    } else {
      // Ts[s][n], then coalesced [B,H,S,64] stores (128-B runs)
      const float qsc = (which == 0) ? rsqrtf((float)lens[b]) * LOG2E : 1.0f;
      __syncthreads();
#pragma unroll
      for (int i = 0; i < 4; ++i)
#pragma unroll
        for (int jj = 0; jj < 4; ++jj)
#pragma unroll
          for (int rr = 0; rr < 4; ++rr)
            sm.Ts[wr * 64 + i * 16 + quad * 4 + rr][wc * 64 + jj * 16 + lcol] =
                (f16)(acc[j][i][jj][rr] * qsc);
      __syncthreads();
      f16* O = (which == 0) ? Qh : Kh;
      const int c8 = t & 7;
#pragma unroll
      for (int p = 0; p < 4; ++p) {
        const int row = p * 32 + (t >> 3);
#pragma unroll
        for (int half = 0; half < 2; ++half) {
          const int h = h0 + half;
          *(f16x8*)&O[(((size_t)b * CH + h) * CS + s0 + row) * CDK + c8 * 8] =
              *(const f16x8*)&sm.Ts[row][half * 64 + c8 * 8];
        }
      }
    }
  }
}

// ---------------------------------------------------------------------------
// Attention (MFMA flash, v18 = v11 + invalid-q-block early exit):
//  * NEW: reference semantics -> rows q >= n have uniform softmax ->
//    output = Vsum/1024, independent of the k-loop. Blocks with
//    qt*128 >= n (avg ~25% of blocks, n in [512,1024]) write the
//    broadcast directly and exit: no LDS, no barriers, no k-loop.
//    Frees SIMD/LDS bandwidth for the valid co-resident blocks.
//  * Valid-path inner code unchanged (v5's verified 64-VGPR structure):
//    kb0/kb1 per set, pk/pv reg prefetch, dbuf K/V, 1 barrier/tile,
//    swapped QK^T, RNE pack + permlane quad-transpose, MFMA row-sums,
//    tail-split masking. NO setprio (r10/r11: phantom WRITE +26us).
//  * XCD decode: h=id&7, qt=(id>>3)&7 fastest, b=id>>6 (FETCH 113->23MB).
//  * 128-row blocks, grid 1024, 4 blocks/CU (LDS 147KB<160).
// ---------------------------------------------------------------------------
__global__ __launch_bounds__(256, 4) void attn_kernel(
    const f16* __restrict__ Qh, const f16* __restrict__ Kh,
    const f16* __restrict__ Vth, const int* __restrict__ lens,
    const float* __restrict__ Vsum, f16* __restrict__ Hbh) {
  const int id = blockIdx.x;
  const int h = id & 7;            // XCD index under %8 round-robin
  const int qt = (id >> 3) & 7;    // fastest on an XCD: same (b,h) panel
  const int b = id >> 6;           // 0..15
  const int n = lens[b];
  const int t = threadIdx.x, w = t >> 6, lane = t & 63, quad = lane >> 4,
            lcol = lane & 15;

  const size_t bh = ((size_t)b * CH + h) * CS;
  const size_t bhd = ((size_t)b * CH + h) * CDK;

  // fully-invalid q-block: all 128 rows >= n -> uniform-softmax fallback.
  // Block-uniform branch (n, qt uniform); no barriers used on this path.
  if (qt * 128 >= n) {
    const int c8 = t & 7, lr = t >> 3;   // 8-f16 column group, row 0..31
    f16x8 v8;
#pragma unroll
    for (int j = 0; j < 8; ++j)
      v8[j] = (f16)(Vsum[bhd + c8 * 8 + j] * (1.0f / 1024.0f));
#pragma unroll
    for (int p = 0; p < 4; ++p) {
      const int row = qt * 128 + p * 32 + lr;
      *(f16x8*)&Hbh[((size_t)b * CS + row) * (CH * CDK) + h * CDK + c8 * 8] =
          v8;
    }
    return;
  }

  const int nt = (n + 63) >> 6;
  const int rem = n & 63;
  const int ntm = rem ? nt - 1 : nt;  // unmasked main tiles

  __shared__ union SM {
    struct { f16 Ks[2][64][72]; f16 Vs[2][64][72]; } kv;  // [buf][k|d][d|k]
    f16 St[4][32][72];  // epilogue staging (post-loop reuse)
  } sm;

  const int qbase = qt * 128 + w * 32;
  f16x8 qa[2][2];
#pragma unroll
  for (int set = 0; set < 2; ++set) {
    const size_t qr = bh + qbase + set * 16 + lcol;
    qa[set][0] = *(const f16x8*)&Qh[qr * CDK + quad * 8];
    qa[set][1] = *(const f16x8*)&Qh[qr * CDK + 32 + quad * 8];
  }

  f16x8 vones;
#pragma unroll
  for (int j = 0; j < 8; ++j) vones[j] = (f16)1.0f;

  f32x4 o[2][4];
#pragma unroll
  for (int set = 0; set < 2; ++set)
#pragma unroll
    for (int dt = 0; dt < 4; ++dt) o[set][dt] = (f32x4){0.f, 0.f, 0.f, 0.f};
  f32x4 o_l[2] = {(f32x4){0.f, 0.f, 0.f, 0.f}, (f32x4){0.f, 0.f, 0.f, 0.f}};

  // tile 0: load + stage into buffer 0
  f16x8 pk[2], pv[2];
#pragma unroll
  for (int i = 0; i < 2; ++i) {
    const int c = t + 256 * i, r = c >> 3, sg = c & 7;
    pk[i] = *(const f16x8*)&Kh[(bh + r) * CDK + sg * 8];
    pv[i] = *(const f16x8*)&Vth[(bhd + r) * CS + sg * 8];
  }
#pragma unroll
  for (int i = 0; i < 2; ++i) {
    const int c = t + 256 * i, r = c >> 3, sg = c & 7;
    *(f16x8*)&sm.kv.Ks[0][r][sg * 8] = pk[i];
    *(f16x8*)&sm.kv.Vs[0][r][sg * 8] = pv[i];
  }
  __syncthreads();

  auto ktile = [&](const int kt, const bool masked) __attribute__((always_inline)) {
    const int cur = kt & 1, nxt = cur ^ 1;
    // prefetch next tile into regs (clamped; uniform straight-line code)
    const int ktn = (kt + 1 < nt) ? kt + 1 : kt;
#pragma unroll
    for (int i = 0; i < 2; ++i) {
      const int c = t + 256 * i, r = c >> 3, sg = c & 7;
      pk[i] = *(const f16x8*)&Kh[(bh + ktn * 64 + r) * CDK + sg * 8];
      pv[i] = *(const f16x8*)&Vth[(bhd + r) * CS + ktn * 64 + sg * 8];
    }

    // swapped QK^T + exp + in-register P->A-frag transpose
    f16x8 pa[2][2];
#pragma unroll
    for (int set = 0; set < 2; ++set) {
      f32x4 st[4];
#pragma unroll
      for (int ct = 0; ct < 4; ++ct) {
        const f16x8 kb0 = *(const f16x8*)&sm.kv.Ks[cur][ct * 16 + lcol][quad * 8];
        const f16x8 kb1 =
            *(const f16x8*)&sm.kv.Ks[cur][ct * 16 + lcol][32 + quad * 8];
        st[ct] = mfma16(kb0, qa[set][0], (f32x4){0.f, 0.f, 0.f, 0.f});
        st[ct] = mfma16(kb1, qa[set][1], st[ct]);
      }
      unsigned pkd[4][2];
#pragma unroll
      for (int c = 0; c < 4; ++c) {
        float p[4];
#pragma unroll
        for (int r = 0; r < 4; ++r) {
          float e = fast_exp2(st[c][r]);
          if (masked) {
            const bool kvld = (kt * 64 + c * 16 + quad * 4 + r) < n;
            e = kvld ? e : 0.f;
          }
          p[r] = e;
        }
        pkd[c][0] = pack_rne(p[0], p[1]);
        pkd[c][1] = pack_rne(p[2], p[3]);
      }
      // quad-transpose: target quad t's dword j2 ends at k = 8t + 2*j2 + {0,1}
#pragma unroll
      for (int half = 0; half < 2; ++half) {
        unsigned x0 = pkd[2 * half][0], y0 = pkd[2 * half + 1][0];
        unsigned x1 = pkd[2 * half][1], y1 = pkd[2 * half + 1][1];
        quad_transpose(x0, y0);
        quad_transpose(x1, y1);
        union { u32x4 u; f16x8 h; } cc;
        cc.u = (u32x4){x0, x1, y0, y1};
        pa[set][half] = cc.h;
      }
    }

    // PV + row-sum MFMAs (P x ones = rowsum, lands directly in O-layout)
#pragma unroll
    for (int dt = 0; dt < 4; ++dt) {
      const f16x8 vb0 = *(const f16x8*)&sm.kv.Vs[cur][dt * 16 + lcol][quad * 8];
      const f16x8 vb1 =
          *(const f16x8*)&sm.kv.Vs[cur][dt * 16 + lcol][32 + quad * 8];
#pragma unroll
      for (int set = 0; set < 2; ++set) {
        o[set][dt] = mfma16(pa[set][0], vb0, o[set][dt]);
        o[set][dt] = mfma16(pa[set][1], vb1, o[set][dt]);
      }
    }
#pragma unroll
    for (int set = 0; set < 2; ++set) {
      o_l[set] = mfma16(pa[set][0], vones, o_l[set]);
      o_l[set] = mfma16(pa[set][1], vones, o_l[set]);
    }

    // stage next tile into the other buffer; one barrier covers both
    // write-visibility (buf nxt) and read-completion (buf cur)
#pragma unroll
    for (int i = 0; i < 2; ++i) {
      const int c = t + 256 * i, r = c >> 3, sg = c & 7;
      *(f16x8*)&sm.kv.Ks[nxt][r][sg * 8] = pk[i];
      *(f16x8*)&sm.kv.Vs[nxt][r][sg * 8] = pv[i];
    }
    __syncthreads();
  };

  int kt = 0;
  for (; kt < ntm; ++kt) ktile(kt, false);
  if (rem) ktile(kt, true);

  // per-lane inverse row-sums (already in O-layout: row quad*4+r, any col)
  float invl[2][4];
#pragma unroll
  for (int set = 0; set < 2; ++set)
#pragma unroll
    for (int r = 0; r < 4; ++r) invl[set][r] = 1.0f / o_l[set][r];

  // O -> wave-private St (f16), then coalesced 128-B-run stores.
  // (final loop barrier already fenced all K/V reads; St aliases kv)
#pragma unroll
  for (int set = 0; set < 2; ++set)
#pragma unroll
    for (int dt = 0; dt < 4; ++dt)
#pragma unroll
      for (int r = 0; r < 4; ++r) {
        const int srow_l = set * 16 + quad * 4 + r;
        const int d = dt * 16 + lcol;
        const float val = (qbase + srow_l < n)
                              ? o[set][dt][r] * invl[set][r]
                              : Vsum[bhd + d] * (1.0f / 1024.0f);
        sm.St[w][srow_l][d] = (f16)val;
      }
  {
    const int lr = lane >> 3, lc = lane & 7;
#pragma unroll
    for (int p = 0; p < 4; ++p) {
      const int row = p * 8 + lr;
      *(f16x8*)&Hbh[((size_t)b * CS + qbase + row) * (CH * CDK) + h * CDK +
                    lc * 8] = *(const f16x8*)&sm.St[w][row][lc * 8];
    }
  }
}

// ---------------------------------------------------------------------------
// Output projection: 128x128 tile, BK=64, gld16 + XOR swizzle (as qkvf).
// 1-D grid 512, XCD-affine decode: the 4 ctile blocks of one Hbh row-panel
// land consecutively on ONE XCD; woutt (0.5MB) L2-resident. NOT paired
// (r15 lesson: pairing halves blocks/CU, occupancy loss ~= barrier gain).
// ---------------------------------------------------------------------------
__global__ __launch_bounds__(256) void outp_kernel(const f16* __restrict__ Hbh,
                                                   const f16* __restrict__ woutt,
                                                   float* __restrict__ out) {
  const int id = blockIdx.x;
  const int xcd = id & 7;
  const int local = id >> 3;            // 0..63 per XCD
  const int ctile = local & 3;
  const int rt = xcd * 16 + (local >> 2);  // 0..127, contiguous per XCD
  const int row0 = rt * 128, col0 = ctile * 128;
  const f16* Wt = woutt + (size_t)col0 * CHID;
  const int t = threadIdx.x;
  const int w = t >> 6, lane = t & 63, quad = lane >> 4, lcol = lane & 15;
  const int wr = w >> 1, wc = w & 1;

  __shared__ f16 Hs[128][64];  // unpadded (lds-dma), XOR-swizzled columns
  __shared__ f16 Ws[128][64];

  f32x4 acc[4][4];
#pragma unroll
  for (int i = 0; i < 4; ++i)
#pragma unroll
    for (int j = 0; j < 4; ++j) acc[i][j] = (f32x4){0.f, 0.f, 0.f, 0.f};

  for (int k0 = 0; k0 < CHID; k0 += 64) {
    __syncthreads();
#pragma unroll
    for (int i = 0; i < 4; ++i) {
      const int c = t + 256 * i, r = c >> 3, sg = c & 7;
      const int gsw = (sg ^ (r & 7)) * 8;
      gld16(&Hbh[(size_t)(row0 + r) * CHID + k0 + gsw],
            (char*)&Hs[0][0] + c * 16);
      gld16(&Wt[(size_t)r * CHID + k0 + gsw], (char*)&Ws[0][0] + c * 16);
    }
    __syncthreads();

    f16x8 bf0[4], bf1[4];
#pragma unroll
    for (int j = 0; j < 4; ++j) {
      const int br = wc * 64 + j * 16 + lcol;
      bf0[j] = *(const f16x8*)&Ws[br][(quad ^ (br & 7)) * 8];
      bf1[j] = *(const f16x8*)&Ws[br][((quad ^ 4) ^ (br & 7)) * 8];
    }
#pragma unroll
    for (int i = 0; i < 4; ++i) {
      const int ar = wr * 64 + i * 16 + lcol;
      const f16x8 af0 = *(const f16x8*)&Hs[ar][(quad ^ (ar & 7)) * 8];
      const f16x8 af1 = *(const f16x8*)&Hs[ar][((quad ^ 4) ^ (ar & 7)) * 8];
#pragma unroll
      for (int j = 0; j < 4; ++j) {
        acc[i][j] = mfma16(af0, bf0[j], acc[i][j]);
        acc[i][j] = mfma16(af1, bf1[j], acc[i][j]);
      }
    }
  }

#pragma unroll
  for (int i = 0; i < 4; ++i) {
#pragma unroll
    for (int rr = 0; rr < 4; ++rr) {
      const size_t rg = row0 + wr * 64 + i * 16 + quad * 4 + rr;
#pragma unroll
      for (int j = 0; j < 4; ++j)
        out[rg * CHID + col0 + wc * 64 + j * 16 + lcol] = acc[i][j][rr];
    }
  }
}

// ---------------------------------------------------------------------------
extern "C" void kernel_launch(void* const* d_in, const int* in_sizes, int n_in,
                              void* d_out, int out_size, void* d_ws,
                              size_t ws_size, hipStream_t stream) {
  const float* x = (const float*)d_in[0];
  const int* mask = (const int*)d_in[1];
  const float* Wq = (const float*)d_in[2];
  const float* Wk = (const float*)d_in[3];
  const float* Wv = (const float*)d_in[4];
  const float* Wout = (const float*)d_in[5];
  float* out = (float*)d_out;

  char* ws = (char*)d_ws;
  int* lens = (int*)ws;
  size_t off = 1024;
  const size_t NX = (size_t)CB * CS * CHID;   // 8,388,608
  const size_t NW = (size_t)CH * CHID * CDK;  // 262,144 per weight
  f16* xh = (f16*)(ws + off);    off += NX * 2;
  f16* wtAll = (f16*)(ws + off); off += NW * 4 * 2;
  f16* Qh = (f16*)(ws + off);    off += NX * 2;
  f16* Kh = (f16*)(ws + off);    off += NX * 2;
  f16* Vth = (f16*)(ws + off);   off += NX * 2;
  f16* Hbh = (f16*)(ws + off);   off += NX * 2;
  float* Vsum = (float*)(ws + off); off += (size_t)CB * CH * CDK * 4;
  f16* woutt = wtAll + NW * 3;

  prep_kernel<<<8464, 256, 0, stream>>>((const float4*)x, (f16x4*)xh, mask,
                                        lens, Vsum, Wq, Wk, Wv, Wout, wtAll);
  qkvf_kernel<<<768, 256, 0, stream>>>(xh, wtAll, lens, Qh, Kh, Vth, Vsum);
  attn_kernel<<<1024, 256, 0, stream>>>(Qh, Kh, Vth, lens, Vsum, Hbh);
  outp_kernel<<<512, 256, 0, stream>>>(Hbh, woutt, out);
}